// Round 6
// baseline (9451.792 us; speedup 1.0000x reference)
//
#include <hip/hip_runtime.h>
#include <cstdint>
#include <math.h>

#define NB 16
#define DM 512
#define NH 8
#define DFF_ 2048
#define SMAX 45
#define PVJ 8

typedef unsigned short ushort_t;
typedef __bf16 bf16x8 __attribute__((ext_vector_type(8)));
typedef float f32x4 __attribute__((ext_vector_type(4)));

// ---------------- bf16 helpers ----------------
__device__ __forceinline__ ushort_t f2b(float f) {  // RNE f32 -> bf16 bits
  uint32_t u = __float_as_uint(f);
  uint32_t r = (u + 0x7FFFu + ((u >> 16) & 1u)) >> 16;
  return (ushort_t)r;
}
__device__ __forceinline__ float bu2f(ushort_t x) {
  return __uint_as_float((uint32_t)x << 16);
}
__device__ __forceinline__ float b2f_lo(uint32_t u) { return __uint_as_float(u << 16); }
__device__ __forceinline__ float b2f_hi(uint32_t u) { return __uint_as_float(u & 0xFFFF0000u); }

// ---------------- threefry2x32 (JAX-compatible) ----------------
__host__ __device__ inline void tf2x32(uint32_t k0, uint32_t k1,
                                       uint32_t x0, uint32_t x1,
                                       uint32_t* o0, uint32_t* o1) {
  uint32_t ks0 = k0, ks1 = k1, ks2 = k0 ^ k1 ^ 0x1BD11BDAu;
  x0 += ks0; x1 += ks1;
#define TF_RND(r) { x0 += x1; x1 = (x1 << (r)) | (x1 >> (32 - (r))); x1 ^= x0; }
  TF_RND(13) TF_RND(15) TF_RND(26) TF_RND(6)
  x0 += ks1; x1 += ks2 + 1u;
  TF_RND(17) TF_RND(29) TF_RND(16) TF_RND(24)
  x0 += ks2; x1 += ks0 + 2u;
  TF_RND(13) TF_RND(15) TF_RND(26) TF_RND(6)
  x0 += ks0; x1 += ks1 + 3u;
  TF_RND(17) TF_RND(29) TF_RND(16) TF_RND(24)
  x0 += ks1; x1 += ks2 + 4u;
  TF_RND(13) TF_RND(15) TF_RND(26) TF_RND(6)
  x0 += ks2; x1 += ks0 + 5u;
#undef TF_RND
  *o0 = x0; *o1 = x1;
}

__global__ void gen_idx_kernel(int* __restrict__ idx, uint32_t k0, uint32_t k1,
                               int n, int mask) {
  int j = blockIdx.x * 256 + threadIdx.x;
  if (j >= n) return;
  int half = n >> 1;
  uint32_t o0, o1;
  if (j < half) {
    tf2x32(k0, k1, (uint32_t)j, (uint32_t)(j + half), &o0, &o1);
    idx[j] = (int)(o0 & (uint32_t)mask);
  } else {
    tf2x32(k0, k1, (uint32_t)(j - half), (uint32_t)j, &o0, &o1);
    idx[j] = (int)(o1 & (uint32_t)mask);
  }
}

// ---------------- block reduce helpers (256 threads, wave64) ----------------
__device__ inline float blk_reduce_sum(float v) {
  __shared__ float s[4];
  for (int o = 32; o > 0; o >>= 1) v += __shfl_down(v, o);
  int lane = threadIdx.x & 63, w = threadIdx.x >> 6;
  if (lane == 0) s[w] = v;
  __syncthreads();
  float r = s[0] + s[1] + s[2] + s[3];
  __syncthreads();
  return r;
}
__device__ inline float blk_reduce_max(float v) {
  __shared__ float s[4];
  for (int o = 32; o > 0; o >>= 1) v = fmaxf(v, __shfl_down(v, o));
  int lane = threadIdx.x & 63, w = threadIdx.x >> 6;
  if (lane == 0) s[w] = v;
  __syncthreads();
  float r = fmaxf(fmaxf(s[0], s[1]), fmaxf(s[2], s[3]));
  __syncthreads();
  return r;
}

// ---------------- embedding (writes f32 h + bf16 shadow) ----------------
__global__ void embed_kernel(const float* __restrict__ x, const float* __restrict__ W,
                             const float* __restrict__ bias, float* __restrict__ h,
                             ushort_t* __restrict__ hb) {
  size_t gid = (size_t)blockIdx.x * 256 + threadIdx.x;
  int o = (int)(gid & 511);
  size_t bl = gid >> 9;
  const float* xr = x + bl * 7;
  float acc = bias[o];
#pragma unroll
  for (int i = 0; i < 7; ++i) acc += xr[i] * W[i * 512 + o];
  h[gid] = acc;
  hb[gid] = f2b(acc);
}

// ---------------- cast kernels (weights only) ----------------
__global__ void cast_bf16(const float* __restrict__ src, ushort_t* __restrict__ dst,
                          size_t n) {
  size_t i = ((size_t)blockIdx.x * 256 + threadIdx.x) * 4;
  if (i >= n) return;
  float4 v = *(const float4*)(src + i);
  ushort4 o;
  o.x = f2b(v.x); o.y = f2b(v.y); o.z = f2b(v.z); o.w = f2b(v.w);
  *(ushort4*)(dst + i) = o;
}

// Bt[n*512+k] = bf16(W[k*512+n])   (512x512)
__global__ void castT512(const float* __restrict__ W, ushort_t* __restrict__ Bt) {
  int gid = blockIdx.x * 256 + threadIdx.x;
  int n = gid >> 9, k = gid & 511;
  Bt[gid] = f2b(W[(size_t)k * 512 + n]);
}

// Bt[n*1536 + dt*512 + i] = bf16(convW[n][i][dt])
__global__ void cast_convW(const float* __restrict__ W, ushort_t* __restrict__ Bt) {
  int gid = blockIdx.x * 256 + threadIdx.x;
  int n = gid / 1536, k = gid - n * 1536;
  int dt = k >> 9, ii = k & 511;
  Bt[gid] = f2b(W[((size_t)n * 512 + ii) * 3 + dt]);
}

// ---------------- bf16 MFMA GEMM (m97 structure) ----------------
__device__ __forceinline__ float gelu_exact(float c) {
  return 0.5f * c * (1.0f + erff(c * 0.70710678118654752f));
}

template <int CONVMODE, int EPI>
__global__ __launch_bounds__(256) void mfma_gemm(
    const ushort_t* __restrict__ A, const ushort_t* __restrict__ Bt,
    const float* __restrict__ bias, float* __restrict__ Cf,
    ushort_t* __restrict__ Cb, const float* __restrict__ bng,
    const float* __restrict__ bnb, int N, int K, int L) {
  __shared__ __align__(16) ushort_t As[128 * 64];
  __shared__ __align__(16) ushort_t Bs[128 * 64];
  const int tid = threadIdx.x;
  const int lane = tid & 63;
  const int wid = tid >> 6;
  const int wr = wid >> 1, wc = wid & 1;
  const int bm = blockIdx.y, bn = blockIdx.x;
  const int ln = lane & 15, lh = lane >> 4;

  f32x4 acc[4][4] = {};

  for (int k0 = 0; k0 < K; k0 += 64) {
    __syncthreads();
#pragma unroll
    for (int it = 0; it < 4; ++it) {
      int c = it * 256 + tid;
      int row = c >> 3, kc = (c & 7) * 8;
      size_t ga;
      if (CONVMODE) {
        int m = bm * 128 + row;
        int b = m / L, tpos = m - b * L;
        int k = k0 + kc;
        int dt = k >> 9, ii = k & 511;
        int tr2 = tpos + dt - 1;
        if (tr2 < 0) tr2 += L;
        if (tr2 >= L) tr2 -= L;
        ga = ((size_t)(b * L + tr2)) * 512 + ii;
      } else {
        ga = (size_t)(bm * 128 + row) * K + k0 + kc;
      }
      __builtin_amdgcn_global_load_lds(
          (const __attribute__((address_space(1))) void*)(A + ga),
          (__attribute__((address_space(3))) void*)(As + c * 8), 16, 0, 0);
      size_t gb = (size_t)(bn * 128 + row) * K + k0 + kc;
      __builtin_amdgcn_global_load_lds(
          (const __attribute__((address_space(1))) void*)(Bt + gb),
          (__attribute__((address_space(3))) void*)(Bs + c * 8), 16, 0, 0);
    }
    __syncthreads();
#pragma unroll
    for (int kk = 0; kk < 2; ++kk) {
      bf16x8 af[4], bf_[4];
#pragma unroll
      for (int m = 0; m < 4; ++m)
        af[m] = *(const bf16x8*)&As[(wr * 64 + m * 16 + ln) * 64 + kk * 32 + lh * 8];
#pragma unroll
      for (int n = 0; n < 4; ++n)
        bf_[n] = *(const bf16x8*)&Bs[(wc * 64 + n * 16 + ln) * 64 + kk * 32 + lh * 8];
#pragma unroll
      for (int m = 0; m < 4; ++m)
#pragma unroll
        for (int n = 0; n < 4; ++n)
          acc[m][n] =
              __builtin_amdgcn_mfma_f32_16x16x32_bf16(af[m], bf_[n], acc[m][n], 0, 0, 0);
    }
  }

  const float bnscale = 0.9999950000374996f;  // 1/sqrt(1+1e-5)
#pragma unroll
  for (int m = 0; m < 4; ++m) {
    int row = bm * 128 + wr * 64 + m * 16 + lh * 4;
#pragma unroll
    for (int n = 0; n < 4; ++n) {
      int col = bn * 128 + wc * 64 + n * 16 + ln;
      float bsv = bias[col];
#pragma unroll
      for (int r = 0; r < 4; ++r) {
        float cval = acc[m][n][r] + bsv;
        size_t oi = (size_t)(row + r) * N + col;
        if (EPI == 0) {
          Cb[oi] = f2b(cval);
        } else if (EPI == 1) {
          Cf[oi] += cval;
        } else if (EPI == 2) {
          Cb[oi] = f2b(gelu_exact(cval));
        } else {
          float c2 = cval * bnscale * bng[col] + bnb[col];
          Cf[oi] = c2 > 0.0f ? c2 : expm1f(c2);
        }
      }
    }
  }
}

// ---------------- LN (in-place, row = 512; writes bf16 shadow) ----------------
__global__ __launch_bounds__(256) void ln_inplace(float* __restrict__ h,
                                                  ushort_t* __restrict__ hb,
                                                  const float* __restrict__ g,
                                                  const float* __restrict__ b) {
  size_t row = blockIdx.x;
  float* hr = h + row * 512;
  ushort_t* hbr = hb + row * 512;
  int t = threadIdx.x;
  float x0 = hr[t], x1 = hr[t + 256];
  float mean = blk_reduce_sum(x0 + x1) * (1.0f / 512.0f);
  float d0 = x0 - mean, d1 = x1 - mean;
  float var = blk_reduce_sum(d0 * d0 + d1 * d1) * (1.0f / 512.0f);
  float rstd = rsqrtf(var + 1e-5f);
  float y0 = d0 * rstd * g[t] + b[t];
  float y1 = d1 * rstd * g[t + 256] + b[t + 256];
  hr[t] = y0;
  hr[t + 256] = y1;
  hbr[t] = f2b(y0);
  hbr[t + 256] = f2b(y1);
}

// ---------------- prob-sparse M scores: one wave per (b,l), coalesced 1KB K rows ----
__global__ __launch_bounds__(256) void prob_scores_wave(const ushort_t* __restrict__ q,
                                                        const ushort_t* __restrict__ k,
                                                        const int* __restrict__ idx,
                                                        float* __restrict__ Mout,
                                                        int L, int S) {
  int wv = (blockIdx.x << 2) + ((threadIdx.x) >> 6);  // wave id over CB*L
  int lane = threadIdx.x & 63;
  int l = wv % L;
  int b = wv / L;
  const ushort_t* qr = q + ((size_t)(b * L + l)) * 512 + lane * 8;
  uint4 qu = *(const uint4*)qr;
  float qf[8];
  qf[0] = b2f_lo(qu.x); qf[1] = b2f_hi(qu.x);
  qf[2] = b2f_lo(qu.y); qf[3] = b2f_hi(qu.y);
  qf[4] = b2f_lo(qu.z); qf[5] = b2f_hi(qu.z);
  qf[6] = b2f_lo(qu.w); qf[7] = b2f_hi(qu.w);
  const int* il = idx + l * S;
  const ushort_t* kb = k + (size_t)b * L * 512 + lane * 8;
  float m = -INFINITY, ssum = 0.0f;
  for (int s = 0; s < S; ++s) {
    int j = il[s];
    uint4 ku = *(const uint4*)(kb + (size_t)j * 512);
    float dot = qf[0] * b2f_lo(ku.x) + qf[1] * b2f_hi(ku.x) +
                qf[2] * b2f_lo(ku.y) + qf[3] * b2f_hi(ku.y) +
                qf[4] * b2f_lo(ku.z) + qf[5] * b2f_hi(ku.z) +
                qf[6] * b2f_lo(ku.w) + qf[7] * b2f_hi(ku.w);
    // reduce within 8-lane head group
    dot += __shfl_xor(dot, 1);
    dot += __shfl_xor(dot, 2);
    dot += __shfl_xor(dot, 4);
    m = fmaxf(m, dot);
    ssum += dot;
  }
  if ((lane & 7) == 0) {
    int hh = lane >> 3;
    Mout[((size_t)(b * 8 + hh)) * L + l] = m - ssum / (float)L;
  }
}

// ---------------- top-k (iterative argmax, lower index wins ties) ----------------
__global__ __launch_bounds__(256) void topk_kernel(const float* __restrict__ Mbuf,
                                                   int* __restrict__ top_idx,
                                                   int L, int S) {
  int bh = blockIdx.x;
  __shared__ float vals[4096];
  __shared__ float rv[256];
  __shared__ int ri[256];
  const float* Mr = Mbuf + (size_t)bh * L;
  int t = threadIdx.x;
  for (int j = t; j < L; j += 256) vals[j] = Mr[j];
  __syncthreads();
  for (int it = 0; it < S; ++it) {
    float bv = -INFINITY;
    int bi = L;
    for (int j = t; j < L; j += 256) {
      float v = vals[j];
      if (v > bv || (v == bv && j < bi)) { bv = v; bi = j; }
    }
    rv[t] = bv; ri[t] = bi;
    __syncthreads();
    for (int s2 = 128; s2 > 0; s2 >>= 1) {
      if (t < s2) {
        float ov = rv[t + s2]; int oi = ri[t + s2];
        if (ov > rv[t] || (ov == rv[t] && oi < ri[t])) { rv[t] = ov; ri[t] = oi; }
      }
      __syncthreads();
    }
    if (t == 0) {
      top_idx[bh * S + it] = ri[0];
      vals[ri[0]] = -INFINITY;
    }
    __syncthreads();
  }
}

// ---------------- mean of V: stage 1 (coalesced column partial sums) ----------------
__global__ __launch_bounds__(256) void mean_v_partial(const ushort_t* __restrict__ v,
                                                      float* __restrict__ part, int L) {
  int b = blockIdx.x;
  int chunk = blockIdx.y;
  int t = threadIdx.x;
  int c = t * 2;
  const ushort_t* base = v + ((size_t)b * L + (size_t)chunk * 256) * 512 + c;
  float a0 = 0.0f, a1 = 0.0f;
#pragma unroll 8
  for (int r = 0; r < 256; ++r) {
    uint32_t u = *(const uint32_t*)(base + (size_t)r * 512);
    a0 += b2f_lo(u);
    a1 += b2f_hi(u);
  }
  float* p = part + ((size_t)b * 16 + chunk) * 512 + c;
  p[0] = a0;
  p[1] = a1;
}

// ---------------- mean of V: stage 2 ----------------
__global__ void mean_v_finish(const float* __restrict__ part, float* __restrict__ mv,
                              int L, int nchunks) {
  int b = blockIdx.x;
  int c = threadIdx.x;  // 512 threads
  float s = 0.0f;
  for (int k = 0; k < nchunks; ++k) s += part[((size_t)b * 16 + k) * 512 + c];
  mv[b * 512 + c] = s / (float)L;
}

// ---------------- fill ctx (bf16) with broadcast mean ----------------
__global__ void fill_ctx(ushort_t* __restrict__ ctx, const float* __restrict__ mv,
                         int L) {
  size_t gid = (size_t)blockIdx.x * 256 + threadIdx.x;  // CB*L*512
  int c = (int)(gid & 511);
  size_t bl = gid >> 9;
  int b = (int)(bl / (size_t)L);
  ctx[gid] = f2b(mv[b * 512 + c]);
}

// ---------------- attention stage 1: scores for selected queries ----------------
__global__ __launch_bounds__(256) void qk_scores(const ushort_t* __restrict__ q,
                                                 const ushort_t* __restrict__ k,
                                                 const int* __restrict__ top_idx,
                                                 float* __restrict__ sc,
                                                 int L, int S) {
  __shared__ float qs[SMAX * 64];
  int bh = blockIdx.y;
  int hh = bh & 7, b = bh >> 3;
  int t = threadIdx.x;
  for (int e = t; e < S * 64; e += 256) {
    int u = e >> 6, d = e & 63;
    int l = top_idx[bh * S + u];
    qs[e] = bu2f(q[((size_t)(b * L + l)) * 512 + hh * 64 + d]);
  }
  __syncthreads();
  int j = blockIdx.x * 256 + t;
  const ushort_t* kr = k + ((size_t)(b * L + j)) * 512 + hh * 64;
  float kk[64];
#pragma unroll
  for (int c = 0; c < 8; ++c) {
    uint4 u4 = ((const uint4*)kr)[c];
    kk[c * 8 + 0] = b2f_lo(u4.x); kk[c * 8 + 1] = b2f_hi(u4.x);
    kk[c * 8 + 2] = b2f_lo(u4.y); kk[c * 8 + 3] = b2f_hi(u4.y);
    kk[c * 8 + 4] = b2f_lo(u4.z); kk[c * 8 + 5] = b2f_hi(u4.z);
    kk[c * 8 + 6] = b2f_lo(u4.w); kk[c * 8 + 7] = b2f_hi(u4.w);
  }
  float* srow = sc + (size_t)bh * S * L + j;
  for (int u = 0; u < S; ++u) {
    const float4* qu = (const float4*)(qs + u * 64);
    float dot = 0.0f;
#pragma unroll
    for (int c = 0; c < 16; ++c) {
      float4 qv = qu[c];
      dot += qv.x * kk[c * 4 + 0] + qv.y * kk[c * 4 + 1] +
             qv.z * kk[c * 4 + 2] + qv.w * kk[c * 4 + 3];
    }
    srow[(size_t)u * L] = dot * 0.125f;
  }
}

// ---------------- attention stage 2: softmax rows ----------------
__global__ __launch_bounds__(256) void softmax_exp(float* __restrict__ sc,
                                                   float* __restrict__ Zbuf, int L) {
  size_t row = blockIdx.x;  // bh*S + u
  float* sr = sc + row * L;
  int t = threadIdx.x;
  float m = -INFINITY;
  for (int j = t; j < L; j += 256) m = fmaxf(m, sr[j]);
  m = blk_reduce_max(m);
  float s = 0.0f;
  for (int j = t; j < L; j += 256) {
    float e = __expf(sr[j] - m);
    sr[j] = e;
    s += e;
  }
  s = blk_reduce_sum(s);
  if (t == 0) Zbuf[row] = s;
}

// ---------------- attention stage 3: PV partial sums ----------------
__global__ __launch_bounds__(256) void pv_partial(const float* __restrict__ sc,
                                                  const ushort_t* __restrict__ v,
                                                  float* __restrict__ part,
                                                  int L, int S, int CBNH) {
  __shared__ float scs[SMAX][64];
  int bh = blockIdx.y, js = blockIdx.x;
  int hh = bh & 7, b = bh >> 3;
  int t = threadIdx.x;
  int d = t & 63, ug = t >> 6;
  int jlen = L / PVJ;
  int j0 = js * jlen;
  float acc[12] = {};
  const float* scb = sc + (size_t)bh * S * L;
  for (int jc = 0; jc < jlen; jc += 64) {
    __syncthreads();
    for (int e = t; e < S * 64; e += 256) {
      int u = e >> 6, jj = e & 63;
      scs[u][jj] = scb[(size_t)u * L + j0 + jc + jj];
    }
    __syncthreads();
#pragma unroll 2
    for (int jb = 0; jb < 64; jb += 4) {
      float vv[4];
#pragma unroll
      for (int r = 0; r < 4; ++r)
        vv[r] = bu2f(v[((size_t)(b * L + j0 + jc + jb + r)) * 512 + hh * 64 + d]);
#pragma unroll
      for (int mi = 0; mi < 12; ++mi) {
        int u = ug + mi * 4;
        if (u < S) {
          float4 p4 = *(const float4*)&scs[u][jb];
          acc[mi] += p4.x * vv[0] + p4.y * vv[1] + p4.z * vv[2] + p4.w * vv[3];
        }
      }
    }
  }
  float* pb = part + ((size_t)js * CBNH + bh) * (SMAX * 64);
#pragma unroll
  for (int mi = 0; mi < 12; ++mi) {
    int u = ug + mi * 4;
    if (u < S) pb[u * 64 + d] = acc[mi];
  }
}

// ---------------- attention stage 4: combine, /Z, scatter ----------------
__global__ void pv_finish(const float* __restrict__ part, const float* __restrict__ Zbuf,
                          const int* __restrict__ top_idx, ushort_t* __restrict__ ctx,
                          int L, int S, int CBNH) {
  int gid = blockIdx.x * 256 + threadIdx.x;  // over CBNH*S*64
  if (gid >= CBNH * S * 64) return;
  int d = gid & 63;
  int r = gid >> 6;  // bh*S + u
  int u = r % S, bh = r / S;
  int hh = bh & 7, b = bh >> 3;
  float s = 0.0f;
#pragma unroll
  for (int js = 0; js < PVJ; ++js)
    s += part[((size_t)js * CBNH + bh) * (SMAX * 64) + u * 64 + d];
  int l = top_idx[bh * S + u];
  ctx[((size_t)(b * L + l)) * 512 + hh * 64 + d] = f2b(s / Zbuf[r]);
}

// ---------------- maxpool window 3 stride 2 (writes f32 + bf16 shadow) ------------
__global__ void maxpool_kernel(const float* __restrict__ y, float* __restrict__ hout,
                               ushort_t* __restrict__ hbout, int L) {
  size_t gid = (size_t)blockIdx.x * 256 + threadIdx.x;  // CB*(L/2)*512
  int Lh = L >> 1;
  int o = (int)(gid & 511);
  size_t bj = gid >> 9;
  int j = (int)(bj % (size_t)Lh);
  int b = (int)(bj / (size_t)Lh);
  const float* base = y + ((size_t)(b * L + 2 * j)) * 512 + o;
  float mx = base[0];
  if (j > 0) mx = fmaxf(mx, base[-512]);
  mx = fmaxf(mx, base[512]);
  hout[gid] = mx;
  hbout[gid] = f2b(mx);
}

// ---------------- final LN + projection ----------------
__global__ __launch_bounds__(256) void final_ln_proj(const float* __restrict__ h,
                                                     const float* __restrict__ g,
                                                     const float* __restrict__ bb,
                                                     const float* __restrict__ pw,
                                                     const float* __restrict__ pb,
                                                     float* __restrict__ out, int L) {
  int b = blockIdx.x / 47, l = blockIdx.x % 47;
  const float* hr = h + ((size_t)(b * L + l)) * 512;
  int t = threadIdx.x;
  float x0 = hr[t], x1 = hr[t + 256];
  float mean = blk_reduce_sum(x0 + x1) * (1.0f / 512.0f);
  float d0 = x0 - mean, d1 = x1 - mean;
  float var = blk_reduce_sum(d0 * d0 + d1 * d1) * (1.0f / 512.0f);
  float rstd = rsqrtf(var + 1e-5f);
  float y0 = d0 * rstd * g[t] + bb[t];
  float y1 = d1 * rstd * g[t + 256] + bb[t + 256];
  float dot = blk_reduce_sum(y0 * pw[t] + y1 * pw[t + 256]);
  if (t == 0) out[b * 47 + l] = dot + pb[0];
}

// ---------------- launcher ----------------
extern "C" void kernel_launch(void* const* d_in, const int* in_sizes, int n_in,
                              void* d_out, int out_size, void* d_ws, size_t ws_size,
                              hipStream_t stream) {
  const float* x = (const float*)d_in[0];
  const float* emb_W = (const float*)d_in[1];
  const float* emb_b = (const float*)d_in[2];
  const float* Wq = (const float*)d_in[3];
  const float* bq = (const float*)d_in[4];
  const float* Wk = (const float*)d_in[5];
  const float* bk = (const float*)d_in[6];
  const float* Wv = (const float*)d_in[7];
  const float* bv = (const float*)d_in[8];
  const float* Wo = (const float*)d_in[9];
  const float* bo = (const float*)d_in[10];
  const float* fW1 = (const float*)d_in[11];
  const float* fb1 = (const float*)d_in[12];
  const float* fW2 = (const float*)d_in[13];
  const float* fb2 = (const float*)d_in[14];
  const float* ln1g = (const float*)d_in[15];
  const float* ln1b = (const float*)d_in[16];
  const float* ln2g = (const float*)d_in[17];
  const float* ln2b = (const float*)d_in[18];
  const float* cW = (const float*)d_in[19];
  const float* cb = (const float*)d_in[20];
  const float* bng = (const float*)d_in[21];
  const float* bnb = (const float*)d_in[22];
  const float* flng = (const float*)d_in[23];
  const float* flnb = (const float*)d_in[24];
  const float* pW = (const float*)d_in[25];
  const float* pb = (const float*)d_in[26];
  float* out = (float*)d_out;

  // batch-group size from ws_size (try 16, 8, 4, 2, 1)
  int CB = 16;
  while (CB > 1) {
    size_t need = 52496384ull + (size_t)CB * 5895400ull;
    if (need * 4 <= ws_size) break;
    CB >>= 1;
  }
  const size_t CBseg = (size_t)CB * 2097152ull;  // CB*4096*512 (bf16 elems)
  const int CBNH = CB * NH;

  float* ws = (float*)d_ws;
  size_t off = 0;
  float* h = ws;                           off += 33554432ull;
  ushort_t* wbase = (ushort_t*)(ws + off); off += 1966080ull;
  ushort_t* WqT = wbase;
  ushort_t* WkT = wbase + 262144;
  ushort_t* WvT = wbase + 524288;
  ushort_t* WoT = wbase + 786432;
  ushort_t* W1b = wbase + 1048576;
  ushort_t* W2b = wbase + 2097152;
  ushort_t* Wcb = wbase + 3145728;
  ushort_t* hbFull = (ushort_t*)(ws + off); off += 16777216ull;  // NB*4096*512 bf16
  ushort_t* gArea = (ushort_t*)(ws + off); off += 2ull * CBseg;  // 4*CBseg ushorts
  ushort_t* qb = gArea;
  ushort_t* kbuf = gArea + CBseg;
  ushort_t* vb = gArea + 2 * CBseg;
  ushort_t* ctxb = gArea + 3 * CBseg;
  ushort_t* ybuf = gArea;        // spans all 4 segs during FF
  float* convY = (float*)gArea;  // spans first 2 segs during conv
  float* Mbuf = ws + off;                  off += (size_t)CB * 32768;
  float* mv = ws + off;                    off += (size_t)CB * 512;
  int* topidx = (int*)(ws + off);          off += (size_t)CB * 384;
  int* idxbuf = (int*)(ws + off);          off += 196608ull;
  float* scbuf = ws + off;                 off += (size_t)CB * 1474560;  // CBNH*SMAX*4096
  float* Zbuf = ws + off;                  off += (size_t)CB * 360;      // CBNH*SMAX
  float* pvpart = ws + off;                off += (size_t)CB * 184320;   // PVJ*CBNH*SMAX*64
  float* mvpart = ws + off;                off += (size_t)CB * 8192;     // CB*16*512

  // embedding (f32 + bf16 shadow)
  {
    size_t total = (size_t)NB * 4096 * DM;
    embed_kernel<<<(int)(total / 256), 256, 0, stream>>>(x, emb_W, emb_b, h, hbFull);
  }

  int L = 4096;
  for (int i = 0; i < 3; ++i) {
    int S = (i == 0) ? 45 : (i == 1) ? 40 : 35;
    int ngroups = NB / CB;
    int Mg = CB * L;
    size_t segL = (size_t)Mg * 512;

    // per-layer weight casts
    castT512<<<1024, 256, 0, stream>>>(Wq + (size_t)i * 262144, WqT);
    castT512<<<1024, 256, 0, stream>>>(Wk + (size_t)i * 262144, WkT);
    castT512<<<1024, 256, 0, stream>>>(Wv + (size_t)i * 262144, WvT);
    castT512<<<1024, 256, 0, stream>>>(Wo + (size_t)i * 262144, WoT);
    cast_bf16<<<1024, 256, 0, stream>>>(fW1 + (size_t)i * 1048576, W1b, 1048576);
    cast_bf16<<<1024, 256, 0, stream>>>(fW2 + (size_t)i * 1048576, W2b, 1048576);
    if (i < 2) cast_convW<<<3072, 256, 0, stream>>>(cW + (size_t)i * 786432, Wcb);

    // JAX randint key
    uint32_t fa, fbk;
    tf2x32(0u, 42u, 0u, (uint32_t)i, &fa, &fbk);
    uint32_t a0, b0, a1, b1;
    tf2x32(fa, fbk, 0u, 2u, &a0, &b0);
    tf2x32(fa, fbk, 1u, 3u, &a1, &b1);
    int n = L * S;
    gen_idx_kernel<<<(n + 255) / 256, 256, 0, stream>>>(idxbuf, b0, b1, n, L - 1);

    // ---- attention per batch group ----
    for (int g = 0; g < ngroups; ++g) {
      float* hg = h + (size_t)g * segL;
      ushort_t* hbg = hbFull + (size_t)g * segL;
      dim3 gq(4, Mg / 128);
      mfma_gemm<0, 0><<<gq, 256, 0, stream>>>(hbg, WqT, bq + i * DM, nullptr, qb,
                                              nullptr, nullptr, 512, 512, 0);
      mfma_gemm<0, 0><<<gq, 256, 0, stream>>>(hbg, WkT, bk + i * DM, nullptr, kbuf,
                                              nullptr, nullptr, 512, 512, 0);
      mfma_gemm<0, 0><<<gq, 256, 0, stream>>>(hbg, WvT, bv + i * DM, nullptr, vb,
                                              nullptr, nullptr, 512, 512, 0);

      prob_scores_wave<<<(CB * L) / 4, 256, 0, stream>>>(qb, kbuf, idxbuf, Mbuf, L, S);
      topk_kernel<<<CBNH, 256, 0, stream>>>(Mbuf, topidx, L, S);

      qk_scores<<<dim3(L / 256, CBNH), 256, 0, stream>>>(qb, kbuf, topidx, scbuf, L, S);
      softmax_exp<<<CBNH * S, 256, 0, stream>>>(scbuf, Zbuf, L);
      mean_v_partial<<<dim3(CB, L / 256), 256, 0, stream>>>(vb, mvpart, L);
      mean_v_finish<<<CB, 512, 0, stream>>>(mvpart, mv, L, L / 256);
      fill_ctx<<<(int)(segL / 256), 256, 0, stream>>>(ctxb, mv, L);
      pv_partial<<<dim3(PVJ, CBNH), 256, 0, stream>>>(scbuf, vb, pvpart, L, S, CBNH);
      pv_finish<<<(CBNH * S * 64 + 255) / 256, 256, 0, stream>>>(pvpart, Zbuf, topidx,
                                                                 ctxb, L, S, CBNH);

      mfma_gemm<0, 1><<<gq, 256, 0, stream>>>(ctxb, WoT, bo + i * DM, hg, nullptr,
                                              nullptr, nullptr, 512, 512, 0);
    }
    ln_inplace<<<NB * L, 256, 0, stream>>>(h, hbFull, ln1g + i * DM, ln1b + i * DM);

    // ---- FF row-chunked (A read from hbFull shadow) ----
    int rows = NB * L;
    int R = CB * 4096;
    if (R > rows) R = rows;
    for (int r0 = 0; r0 < rows; r0 += R) {
      float* hr = h + (size_t)r0 * 512;
      ushort_t* hbr = hbFull + (size_t)r0 * 512;
      dim3 g1(16, R / 128);
      mfma_gemm<0, 2><<<g1, 256, 0, stream>>>(hbr, W1b, fb1 + i * DFF_, nullptr, ybuf,
                                              nullptr, nullptr, 2048, 512, 0);
      dim3 g2(4, R / 128);
      mfma_gemm<0, 1><<<g2, 256, 0, stream>>>(ybuf, W2b, fb2 + i * DM, hr, nullptr,
                                              nullptr, nullptr, 512, 2048, 0);
    }
    ln_inplace<<<NB * L, 256, 0, stream>>>(h, hbFull, ln2g + i * DM, ln2b + i * DM);

    // ---- conv + maxpool per batch group ----
    if (i < 2) {
      int Lh = L / 2;
      for (int g = 0; g < ngroups; ++g) {
        ushort_t* hbg = hbFull + (size_t)g * segL;
        dim3 gc(4, Mg / 128);
        mfma_gemm<1, 3><<<gc, 256, 0, stream>>>(hbg, Wcb, cb + i * DM, convY, nullptr,
                                                bng + i * DM, bnb + i * DM, 512, 1536, L);
        size_t tot = (size_t)CB * Lh * 512;
        maxpool_kernel<<<(int)(tot / 256), 256, 0, stream>>>(
            convY, h + (size_t)g * CB * Lh * 512, hbFull + (size_t)g * CB * Lh * 512, L);
      }
      L = Lh;
    }
  }

  final_ln_proj<<<NB * 47, 256, 0, stream>>>(h, flng, flnb, pW, pb, out, L);
}

// Round 7
// 5847.784 us; speedup vs baseline: 1.6163x; 1.6163x over previous
//
#include <hip/hip_runtime.h>
#include <cstdint>
#include <math.h>

#define NB 16
#define DM 512
#define NH 8
#define DFF_ 2048
#define SMAX 45
#define PVJ 8

typedef unsigned short ushort_t;
typedef __bf16 bf16x8 __attribute__((ext_vector_type(8)));
typedef float f32x4 __attribute__((ext_vector_type(4)));

// ---------------- bf16 helpers ----------------
__device__ __forceinline__ ushort_t f2b(float f) {  // RNE f32 -> bf16 bits
  uint32_t u = __float_as_uint(f);
  uint32_t r = (u + 0x7FFFu + ((u >> 16) & 1u)) >> 16;
  return (ushort_t)r;
}
__device__ __forceinline__ float bu2f(ushort_t x) {
  return __uint_as_float((uint32_t)x << 16);
}
__device__ __forceinline__ float b2f_lo(uint32_t u) { return __uint_as_float(u << 16); }
__device__ __forceinline__ float b2f_hi(uint32_t u) { return __uint_as_float(u & 0xFFFF0000u); }

// ---------------- threefry2x32 (JAX-compatible) ----------------
__host__ __device__ inline void tf2x32(uint32_t k0, uint32_t k1,
                                       uint32_t x0, uint32_t x1,
                                       uint32_t* o0, uint32_t* o1) {
  uint32_t ks0 = k0, ks1 = k1, ks2 = k0 ^ k1 ^ 0x1BD11BDAu;
  x0 += ks0; x1 += ks1;
#define TF_RND(r) { x0 += x1; x1 = (x1 << (r)) | (x1 >> (32 - (r))); x1 ^= x0; }
  TF_RND(13) TF_RND(15) TF_RND(26) TF_RND(6)
  x0 += ks1; x1 += ks2 + 1u;
  TF_RND(17) TF_RND(29) TF_RND(16) TF_RND(24)
  x0 += ks2; x1 += ks0 + 2u;
  TF_RND(13) TF_RND(15) TF_RND(26) TF_RND(6)
  x0 += ks0; x1 += ks1 + 3u;
  TF_RND(17) TF_RND(29) TF_RND(16) TF_RND(24)
  x0 += ks1; x1 += ks2 + 4u;
  TF_RND(13) TF_RND(15) TF_RND(26) TF_RND(6)
  x0 += ks2; x1 += ks0 + 5u;
#undef TF_RND
  *o0 = x0; *o1 = x1;
}

__global__ void gen_idx_kernel(int* __restrict__ idx, uint32_t k0, uint32_t k1,
                               int n, int mask) {
  int j = blockIdx.x * 256 + threadIdx.x;
  if (j >= n) return;
  int half = n >> 1;
  uint32_t o0, o1;
  if (j < half) {
    tf2x32(k0, k1, (uint32_t)j, (uint32_t)(j + half), &o0, &o1);
    idx[j] = (int)(o0 & (uint32_t)mask);
  } else {
    tf2x32(k0, k1, (uint32_t)(j - half), (uint32_t)j, &o0, &o1);
    idx[j] = (int)(o1 & (uint32_t)mask);
  }
}

// ---------------- block reduce helpers (256 threads, wave64) ----------------
__device__ inline float blk_reduce_sum(float v) {
  __shared__ float s[4];
  for (int o = 32; o > 0; o >>= 1) v += __shfl_down(v, o);
  int lane = threadIdx.x & 63, w = threadIdx.x >> 6;
  if (lane == 0) s[w] = v;
  __syncthreads();
  float r = s[0] + s[1] + s[2] + s[3];
  __syncthreads();
  return r;
}
__device__ inline float blk_reduce_max(float v) {
  __shared__ float s[4];
  for (int o = 32; o > 0; o >>= 1) v = fmaxf(v, __shfl_down(v, o));
  int lane = threadIdx.x & 63, w = threadIdx.x >> 6;
  if (lane == 0) s[w] = v;
  __syncthreads();
  float r = fmaxf(fmaxf(s[0], s[1]), fmaxf(s[2], s[3]));
  __syncthreads();
  return r;
}

// ---------------- embedding ----------------
__global__ void embed_kernel(const float* __restrict__ x, const float* __restrict__ W,
                             const float* __restrict__ bias, float* __restrict__ h) {
  size_t gid = (size_t)blockIdx.x * 256 + threadIdx.x;
  int o = (int)(gid & 511);
  size_t bl = gid >> 9;
  const float* xr = x + bl * 7;
  float acc = bias[o];
#pragma unroll
  for (int i = 0; i < 7; ++i) acc += xr[i] * W[i * 512 + o];
  h[gid] = acc;
}

// ---------------- cast kernels ----------------
__global__ void cast_bf16(const float* __restrict__ src, ushort_t* __restrict__ dst,
                          size_t n) {
  size_t i = ((size_t)blockIdx.x * 256 + threadIdx.x) * 4;
  if (i >= n) return;
  float4 v = *(const float4*)(src + i);
  ushort4 o;
  o.x = f2b(v.x); o.y = f2b(v.y); o.z = f2b(v.z); o.w = f2b(v.w);
  *(ushort4*)(dst + i) = o;
}

// Bt[n*512+k] = bf16(W[k*512+n])   (512x512)
__global__ void castT512(const float* __restrict__ W, ushort_t* __restrict__ Bt) {
  int gid = blockIdx.x * 256 + threadIdx.x;
  int n = gid >> 9, k = gid & 511;
  Bt[gid] = f2b(W[(size_t)k * 512 + n]);
}

// Bt[n*1536 + dt*512 + i] = bf16(convW[n][i][dt])
__global__ void cast_convW(const float* __restrict__ W, ushort_t* __restrict__ Bt) {
  int gid = blockIdx.x * 256 + threadIdx.x;
  int n = gid / 1536, k = gid - n * 1536;
  int dt = k >> 9, ii = k & 511;
  Bt[gid] = f2b(W[((size_t)n * 512 + ii) * 3 + dt]);
}

// ---------------- bf16 MFMA GEMM (m97 structure) ----------------
__device__ __forceinline__ float gelu_exact(float c) {
  return 0.5f * c * (1.0f + erff(c * 0.70710678118654752f));
}

template <int CONVMODE, int EPI>
__global__ __launch_bounds__(256) void mfma_gemm(
    const ushort_t* __restrict__ A, const ushort_t* __restrict__ Bt,
    const float* __restrict__ bias, float* __restrict__ Cf,
    ushort_t* __restrict__ Cb, const float* __restrict__ bng,
    const float* __restrict__ bnb, int N, int K, int L) {
  __shared__ __align__(16) ushort_t As[128 * 64];
  __shared__ __align__(16) ushort_t Bs[128 * 64];
  const int tid = threadIdx.x;
  const int lane = tid & 63;
  const int wid = tid >> 6;
  const int wr = wid >> 1, wc = wid & 1;
  const int bm = blockIdx.y, bn = blockIdx.x;
  const int ln = lane & 15, lh = lane >> 4;

  f32x4 acc[4][4] = {};

  for (int k0 = 0; k0 < K; k0 += 64) {
    __syncthreads();
#pragma unroll
    for (int it = 0; it < 4; ++it) {
      int c = it * 256 + tid;
      int row = c >> 3, kc = (c & 7) * 8;
      size_t ga;
      if (CONVMODE) {
        int m = bm * 128 + row;
        int b = m / L, tpos = m - b * L;
        int k = k0 + kc;
        int dt = k >> 9, ii = k & 511;
        int tr2 = tpos + dt - 1;
        if (tr2 < 0) tr2 += L;
        if (tr2 >= L) tr2 -= L;
        ga = ((size_t)(b * L + tr2)) * 512 + ii;
      } else {
        ga = (size_t)(bm * 128 + row) * K + k0 + kc;
      }
      __builtin_amdgcn_global_load_lds(
          (const __attribute__((address_space(1))) void*)(A + ga),
          (__attribute__((address_space(3))) void*)(As + c * 8), 16, 0, 0);
      size_t gb = (size_t)(bn * 128 + row) * K + k0 + kc;
      __builtin_amdgcn_global_load_lds(
          (const __attribute__((address_space(1))) void*)(Bt + gb),
          (__attribute__((address_space(3))) void*)(Bs + c * 8), 16, 0, 0);
    }
    __syncthreads();
#pragma unroll
    for (int kk = 0; kk < 2; ++kk) {
      bf16x8 af[4], bf_[4];
#pragma unroll
      for (int m = 0; m < 4; ++m)
        af[m] = *(const bf16x8*)&As[(wr * 64 + m * 16 + ln) * 64 + kk * 32 + lh * 8];
#pragma unroll
      for (int n = 0; n < 4; ++n)
        bf_[n] = *(const bf16x8*)&Bs[(wc * 64 + n * 16 + ln) * 64 + kk * 32 + lh * 8];
#pragma unroll
      for (int m = 0; m < 4; ++m)
#pragma unroll
        for (int n = 0; n < 4; ++n)
          acc[m][n] =
              __builtin_amdgcn_mfma_f32_16x16x32_bf16(af[m], bf_[n], acc[m][n], 0, 0, 0);
    }
  }

  const float bnscale = 0.9999950000374996f;  // 1/sqrt(1+1e-5)
#pragma unroll
  for (int m = 0; m < 4; ++m) {
    int row = bm * 128 + wr * 64 + m * 16 + lh * 4;
#pragma unroll
    for (int n = 0; n < 4; ++n) {
      int col = bn * 128 + wc * 64 + n * 16 + ln;
      float bsv = bias[col];
#pragma unroll
      for (int r = 0; r < 4; ++r) {
        float cval = acc[m][n][r] + bsv;
        size_t oi = (size_t)(row + r) * N + col;
        if (EPI == 0) {
          Cb[oi] = f2b(cval);
        } else if (EPI == 1) {
          Cf[oi] += cval;
        } else if (EPI == 2) {
          Cb[oi] = f2b(gelu_exact(cval));
        } else {
          float c2 = cval * bnscale * bng[col] + bnb[col];
          Cf[oi] = c2 > 0.0f ? c2 : expm1f(c2);
        }
      }
    }
  }
}

// ---------------- LN (in-place, row = 512) ----------------
__global__ __launch_bounds__(256) void ln_inplace(float* __restrict__ h,
                                                  const float* __restrict__ g,
                                                  const float* __restrict__ b) {
  size_t row = blockIdx.x;
  float* hr = h + row * 512;
  int t = threadIdx.x;
  float x0 = hr[t], x1 = hr[t + 256];
  float mean = blk_reduce_sum(x0 + x1) * (1.0f / 512.0f);
  float d0 = x0 - mean, d1 = x1 - mean;
  float var = blk_reduce_sum(d0 * d0 + d1 * d1) * (1.0f / 512.0f);
  float rstd = rsqrtf(var + 1e-5f);
  hr[t] = d0 * rstd * g[t] + b[t];
  hr[t + 256] = d1 * rstd * g[t + 256] + b[t + 256];
}

// ---------------- prob-sparse M scores: one wave per (b,l), coalesced 1KB K rows ----
__global__ __launch_bounds__(256) void prob_scores_wave(const ushort_t* __restrict__ q,
                                                        const ushort_t* __restrict__ k,
                                                        const int* __restrict__ idx,
                                                        float* __restrict__ Mout,
                                                        int L, int S) {
  int wv = (blockIdx.x << 2) + ((threadIdx.x) >> 6);  // wave id over CB*L
  int lane = threadIdx.x & 63;
  int l = wv % L;
  int b = wv / L;
  const ushort_t* qr = q + ((size_t)(b * L + l)) * 512 + lane * 8;
  uint4 qu = *(const uint4*)qr;
  float qf[8];
  qf[0] = b2f_lo(qu.x); qf[1] = b2f_hi(qu.x);
  qf[2] = b2f_lo(qu.y); qf[3] = b2f_hi(qu.y);
  qf[4] = b2f_lo(qu.z); qf[5] = b2f_hi(qu.z);
  qf[6] = b2f_lo(qu.w); qf[7] = b2f_hi(qu.w);
  const int* il = idx + l * S;
  const ushort_t* kb = k + (size_t)b * L * 512 + lane * 8;
  float m = -INFINITY, ssum = 0.0f;
  for (int s = 0; s < S; ++s) {
    int j = il[s];
    uint4 ku = *(const uint4*)(kb + (size_t)j * 512);
    float dot = qf[0] * b2f_lo(ku.x) + qf[1] * b2f_hi(ku.x) +
                qf[2] * b2f_lo(ku.y) + qf[3] * b2f_hi(ku.y) +
                qf[4] * b2f_lo(ku.z) + qf[5] * b2f_hi(ku.z) +
                qf[6] * b2f_lo(ku.w) + qf[7] * b2f_hi(ku.w);
    // reduce within 8-lane head group
    dot += __shfl_xor(dot, 1);
    dot += __shfl_xor(dot, 2);
    dot += __shfl_xor(dot, 4);
    m = fmaxf(m, dot);
    ssum += dot;
  }
  if ((lane & 7) == 0) {
    int hh = lane >> 3;
    Mout[((size_t)(b * 8 + hh)) * L + l] = m - ssum / (float)L;
  }
}

// ---------------- top-k (iterative argmax, lower index wins ties) ----------------
__global__ __launch_bounds__(256) void topk_kernel(const float* __restrict__ Mbuf,
                                                   int* __restrict__ top_idx,
                                                   int L, int S) {
  int bh = blockIdx.x;
  __shared__ float vals[4096];
  __shared__ float rv[256];
  __shared__ int ri[256];
  const float* Mr = Mbuf + (size_t)bh * L;
  int t = threadIdx.x;
  for (int j = t; j < L; j += 256) vals[j] = Mr[j];
  __syncthreads();
  for (int it = 0; it < S; ++it) {
    float bv = -INFINITY;
    int bi = L;
    for (int j = t; j < L; j += 256) {
      float v = vals[j];
      if (v > bv || (v == bv && j < bi)) { bv = v; bi = j; }
    }
    rv[t] = bv; ri[t] = bi;
    __syncthreads();
    for (int s2 = 128; s2 > 0; s2 >>= 1) {
      if (t < s2) {
        float ov = rv[t + s2]; int oi = ri[t + s2];
        if (ov > rv[t] || (ov == rv[t] && oi < ri[t])) { rv[t] = ov; ri[t] = oi; }
      }
      __syncthreads();
    }
    if (t == 0) {
      top_idx[bh * S + it] = ri[0];
      vals[ri[0]] = -INFINITY;
    }
    __syncthreads();
  }
}

// ---------------- mean of V: stage 1 (coalesced column partial sums) ----------------
__global__ __launch_bounds__(256) void mean_v_partial(const ushort_t* __restrict__ v,
                                                      float* __restrict__ part, int L) {
  int b = blockIdx.x;
  int chunk = blockIdx.y;
  int t = threadIdx.x;
  int c = t * 2;
  const ushort_t* base = v + ((size_t)b * L + (size_t)chunk * 256) * 512 + c;
  float a0 = 0.0f, a1 = 0.0f;
#pragma unroll 8
  for (int r = 0; r < 256; ++r) {
    uint32_t u = *(const uint32_t*)(base + (size_t)r * 512);
    a0 += b2f_lo(u);
    a1 += b2f_hi(u);
  }
  float* p = part + ((size_t)b * 16 + chunk) * 512 + c;
  p[0] = a0;
  p[1] = a1;
}

// ---------------- mean of V: stage 2 ----------------
__global__ void mean_v_finish(const float* __restrict__ part, float* __restrict__ mv,
                              int L, int nchunks) {
  int b = blockIdx.x;
  int c = threadIdx.x;  // 512 threads
  float s = 0.0f;
  for (int k = 0; k < nchunks; ++k) s += part[((size_t)b * 16 + k) * 512 + c];
  mv[b * 512 + c] = s / (float)L;
}

// ---------------- fill ctx (bf16) with broadcast mean ----------------
__global__ void fill_ctx(ushort_t* __restrict__ ctx, const float* __restrict__ mv,
                         int L) {
  size_t gid = (size_t)blockIdx.x * 256 + threadIdx.x;  // CB*L*512
  int c = (int)(gid & 511);
  size_t bl = gid >> 9;
  int b = (int)(bl / (size_t)L);
  ctx[gid] = f2b(mv[b * 512 + c]);
}

// ---------------- attention stage 1: scores for selected queries ----------------
__global__ __launch_bounds__(256) void qk_scores(const ushort_t* __restrict__ q,
                                                 const ushort_t* __restrict__ k,
                                                 const int* __restrict__ top_idx,
                                                 float* __restrict__ sc,
                                                 int L, int S) {
  __shared__ float qs[SMAX * 64];
  int bh = blockIdx.y;
  int hh = bh & 7, b = bh >> 3;
  int t = threadIdx.x;
  for (int e = t; e < S * 64; e += 256) {
    int u = e >> 6, d = e & 63;
    int l = top_idx[bh * S + u];
    qs[e] = bu2f(q[((size_t)(b * L + l)) * 512 + hh * 64 + d]);
  }
  __syncthreads();
  int j = blockIdx.x * 256 + t;
  const ushort_t* kr = k + ((size_t)(b * L + j)) * 512 + hh * 64;
  float kk[64];
#pragma unroll
  for (int c = 0; c < 8; ++c) {
    uint4 u4 = ((const uint4*)kr)[c];
    kk[c * 8 + 0] = b2f_lo(u4.x); kk[c * 8 + 1] = b2f_hi(u4.x);
    kk[c * 8 + 2] = b2f_lo(u4.y); kk[c * 8 + 3] = b2f_hi(u4.y);
    kk[c * 8 + 4] = b2f_lo(u4.z); kk[c * 8 + 5] = b2f_hi(u4.z);
    kk[c * 8 + 6] = b2f_lo(u4.w); kk[c * 8 + 7] = b2f_hi(u4.w);
  }
  float* srow = sc + (size_t)bh * S * L + j;
  for (int u = 0; u < S; ++u) {
    const float4* qu = (const float4*)(qs + u * 64);
    float dot = 0.0f;
#pragma unroll
    for (int c = 0; c < 16; ++c) {
      float4 qv = qu[c];
      dot += qv.x * kk[c * 4 + 0] + qv.y * kk[c * 4 + 1] +
             qv.z * kk[c * 4 + 2] + qv.w * kk[c * 4 + 3];
    }
    srow[(size_t)u * L] = dot * 0.125f;
  }
}

// ---------------- attention stage 2: softmax rows ----------------
__global__ __launch_bounds__(256) void softmax_exp(float* __restrict__ sc,
                                                   float* __restrict__ Zbuf, int L) {
  size_t row = blockIdx.x;  // bh*S + u
  float* sr = sc + row * L;
  int t = threadIdx.x;
  float m = -INFINITY;
  for (int j = t; j < L; j += 256) m = fmaxf(m, sr[j]);
  m = blk_reduce_max(m);
  float s = 0.0f;
  for (int j = t; j < L; j += 256) {
    float e = __expf(sr[j] - m);
    sr[j] = e;
    s += e;
  }
  s = blk_reduce_sum(s);
  if (t == 0) Zbuf[row] = s;
}

// ---------------- attention stage 3: PV partial sums ----------------
__global__ __launch_bounds__(256) void pv_partial(const float* __restrict__ sc,
                                                  const ushort_t* __restrict__ v,
                                                  float* __restrict__ part,
                                                  int L, int S, int CBNH) {
  __shared__ float scs[SMAX][64];
  int bh = blockIdx.y, js = blockIdx.x;
  int hh = bh & 7, b = bh >> 3;
  int t = threadIdx.x;
  int d = t & 63, ug = t >> 6;
  int jlen = L / PVJ;
  int j0 = js * jlen;
  float acc[12] = {};
  const float* scb = sc + (size_t)bh * S * L;
  for (int jc = 0; jc < jlen; jc += 64) {
    __syncthreads();
    for (int e = t; e < S * 64; e += 256) {
      int u = e >> 6, jj = e & 63;
      scs[u][jj] = scb[(size_t)u * L + j0 + jc + jj];
    }
    __syncthreads();
#pragma unroll 2
    for (int jb = 0; jb < 64; jb += 4) {
      float vv[4];
#pragma unroll
      for (int r = 0; r < 4; ++r)
        vv[r] = bu2f(v[((size_t)(b * L + j0 + jc + jb + r)) * 512 + hh * 64 + d]);
#pragma unroll
      for (int mi = 0; mi < 12; ++mi) {
        int u = ug + mi * 4;
        if (u < S) {
          float4 p4 = *(const float4*)&scs[u][jb];
          acc[mi] += p4.x * vv[0] + p4.y * vv[1] + p4.z * vv[2] + p4.w * vv[3];
        }
      }
    }
  }
  float* pb = part + ((size_t)js * CBNH + bh) * (SMAX * 64);
#pragma unroll
  for (int mi = 0; mi < 12; ++mi) {
    int u = ug + mi * 4;
    if (u < S) pb[u * 64 + d] = acc[mi];
  }
}

// ---------------- attention stage 4: combine, /Z, scatter ----------------
__global__ void pv_finish(const float* __restrict__ part, const float* __restrict__ Zbuf,
                          const int* __restrict__ top_idx, ushort_t* __restrict__ ctx,
                          int L, int S, int CBNH) {
  int gid = blockIdx.x * 256 + threadIdx.x;  // over CBNH*S*64
  if (gid >= CBNH * S * 64) return;
  int d = gid & 63;
  int r = gid >> 6;  // bh*S + u
  int u = r % S, bh = r / S;
  int hh = bh & 7, b = bh >> 3;
  float s = 0.0f;
#pragma unroll
  for (int js = 0; js < PVJ; ++js)
    s += part[((size_t)js * CBNH + bh) * (SMAX * 64) + u * 64 + d];
  int l = top_idx[bh * S + u];
  ctx[((size_t)(b * L + l)) * 512 + hh * 64 + d] = f2b(s / Zbuf[r]);
}

// ---------------- maxpool window 3 stride 2 ----------------
__global__ void maxpool_kernel(const float* __restrict__ y, float* __restrict__ hout,
                               int L) {
  size_t gid = (size_t)blockIdx.x * 256 + threadIdx.x;  // CB*(L/2)*512
  int Lh = L >> 1;
  int o = (int)(gid & 511);
  size_t bj = gid >> 9;
  int j = (int)(bj % (size_t)Lh);
  int b = (int)(bj / (size_t)Lh);
  const float* base = y + ((size_t)(b * L + 2 * j)) * 512 + o;
  float mx = base[0];
  if (j > 0) mx = fmaxf(mx, base[-512]);
  mx = fmaxf(mx, base[512]);
  hout[gid] = mx;
}

// ---------------- final LN + projection ----------------
__global__ __launch_bounds__(256) void final_ln_proj(const float* __restrict__ h,
                                                     const float* __restrict__ g,
                                                     const float* __restrict__ bb,
                                                     const float* __restrict__ pw,
                                                     const float* __restrict__ pb,
                                                     float* __restrict__ out, int L) {
  int b = blockIdx.x / 47, l = blockIdx.x % 47;
  const float* hr = h + ((size_t)(b * L + l)) * 512;
  int t = threadIdx.x;
  float x0 = hr[t], x1 = hr[t + 256];
  float mean = blk_reduce_sum(x0 + x1) * (1.0f / 512.0f);
  float d0 = x0 - mean, d1 = x1 - mean;
  float var = blk_reduce_sum(d0 * d0 + d1 * d1) * (1.0f / 512.0f);
  float rstd = rsqrtf(var + 1e-5f);
  float y0 = d0 * rstd * g[t] + bb[t];
  float y1 = d1 * rstd * g[t + 256] + bb[t + 256];
  float dot = blk_reduce_sum(y0 * pw[t] + y1 * pw[t + 256]);
  if (t == 0) out[b * 47 + l] = dot + pb[0];
}

// ---------------- launcher ----------------
extern "C" void kernel_launch(void* const* d_in, const int* in_sizes, int n_in,
                              void* d_out, int out_size, void* d_ws, size_t ws_size,
                              hipStream_t stream) {
  const float* x = (const float*)d_in[0];
  const float* emb_W = (const float*)d_in[1];
  const float* emb_b = (const float*)d_in[2];
  const float* Wq = (const float*)d_in[3];
  const float* bq = (const float*)d_in[4];
  const float* Wk = (const float*)d_in[5];
  const float* bk = (const float*)d_in[6];
  const float* Wv = (const float*)d_in[7];
  const float* bv = (const float*)d_in[8];
  const float* Wo = (const float*)d_in[9];
  const float* bo = (const float*)d_in[10];
  const float* fW1 = (const float*)d_in[11];
  const float* fb1 = (const float*)d_in[12];
  const float* fW2 = (const float*)d_in[13];
  const float* fb2 = (const float*)d_in[14];
  const float* ln1g = (const float*)d_in[15];
  const float* ln1b = (const float*)d_in[16];
  const float* ln2g = (const float*)d_in[17];
  const float* ln2b = (const float*)d_in[18];
  const float* cW = (const float*)d_in[19];
  const float* cb = (const float*)d_in[20];
  const float* bng = (const float*)d_in[21];
  const float* bnb = (const float*)d_in[22];
  const float* flng = (const float*)d_in[23];
  const float* flnb = (const float*)d_in[24];
  const float* pW = (const float*)d_in[25];
  const float* pb = (const float*)d_in[26];
  float* out = (float*)d_out;

  // batch-group size from ws_size (try 16, 8, 4, 2, 1) — round-5 footprint
  int CB = 16;
  while (CB > 1) {
    size_t need = 33554432ull + 1966080ull + (size_t)CB * 6943976ull +
                  196608ull + 2048ull;
    if (need * 4 <= ws_size) break;
    CB >>= 1;
  }
  const size_t CBseg = (size_t)CB * 2097152ull;  // CB*4096*512 (bf16 elems)
  const int CBNH = CB * NH;

  float* ws = (float*)d_ws;
  size_t off = 0;
  float* h = ws;                           off += 33554432ull;
  ushort_t* wbase = (ushort_t*)(ws + off); off += 1966080ull;
  ushort_t* WqT = wbase;
  ushort_t* WkT = wbase + 262144;
  ushort_t* WvT = wbase + 524288;
  ushort_t* WoT = wbase + 786432;
  ushort_t* W1b = wbase + 1048576;
  ushort_t* W2b = wbase + 2097152;
  ushort_t* Wcb = wbase + 3145728;
  ushort_t* gArea = (ushort_t*)(ws + off); off += (5ull * CBseg) / 2;
  ushort_t* hb = gArea;
  ushort_t* qb = gArea + CBseg;
  ushort_t* kbuf = gArea + 2 * CBseg;
  ushort_t* vb = gArea + 3 * CBseg;
  ushort_t* ctxb = gArea + 4 * CBseg;
  ushort_t* ybuf = qb;           // spans qb..ctxb (4*CBseg bf16)
  float* convY = (float*)qb;     // spans qb,kbuf (CBseg f32)
  float* Mbuf = ws + off;                  off += (size_t)CB * 32768;
  float* mv = ws + off;                    off += (size_t)CB * 512;
  int* topidx = (int*)(ws + off);          off += (size_t)CB * 384;
  int* idxbuf = (int*)(ws + off);          off += 196608ull;
  float* scbuf = ws + off;                 off += (size_t)CB * 1474560;  // CBNH*SMAX*4096
  float* Zbuf = ws + off;                  off += (size_t)CB * 360;      // CBNH*SMAX
  float* pvpart = ws + off;                off += (size_t)CB * 184320;   // PVJ*CBNH*SMAX*64
  float* mvpart = ws + off;                off += (size_t)CB * 8192;     // CB*16*512

  // embedding
  {
    size_t total = (size_t)NB * 4096 * DM;
    embed_kernel<<<(int)(total / 256), 256, 0, stream>>>(x, emb_W, emb_b, h);
  }

  int L = 4096;
  for (int i = 0; i < 3; ++i) {
    int S = (i == 0) ? 45 : (i == 1) ? 40 : 35;
    int ngroups = NB / CB;
    int Mg = CB * L;
    size_t segL = (size_t)Mg * 512;

    // per-layer weight casts
    castT512<<<1024, 256, 0, stream>>>(Wq + (size_t)i * 262144, WqT);
    castT512<<<1024, 256, 0, stream>>>(Wk + (size_t)i * 262144, WkT);
    castT512<<<1024, 256, 0, stream>>>(Wv + (size_t)i * 262144, WvT);
    castT512<<<1024, 256, 0, stream>>>(Wo + (size_t)i * 262144, WoT);
    cast_bf16<<<1024, 256, 0, stream>>>(fW1 + (size_t)i * 1048576, W1b, 1048576);
    cast_bf16<<<1024, 256, 0, stream>>>(fW2 + (size_t)i * 1048576, W2b, 1048576);
    if (i < 2) cast_convW<<<3072, 256, 0, stream>>>(cW + (size_t)i * 786432, Wcb);

    // JAX randint key
    uint32_t fa, fbk;
    tf2x32(0u, 42u, 0u, (uint32_t)i, &fa, &fbk);
    uint32_t a0, b0, a1, b1;
    tf2x32(fa, fbk, 0u, 2u, &a0, &b0);
    tf2x32(fa, fbk, 1u, 3u, &a1, &b1);
    int n = L * S;
    gen_idx_kernel<<<(n + 255) / 256, 256, 0, stream>>>(idxbuf, b0, b1, n, L - 1);

    // ---- attention per batch group ----
    for (int g = 0; g < ngroups; ++g) {
      float* hg = h + (size_t)g * segL;
      cast_bf16<<<(int)(segL / 1024), 256, 0, stream>>>(hg, hb, segL);
      dim3 gq(4, Mg / 128);
      mfma_gemm<0, 0><<<gq, 256, 0, stream>>>(hb, WqT, bq + i * DM, nullptr, qb,
                                              nullptr, nullptr, 512, 512, 0);
      mfma_gemm<0, 0><<<gq, 256, 0, stream>>>(hb, WkT, bk + i * DM, nullptr, kbuf,
                                              nullptr, nullptr, 512, 512, 0);
      mfma_gemm<0, 0><<<gq, 256, 0, stream>>>(hb, WvT, bv + i * DM, nullptr, vb,
                                              nullptr, nullptr, 512, 512, 0);

      prob_scores_wave<<<(CB * L) / 4, 256, 0, stream>>>(qb, kbuf, idxbuf, Mbuf, L, S);
      topk_kernel<<<CBNH, 256, 0, stream>>>(Mbuf, topidx, L, S);

      qk_scores<<<dim3(L / 256, CBNH), 256, 0, stream>>>(qb, kbuf, topidx, scbuf, L, S);
      softmax_exp<<<CBNH * S, 256, 0, stream>>>(scbuf, Zbuf, L);
      mean_v_partial<<<dim3(CB, L / 256), 256, 0, stream>>>(vb, mvpart, L);
      mean_v_finish<<<CB, 512, 0, stream>>>(mvpart, mv, L, L / 256);
      fill_ctx<<<(int)(segL / 256), 256, 0, stream>>>(ctxb, mv, L);
      pv_partial<<<dim3(PVJ, CBNH), 256, 0, stream>>>(scbuf, vb, pvpart, L, S, CBNH);
      pv_finish<<<(CBNH * S * 64 + 255) / 256, 256, 0, stream>>>(pvpart, Zbuf, topidx,
                                                                 ctxb, L, S, CBNH);

      mfma_gemm<0, 1><<<gq, 256, 0, stream>>>(ctxb, WoT, bo + i * DM, hg, nullptr,
                                              nullptr, nullptr, 512, 512, 0);
    }
    ln_inplace<<<NB * L, 256, 0, stream>>>(h, ln1g + i * DM, ln1b + i * DM);

    // ---- FF row-chunked ----
    int rows = NB * L;
    int R = CB * 4096;
    if (R > rows) R = rows;
    for (int r0 = 0; r0 < rows; r0 += R) {
      float* hr = h + (size_t)r0 * 512;
      size_t rseg = (size_t)R * 512;
      cast_bf16<<<(int)(rseg / 1024), 256, 0, stream>>>(hr, hb, rseg);
      dim3 g1(16, R / 128);
      mfma_gemm<0, 2><<<g1, 256, 0, stream>>>(hb, W1b, fb1 + i * DFF_, nullptr, ybuf,
                                              nullptr, nullptr, 2048, 512, 0);
      dim3 g2(4, R / 128);
      mfma_gemm<0, 1><<<g2, 256, 0, stream>>>(ybuf, W2b, fb2 + i * DM, hr, nullptr,
                                              nullptr, nullptr, 512, 2048, 0);
    }
    ln_inplace<<<NB * L, 256, 0, stream>>>(h, ln2g + i * DM, ln2b + i * DM);

    // ---- conv + maxpool per batch group ----
    if (i < 2) {
      int Lh = L / 2;
      for (int g = 0; g < ngroups; ++g) {
        float* hg = h + (size_t)g * segL;
        cast_bf16<<<(int)(segL / 1024), 256, 0, stream>>>(hg, hb, segL);
        dim3 gc(4, Mg / 128);
        mfma_gemm<1, 3><<<gc, 256, 0, stream>>>(hb, Wcb, cb + i * DM, convY, nullptr,
                                                bng + i * DM, bnb + i * DM, 512, 1536, L);
        size_t tot = (size_t)CB * Lh * 512;
        maxpool_kernel<<<(int)(tot / 256), 256, 0, stream>>>(
            convY, h + (size_t)g * CB * Lh * 512, L);
      }
      L = Lh;
    }
  }

  final_ln_proj<<<NB * 47, 256, 0, stream>>>(h, flng, flnb, pW, pb, out, L);
}

// Round 8
// 5790.345 us; speedup vs baseline: 1.6323x; 1.0099x over previous
//
#include <hip/hip_runtime.h>
#include <cstdint>
#include <math.h>

#define NB 16
#define DM 512
#define NH 8
#define DFF_ 2048
#define SMAX 45
#define PVJ 8

typedef unsigned short ushort_t;
typedef __bf16 bf16x8 __attribute__((ext_vector_type(8)));
typedef float f32x4 __attribute__((ext_vector_type(4)));

// ---------------- bf16 helpers ----------------
__device__ __forceinline__ ushort_t f2b(float f) {  // RNE f32 -> bf16 bits
  uint32_t u = __float_as_uint(f);
  uint32_t r = (u + 0x7FFFu + ((u >> 16) & 1u)) >> 16;
  return (ushort_t)r;
}
__device__ __forceinline__ float bu2f(ushort_t x) {
  return __uint_as_float((uint32_t)x << 16);
}
__device__ __forceinline__ float b2f_lo(uint32_t u) { return __uint_as_float(u << 16); }
__device__ __forceinline__ float b2f_hi(uint32_t u) { return __uint_as_float(u & 0xFFFF0000u); }

// ---------------- threefry2x32 (JAX-compatible) ----------------
__host__ __device__ inline void tf2x32(uint32_t k0, uint32_t k1,
                                       uint32_t x0, uint32_t x1,
                                       uint32_t* o0, uint32_t* o1) {
  uint32_t ks0 = k0, ks1 = k1, ks2 = k0 ^ k1 ^ 0x1BD11BDAu;
  x0 += ks0; x1 += ks1;
#define TF_RND(r) { x0 += x1; x1 = (x1 << (r)) | (x1 >> (32 - (r))); x1 ^= x0; }
  TF_RND(13) TF_RND(15) TF_RND(26) TF_RND(6)
  x0 += ks1; x1 += ks2 + 1u;
  TF_RND(17) TF_RND(29) TF_RND(16) TF_RND(24)
  x0 += ks2; x1 += ks0 + 2u;
  TF_RND(13) TF_RND(15) TF_RND(26) TF_RND(6)
  x0 += ks0; x1 += ks1 + 3u;
  TF_RND(17) TF_RND(29) TF_RND(16) TF_RND(24)
  x0 += ks1; x1 += ks2 + 4u;
  TF_RND(13) TF_RND(15) TF_RND(26) TF_RND(6)
  x0 += ks2; x1 += ks0 + 5u;
#undef TF_RND
  *o0 = x0; *o1 = x1;
}

__global__ void gen_idx_kernel(int* __restrict__ idx, uint32_t k0, uint32_t k1,
                               int n, int mask) {
  int j = blockIdx.x * 256 + threadIdx.x;
  if (j >= n) return;
  int half = n >> 1;
  uint32_t o0, o1;
  if (j < half) {
    tf2x32(k0, k1, (uint32_t)j, (uint32_t)(j + half), &o0, &o1);
    idx[j] = (int)(o0 & (uint32_t)mask);
  } else {
    tf2x32(k0, k1, (uint32_t)(j - half), (uint32_t)j, &o0, &o1);
    idx[j] = (int)(o1 & (uint32_t)mask);
  }
}

// ---------------- block reduce helpers (256 threads, wave64) ----------------
__device__ inline float blk_reduce_sum(float v) {
  __shared__ float s[4];
  for (int o = 32; o > 0; o >>= 1) v += __shfl_down(v, o);
  int lane = threadIdx.x & 63, w = threadIdx.x >> 6;
  if (lane == 0) s[w] = v;
  __syncthreads();
  float r = s[0] + s[1] + s[2] + s[3];
  __syncthreads();
  return r;
}

// ---------------- embedding ----------------
__global__ void embed_kernel(const float* __restrict__ x, const float* __restrict__ W,
                             const float* __restrict__ bias, float* __restrict__ h) {
  size_t gid = (size_t)blockIdx.x * 256 + threadIdx.x;
  int o = (int)(gid & 511);
  size_t bl = gid >> 9;
  const float* xr = x + bl * 7;
  float acc = bias[o];
#pragma unroll
  for (int i = 0; i < 7; ++i) acc += xr[i] * W[i * 512 + o];
  h[gid] = acc;
}

// ---------------- cast kernels ----------------
__global__ void cast_bf16(const float* __restrict__ src, ushort_t* __restrict__ dst,
                          size_t n) {
  size_t i = ((size_t)blockIdx.x * 256 + threadIdx.x) * 4;
  if (i >= n) return;
  float4 v = *(const float4*)(src + i);
  ushort4 o;
  o.x = f2b(v.x); o.y = f2b(v.y); o.z = f2b(v.z); o.w = f2b(v.w);
  *(ushort4*)(dst + i) = o;
}

// Bt[n*512+k] = bf16(W[k*512+n])   (512x512)
__global__ void castT512(const float* __restrict__ W, ushort_t* __restrict__ Bt) {
  int gid = blockIdx.x * 256 + threadIdx.x;
  int n = gid >> 9, k = gid & 511;
  Bt[gid] = f2b(W[(size_t)k * 512 + n]);
}

// Bt[n*1536 + dt*512 + i] = bf16(convW[n][i][dt])
__global__ void cast_convW(const float* __restrict__ W, ushort_t* __restrict__ Bt) {
  int gid = blockIdx.x * 256 + threadIdx.x;
  int n = gid / 1536, k = gid - n * 1536;
  int dt = k >> 9, ii = k & 511;
  Bt[gid] = f2b(W[((size_t)n * 512 + ii) * 3 + dt]);
}

// ---------------- bf16 MFMA GEMM (m97 structure) ----------------
__device__ __forceinline__ float gelu_exact(float c) {
  return 0.5f * c * (1.0f + erff(c * 0.70710678118654752f));
}

template <int CONVMODE, int EPI>
__global__ __launch_bounds__(256) void mfma_gemm(
    const ushort_t* __restrict__ A, const ushort_t* __restrict__ Bt,
    const float* __restrict__ bias, float* __restrict__ Cf,
    ushort_t* __restrict__ Cb, const float* __restrict__ bng,
    const float* __restrict__ bnb, int N, int K, int L) {
  __shared__ __align__(16) ushort_t As[128 * 64];
  __shared__ __align__(16) ushort_t Bs[128 * 64];
  const int tid = threadIdx.x;
  const int lane = tid & 63;
  const int wid = tid >> 6;
  const int wr = wid >> 1, wc = wid & 1;
  const int bm = blockIdx.y, bn = blockIdx.x;
  const int ln = lane & 15, lh = lane >> 4;

  f32x4 acc[4][4] = {};

  for (int k0 = 0; k0 < K; k0 += 64) {
    __syncthreads();
#pragma unroll
    for (int it = 0; it < 4; ++it) {
      int c = it * 256 + tid;
      int row = c >> 3, kc = (c & 7) * 8;
      size_t ga;
      if (CONVMODE) {
        int m = bm * 128 + row;
        int b = m / L, tpos = m - b * L;
        int k = k0 + kc;
        int dt = k >> 9, ii = k & 511;
        int tr2 = tpos + dt - 1;
        if (tr2 < 0) tr2 += L;
        if (tr2 >= L) tr2 -= L;
        ga = ((size_t)(b * L + tr2)) * 512 + ii;
      } else {
        ga = (size_t)(bm * 128 + row) * K + k0 + kc;
      }
      __builtin_amdgcn_global_load_lds(
          (const __attribute__((address_space(1))) void*)(A + ga),
          (__attribute__((address_space(3))) void*)(As + c * 8), 16, 0, 0);
      size_t gb = (size_t)(bn * 128 + row) * K + k0 + kc;
      __builtin_amdgcn_global_load_lds(
          (const __attribute__((address_space(1))) void*)(Bt + gb),
          (__attribute__((address_space(3))) void*)(Bs + c * 8), 16, 0, 0);
    }
    __syncthreads();
#pragma unroll
    for (int kk = 0; kk < 2; ++kk) {
      bf16x8 af[4], bf_[4];
#pragma unroll
      for (int m = 0; m < 4; ++m)
        af[m] = *(const bf16x8*)&As[(wr * 64 + m * 16 + ln) * 64 + kk * 32 + lh * 8];
#pragma unroll
      for (int n = 0; n < 4; ++n)
        bf_[n] = *(const bf16x8*)&Bs[(wc * 64 + n * 16 + ln) * 64 + kk * 32 + lh * 8];
#pragma unroll
      for (int m = 0; m < 4; ++m)
#pragma unroll
        for (int n = 0; n < 4; ++n)
          acc[m][n] =
              __builtin_amdgcn_mfma_f32_16x16x32_bf16(af[m], bf_[n], acc[m][n], 0, 0, 0);
    }
  }

  const float bnscale = 0.9999950000374996f;  // 1/sqrt(1+1e-5)
#pragma unroll
  for (int m = 0; m < 4; ++m) {
    int row = bm * 128 + wr * 64 + m * 16 + lh * 4;
#pragma unroll
    for (int n = 0; n < 4; ++n) {
      int col = bn * 128 + wc * 64 + n * 16 + ln;
      float bsv = bias[col];
#pragma unroll
      for (int r = 0; r < 4; ++r) {
        float cval = acc[m][n][r] + bsv;
        size_t oi = (size_t)(row + r) * N + col;
        if (EPI == 0) {
          Cb[oi] = f2b(cval);
        } else if (EPI == 1) {
          Cf[oi] += cval;
        } else if (EPI == 2) {
          Cb[oi] = f2b(gelu_exact(cval));
        } else {
          float c2 = cval * bnscale * bng[col] + bnb[col];
          Cf[oi] = c2 > 0.0f ? c2 : expm1f(c2);
        }
      }
    }
  }
}

// ---------------- LN (in-place, row = 512) ----------------
__global__ __launch_bounds__(256) void ln_inplace(float* __restrict__ h,
                                                  const float* __restrict__ g,
                                                  const float* __restrict__ b) {
  size_t row = blockIdx.x;
  float* hr = h + row * 512;
  int t = threadIdx.x;
  float x0 = hr[t], x1 = hr[t + 256];
  float mean = blk_reduce_sum(x0 + x1) * (1.0f / 512.0f);
  float d0 = x0 - mean, d1 = x1 - mean;
  float var = blk_reduce_sum(d0 * d0 + d1 * d1) * (1.0f / 512.0f);
  float rstd = rsqrtf(var + 1e-5f);
  hr[t] = d0 * rstd * g[t] + b[t];
  hr[t + 256] = d1 * rstd * g[t + 256] + b[t + 256];
}

// ---------------- prob-sparse M scores: one wave per (b,l), coalesced 1KB K rows ----
__global__ __launch_bounds__(256) void prob_scores_wave(const ushort_t* __restrict__ q,
                                                        const ushort_t* __restrict__ k,
                                                        const int* __restrict__ idx,
                                                        float* __restrict__ Mout,
                                                        int L, int S) {
  int wv = (blockIdx.x << 2) + ((threadIdx.x) >> 6);  // wave id over CB*L
  int lane = threadIdx.x & 63;
  int l = wv % L;
  int b = wv / L;
  const ushort_t* qr = q + ((size_t)(b * L + l)) * 512 + lane * 8;
  uint4 qu = *(const uint4*)qr;
  float qf[8];
  qf[0] = b2f_lo(qu.x); qf[1] = b2f_hi(qu.x);
  qf[2] = b2f_lo(qu.y); qf[3] = b2f_hi(qu.y);
  qf[4] = b2f_lo(qu.z); qf[5] = b2f_hi(qu.z);
  qf[6] = b2f_lo(qu.w); qf[7] = b2f_hi(qu.w);
  const int* il = idx + l * S;
  const ushort_t* kb = k + (size_t)b * L * 512 + lane * 8;
  float m = -INFINITY, ssum = 0.0f;
  for (int s = 0; s < S; ++s) {
    int j = il[s];
    uint4 ku = *(const uint4*)(kb + (size_t)j * 512);
    float dot = qf[0] * b2f_lo(ku.x) + qf[1] * b2f_hi(ku.x) +
                qf[2] * b2f_lo(ku.y) + qf[3] * b2f_hi(ku.y) +
                qf[4] * b2f_lo(ku.z) + qf[5] * b2f_hi(ku.z) +
                qf[6] * b2f_lo(ku.w) + qf[7] * b2f_hi(ku.w);
    dot += __shfl_xor(dot, 1);
    dot += __shfl_xor(dot, 2);
    dot += __shfl_xor(dot, 4);
    m = fmaxf(m, dot);
    ssum += dot;
  }
  if ((lane & 7) == 0) {
    int hh = lane >> 3;
    Mout[((size_t)(b * 8 + hh)) * L + l] = m - ssum / (float)L;
  }
}

// ---------------- top-k: register-cached iterative argmax ----------------
// lower index wins ties (matches lax.top_k). Per iteration: wave shfl reduce
// + 4-way cross-wave merge; only the winning chunk owner rescans.
__global__ __launch_bounds__(256) void topk_kernel(const float* __restrict__ Mbuf,
                                                   int* __restrict__ top_idx,
                                                   int L, int S) {
  int bh = blockIdx.x;
  __shared__ float vals[4096];
  __shared__ float rw[4];
  __shared__ int ri2[4];
  const float* Mr = Mbuf + (size_t)bh * L;
  int t = threadIdx.x;
  int lane = t & 63, w = t >> 6;
  int chunk = L >> 8;  // L/256
  int base = t * chunk;
  for (int j = t; j < L; j += 256) vals[j] = Mr[j];
  __syncthreads();
  float lmax = -INFINITY;
  int lidx = 1 << 30;
  for (int i = 0; i < chunk; ++i) {
    float vv = vals[base + i];
    if (vv > lmax || (vv == lmax && base + i < lidx)) { lmax = vv; lidx = base + i; }
  }
  for (int it = 0; it < S; ++it) {
    float v2 = lmax;
    int i2 = lidx;
#pragma unroll
    for (int o2 = 1; o2 < 64; o2 <<= 1) {
      float ov = __shfl_xor(v2, o2);
      int oi = __shfl_xor(i2, o2);
      if (ov > v2 || (ov == v2 && oi < i2)) { v2 = ov; i2 = oi; }
    }
    if (lane == 0) { rw[w] = v2; ri2[w] = i2; }
    __syncthreads();
    float bv = rw[0];
    int bi = ri2[0];
#pragma unroll
    for (int ww = 1; ww < 4; ++ww) {
      float ov = rw[ww];
      int oi = ri2[ww];
      if (ov > bv || (ov == bv && oi < bi)) { bv = ov; bi = oi; }
    }
    if (t == 0) top_idx[bh * S + it] = bi;
    if (bi >= base && bi < base + chunk) {
      vals[bi] = -INFINITY;
      lmax = -INFINITY;
      lidx = 1 << 30;
      for (int i = 0; i < chunk; ++i) {
        float vv = vals[base + i];
        if (vv > lmax || (vv == lmax && base + i < lidx)) { lmax = vv; lidx = base + i; }
      }
    }
    __syncthreads();
  }
}

// ---------------- mean of V: stage 1 (coalesced column partial sums) ----------------
__global__ __launch_bounds__(256) void mean_v_partial(const ushort_t* __restrict__ v,
                                                      float* __restrict__ part, int L) {
  int b = blockIdx.x;
  int chunk = blockIdx.y;
  int t = threadIdx.x;
  int c = t * 2;
  const ushort_t* base = v + ((size_t)b * L + (size_t)chunk * 256) * 512 + c;
  float a0 = 0.0f, a1 = 0.0f;
#pragma unroll 8
  for (int r = 0; r < 256; ++r) {
    uint32_t u = *(const uint32_t*)(base + (size_t)r * 512);
    a0 += b2f_lo(u);
    a1 += b2f_hi(u);
  }
  float* p = part + ((size_t)b * 16 + chunk) * 512 + c;
  p[0] = a0;
  p[1] = a1;
}

// ---------------- mean of V: stage 2 ----------------
__global__ void mean_v_finish(const float* __restrict__ part, float* __restrict__ mv,
                              int L, int nchunks) {
  int b = blockIdx.x;
  int c = threadIdx.x;  // 512 threads
  float s = 0.0f;
  for (int k = 0; k < nchunks; ++k) s += part[((size_t)b * 16 + k) * 512 + c];
  mv[b * 512 + c] = s / (float)L;
}

// ---------------- fill ctx (bf16) with broadcast mean ----------------
__global__ void fill_ctx(ushort_t* __restrict__ ctx, const float* __restrict__ mv,
                         int L) {
  size_t gid = (size_t)blockIdx.x * 256 + threadIdx.x;  // CB*L*512
  int c = (int)(gid & 511);
  size_t bl = gid >> 9;
  int b = (int)(bl / (size_t)L);
  ctx[gid] = f2b(mv[b * 512 + c]);
}

// ---------------- fused flash attention over selected queries ----------------
// grid (PVJ, CBNH). Each block: keys [js*L/PVJ, (js+1)*L/PVJ) for all S queries
// of one bh. Online softmax; partials (m, z, O-unnormalized) written per split.
__global__ __launch_bounds__(256) void flash_attn(const ushort_t* __restrict__ q,
                                                  const ushort_t* __restrict__ k,
                                                  const ushort_t* __restrict__ v,
                                                  const int* __restrict__ top_idx,
                                                  float* __restrict__ pm,
                                                  float* __restrict__ pz,
                                                  float* __restrict__ po,
                                                  int L, int S, int CBNH) {
  __shared__ float qs[SMAX * 64];
  __shared__ float pt[SMAX * 64];
  __shared__ float srow[SMAX];
  int bh = blockIdx.y, js = blockIdx.x;
  int hh = bh & 7, b = bh >> 3;
  int t = threadIdx.x;
  int lane = t & 63, w = t >> 6;
  for (int e = t; e < S * 64; e += 256) {
    int u = e >> 6, d = e & 63;
    int l = top_idx[bh * S + u];
    qs[e] = bu2f(q[((size_t)(b * L + l)) * 512 + hh * 64 + d]);
  }
  __syncthreads();
  int jlen = L / PVJ, j0 = js * jlen;
  float m[12], z[12], oacc[12];
#pragma unroll
  for (int mi = 0; mi < 12; ++mi) { m[mi] = -INFINITY; z[mi] = 0.0f; oacc[mi] = 0.0f; }

  for (int jt = 0; jt < jlen; jt += 64) {
    // stage A: lane = key; K row in registers; scores + online max + P -> LDS
    const ushort_t* kr = k + ((size_t)(b * L + j0 + jt + lane)) * 512 + hh * 64;
    uint4 kreg[8];
#pragma unroll
    for (int c = 0; c < 8; ++c) kreg[c] = ((const uint4*)kr)[c];
#pragma unroll
    for (int mi = 0; mi < 12; ++mi) {
      int u = w + mi * 4;
      if (u < S) {
        const float* qu = qs + u * 64;
        float dot = 0.0f;
#pragma unroll
        for (int c = 0; c < 8; ++c) {
          uint4 ku = kreg[c];
          const float* q8 = qu + c * 8;
          dot += q8[0] * b2f_lo(ku.x) + q8[1] * b2f_hi(ku.x) +
                 q8[2] * b2f_lo(ku.y) + q8[3] * b2f_hi(ku.y) +
                 q8[4] * b2f_lo(ku.z) + q8[5] * b2f_hi(ku.z) +
                 q8[6] * b2f_lo(ku.w) + q8[7] * b2f_hi(ku.w);
        }
        dot *= 0.125f;  // 1/sqrt(64)
        float tmax = dot;
#pragma unroll
        for (int o2 = 1; o2 < 64; o2 <<= 1) tmax = fmaxf(tmax, __shfl_xor(tmax, o2));
        float nm = fmaxf(m[mi], tmax);
        float sc2 = __expf(m[mi] - nm);  // first tile: exp(-inf) = 0
        float P = __expf(dot - nm);
        float ps = P;
#pragma unroll
        for (int o2 = 1; o2 < 64; o2 <<= 1) ps += __shfl_xor(ps, o2);
        z[mi] = z[mi] * sc2 + ps;
        m[mi] = nm;
        pt[u * 64 + lane] = P;
        if (lane == 0) srow[u] = sc2;
      }
    }
    __syncthreads();
    // stage B: lane = d; rescale O, accumulate P*V (coalesced V rows)
#pragma unroll
    for (int mi = 0; mi < 12; ++mi) {
      int u = w + mi * 4;
      if (u < S) oacc[mi] *= srow[u];
    }
    for (int jb = 0; jb < 64; jb += 4) {
      float vv[4];
#pragma unroll
      for (int r = 0; r < 4; ++r)
        vv[r] = bu2f(v[((size_t)(b * L + j0 + jt + jb + r)) * 512 + hh * 64 + lane]);
#pragma unroll
      for (int mi = 0; mi < 12; ++mi) {
        int u = w + mi * 4;
        if (u < S) {
          const float* p4 = &pt[u * 64 + jb];
          oacc[mi] += p4[0] * vv[0] + p4[1] * vv[1] + p4[2] * vv[2] + p4[3] * vv[3];
        }
      }
    }
    __syncthreads();
  }
  size_t base = (size_t)js * CBNH + bh;
#pragma unroll
  for (int mi = 0; mi < 12; ++mi) {
    int u = w + mi * 4;
    if (u < S) {
      po[(base * SMAX + u) * 64 + lane] = oacc[mi];
      if (lane == 0) { pm[base * SMAX + u] = m[mi]; pz[base * SMAX + u] = z[mi]; }
    }
  }
}

// ---------------- combine flash partials, /Z, scatter into ctx ----------------
__global__ void flash_finish(const float* __restrict__ pm, const float* __restrict__ pz,
                             const float* __restrict__ po, const int* __restrict__ top_idx,
                             ushort_t* __restrict__ ctx, int L, int S, int CBNH) {
  int gid = blockIdx.x * 256 + threadIdx.x;  // over CBNH*S*64
  if (gid >= CBNH * S * 64) return;
  int d = gid & 63;
  int r = gid >> 6;  // bh*S + u
  int u = r % S, bh = r / S;
  int hh = bh & 7, b = bh >> 3;
  float M = -INFINITY;
#pragma unroll
  for (int js = 0; js < PVJ; ++js)
    M = fmaxf(M, pm[((size_t)js * CBNH + bh) * SMAX + u]);
  float Z = 0.0f, O = 0.0f;
#pragma unroll
  for (int js = 0; js < PVJ; ++js) {
    size_t pi = ((size_t)js * CBNH + bh) * SMAX + u;
    float e = __expf(pm[pi] - M);
    Z += pz[pi] * e;
    O += po[pi * 64 + d] * e;
  }
  int l = top_idx[bh * S + u];
  ctx[((size_t)(b * L + l)) * 512 + hh * 64 + d] = f2b(O / Z);
}

// ---------------- maxpool window 3 stride 2 ----------------
__global__ void maxpool_kernel(const float* __restrict__ y, float* __restrict__ hout,
                               int L) {
  size_t gid = (size_t)blockIdx.x * 256 + threadIdx.x;  // CB*(L/2)*512
  int Lh = L >> 1;
  int o = (int)(gid & 511);
  size_t bj = gid >> 9;
  int j = (int)(bj % (size_t)Lh);
  int b = (int)(bj / (size_t)Lh);
  const float* base = y + ((size_t)(b * L + 2 * j)) * 512 + o;
  float mx = base[0];
  if (j > 0) mx = fmaxf(mx, base[-512]);
  mx = fmaxf(mx, base[512]);
  hout[gid] = mx;
}

// ---------------- final LN + projection ----------------
__global__ __launch_bounds__(256) void final_ln_proj(const float* __restrict__ h,
                                                     const float* __restrict__ g,
                                                     const float* __restrict__ bb,
                                                     const float* __restrict__ pw,
                                                     const float* __restrict__ pb,
                                                     float* __restrict__ out, int L) {
  int b = blockIdx.x / 47, l = blockIdx.x % 47;
  const float* hr = h + ((size_t)(b * L + l)) * 512;
  int t = threadIdx.x;
  float x0 = hr[t], x1 = hr[t + 256];
  float mean = blk_reduce_sum(x0 + x1) * (1.0f / 512.0f);
  float d0 = x0 - mean, d1 = x1 - mean;
  float var = blk_reduce_sum(d0 * d0 + d1 * d1) * (1.0f / 512.0f);
  float rstd = rsqrtf(var + 1e-5f);
  float y0 = d0 * rstd * g[t] + bb[t];
  float y1 = d1 * rstd * g[t + 256] + bb[t + 256];
  float dot = blk_reduce_sum(y0 * pw[t] + y1 * pw[t + 256]);
  if (t == 0) out[b * 47 + l] = dot + pb[0];
}

// ---------------- launcher ----------------
extern "C" void kernel_launch(void* const* d_in, const int* in_sizes, int n_in,
                              void* d_out, int out_size, void* d_ws, size_t ws_size,
                              hipStream_t stream) {
  const float* x = (const float*)d_in[0];
  const float* emb_W = (const float*)d_in[1];
  const float* emb_b = (const float*)d_in[2];
  const float* Wq = (const float*)d_in[3];
  const float* bq = (const float*)d_in[4];
  const float* Wk = (const float*)d_in[5];
  const float* bk = (const float*)d_in[6];
  const float* Wv = (const float*)d_in[7];
  const float* bv = (const float*)d_in[8];
  const float* Wo = (const float*)d_in[9];
  const float* bo = (const float*)d_in[10];
  const float* fW1 = (const float*)d_in[11];
  const float* fb1 = (const float*)d_in[12];
  const float* fW2 = (const float*)d_in[13];
  const float* fb2 = (const float*)d_in[14];
  const float* ln1g = (const float*)d_in[15];
  const float* ln1b = (const float*)d_in[16];
  const float* ln2g = (const float*)d_in[17];
  const float* ln2b = (const float*)d_in[18];
  const float* cW = (const float*)d_in[19];
  const float* cb = (const float*)d_in[20];
  const float* bng = (const float*)d_in[21];
  const float* bnb = (const float*)d_in[22];
  const float* flng = (const float*)d_in[23];
  const float* flnb = (const float*)d_in[24];
  const float* pW = (const float*)d_in[25];
  const float* pb = (const float*)d_in[26];
  float* out = (float*)d_out;

  // batch-group size from ws_size (try 16, 8, 4, 2, 1)
  int CB = 16;
  while (CB > 1) {
    size_t need = 35719168ull + (size_t)CB * 5474816ull;
    if (need * 4 <= ws_size) break;
    CB >>= 1;
  }
  const size_t CBseg = (size_t)CB * 2097152ull;  // CB*4096*512 (bf16 elems)
  const int CBNH = CB * NH;

  float* ws = (float*)d_ws;
  size_t off = 0;
  float* h = ws;                           off += 33554432ull;
  ushort_t* wbase = (ushort_t*)(ws + off); off += 1966080ull;
  ushort_t* WqT = wbase;
  ushort_t* WkT = wbase + 262144;
  ushort_t* WvT = wbase + 524288;
  ushort_t* WoT = wbase + 786432;
  ushort_t* W1b = wbase + 1048576;
  ushort_t* W2b = wbase + 2097152;
  ushort_t* Wcb = wbase + 3145728;
  ushort_t* gArea = (ushort_t*)(ws + off); off += (5ull * CBseg) / 2;
  ushort_t* hb = gArea;
  ushort_t* qb = gArea + CBseg;
  ushort_t* kbuf = gArea + 2 * CBseg;
  ushort_t* vb = gArea + 3 * CBseg;
  ushort_t* ctxb = gArea + 4 * CBseg;
  ushort_t* ybuf = qb;           // spans qb..ctxb (4*CBseg bf16)
  float* convY = (float*)qb;     // spans qb,kbuf (CBseg f32)
  float* Mbuf = ws + off;                  off += (size_t)CB * 32768;
  float* mv = ws + off;                    off += (size_t)CB * 512;
  int* topidx = (int*)(ws + off);          off += (size_t)CB * 384;
  int* idxbuf = (int*)(ws + off);          off += 196608ull;
  float* pmb = ws + off;                   off += (size_t)CB * 2880;    // PVJ*CBNH*SMAX
  float* pzb = ws + off;                   off += (size_t)CB * 2880;
  float* pob = ws + off;                   off += (size_t)CB * 184320;  // PVJ*CBNH*SMAX*64
  float* mvpart = ws + off;                off += (size_t)CB * 8192;    // CB*16*512

  // embedding
  {
    size_t total = (size_t)NB * 4096 * DM;
    embed_kernel<<<(int)(total / 256), 256, 0, stream>>>(x, emb_W, emb_b, h);
  }

  int L = 4096;
  for (int i = 0; i < 3; ++i) {
    int S = (i == 0) ? 45 : (i == 1) ? 40 : 35;
    int ngroups = NB / CB;
    int Mg = CB * L;
    size_t segL = (size_t)Mg * 512;

    // per-layer weight casts
    castT512<<<1024, 256, 0, stream>>>(Wq + (size_t)i * 262144, WqT);
    castT512<<<1024, 256, 0, stream>>>(Wk + (size_t)i * 262144, WkT);
    castT512<<<1024, 256, 0, stream>>>(Wv + (size_t)i * 262144, WvT);
    castT512<<<1024, 256, 0, stream>>>(Wo + (size_t)i * 262144, WoT);
    cast_bf16<<<1024, 256, 0, stream>>>(fW1 + (size_t)i * 1048576, W1b, 1048576);
    cast_bf16<<<1024, 256, 0, stream>>>(fW2 + (size_t)i * 1048576, W2b, 1048576);
    if (i < 2) cast_convW<<<3072, 256, 0, stream>>>(cW + (size_t)i * 786432, Wcb);

    // JAX randint key
    uint32_t fa, fbk;
    tf2x32(0u, 42u, 0u, (uint32_t)i, &fa, &fbk);
    uint32_t a0, b0, a1, b1;
    tf2x32(fa, fbk, 0u, 2u, &a0, &b0);
    tf2x32(fa, fbk, 1u, 3u, &a1, &b1);
    int n = L * S;
    gen_idx_kernel<<<(n + 255) / 256, 256, 0, stream>>>(idxbuf, b0, b1, n, L - 1);

    // ---- attention per batch group ----
    for (int g = 0; g < ngroups; ++g) {
      float* hg = h + (size_t)g * segL;
      cast_bf16<<<(int)(segL / 1024), 256, 0, stream>>>(hg, hb, segL);
      dim3 gq(4, Mg / 128);
      mfma_gemm<0, 0><<<gq, 256, 0, stream>>>(hb, WqT, bq + i * DM, nullptr, qb,
                                              nullptr, nullptr, 512, 512, 0);
      mfma_gemm<0, 0><<<gq, 256, 0, stream>>>(hb, WkT, bk + i * DM, nullptr, kbuf,
                                              nullptr, nullptr, 512, 512, 0);
      mfma_gemm<0, 0><<<gq, 256, 0, stream>>>(hb, WvT, bv + i * DM, nullptr, vb,
                                              nullptr, nullptr, 512, 512, 0);

      prob_scores_wave<<<(CB * L) / 4, 256, 0, stream>>>(qb, kbuf, idxbuf, Mbuf, L, S);
      topk_kernel<<<CBNH, 256, 0, stream>>>(Mbuf, topidx, L, S);

      mean_v_partial<<<dim3(CB, L / 256), 256, 0, stream>>>(vb, mvpart, L);
      mean_v_finish<<<CB, 512, 0, stream>>>(mvpart, mv, L, L / 256);
      fill_ctx<<<(int)(segL / 256), 256, 0, stream>>>(ctxb, mv, L);
      flash_attn<<<dim3(PVJ, CBNH), 256, 0, stream>>>(qb, kbuf, vb, topidx,
                                                      pmb, pzb, pob, L, S, CBNH);
      flash_finish<<<(CBNH * S * 64 + 255) / 256, 256, 0, stream>>>(
          pmb, pzb, pob, topidx, ctxb, L, S, CBNH);

      mfma_gemm<0, 1><<<gq, 256, 0, stream>>>(ctxb, WoT, bo + i * DM, hg, nullptr,
                                              nullptr, nullptr, 512, 512, 0);
    }
    ln_inplace<<<NB * L, 256, 0, stream>>>(h, ln1g + i * DM, ln1b + i * DM);

    // ---- FF row-chunked ----
    int rows = NB * L;
    int R = CB * 4096;
    if (R > rows) R = rows;
    for (int r0 = 0; r0 < rows; r0 += R) {
      float* hr = h + (size_t)r0 * 512;
      size_t rseg = (size_t)R * 512;
      cast_bf16<<<(int)(rseg / 1024), 256, 0, stream>>>(hr, hb, rseg);
      dim3 g1(16, R / 128);
      mfma_gemm<0, 2><<<g1, 256, 0, stream>>>(hb, W1b, fb1 + i * DFF_, nullptr, ybuf,
                                              nullptr, nullptr, 2048, 512, 0);
      dim3 g2(4, R / 128);
      mfma_gemm<0, 1><<<g2, 256, 0, stream>>>(ybuf, W2b, fb2 + i * DM, hr, nullptr,
                                              nullptr, nullptr, 512, 2048, 0);
    }
    ln_inplace<<<NB * L, 256, 0, stream>>>(h, ln2g + i * DM, ln2b + i * DM);

    // ---- conv + maxpool per batch group ----
    if (i < 2) {
      int Lh = L / 2;
      for (int g = 0; g < ngroups; ++g) {
        float* hg = h + (size_t)g * segL;
        cast_bf16<<<(int)(segL / 1024), 256, 0, stream>>>(hg, hb, segL);
        dim3 gc(4, Mg / 128);
        mfma_gemm<1, 3><<<gc, 256, 0, stream>>>(hb, Wcb, cb + i * DM, convY, nullptr,
                                                bng + i * DM, bnb + i * DM, 512, 1536, L);
        size_t tot = (size_t)CB * Lh * 512;
        maxpool_kernel<<<(int)(tot / 256), 256, 0, stream>>>(
            convY, h + (size_t)g * CB * Lh * 512, L);
      }
      L = Lh;
    }
  }

  final_ln_proj<<<NB * 47, 256, 0, stream>>>(h, flng, flnb, pW, pb, out, L);
}

// Round 9
// 5462.077 us; speedup vs baseline: 1.7304x; 1.0601x over previous
//
#include <hip/hip_runtime.h>
#include <cstdint>
#include <math.h>

#define NB 16
#define DM 512
#define NH 8
#define DFF_ 2048
#define SMAX 45
#define FJMAX 32

typedef unsigned short ushort_t;
typedef __bf16 bf16x8 __attribute__((ext_vector_type(8)));
typedef float f32x4 __attribute__((ext_vector_type(4)));

// ---------------- bf16 helpers ----------------
__device__ __forceinline__ ushort_t f2b(float f) {  // RNE f32 -> bf16 bits
  uint32_t u = __float_as_uint(f);
  uint32_t r = (u + 0x7FFFu + ((u >> 16) & 1u)) >> 16;
  return (ushort_t)r;
}
__device__ __forceinline__ float bu2f(ushort_t x) {
  return __uint_as_float((uint32_t)x << 16);
}
__device__ __forceinline__ float b2f_lo(uint32_t u) { return __uint_as_float(u << 16); }
__device__ __forceinline__ float b2f_hi(uint32_t u) { return __uint_as_float(u & 0xFFFF0000u); }

// ---------------- threefry2x32 (JAX-compatible) ----------------
__host__ __device__ inline void tf2x32(uint32_t k0, uint32_t k1,
                                       uint32_t x0, uint32_t x1,
                                       uint32_t* o0, uint32_t* o1) {
  uint32_t ks0 = k0, ks1 = k1, ks2 = k0 ^ k1 ^ 0x1BD11BDAu;
  x0 += ks0; x1 += ks1;
#define TF_RND(r) { x0 += x1; x1 = (x1 << (r)) | (x1 >> (32 - (r))); x1 ^= x0; }
  TF_RND(13) TF_RND(15) TF_RND(26) TF_RND(6)
  x0 += ks1; x1 += ks2 + 1u;
  TF_RND(17) TF_RND(29) TF_RND(16) TF_RND(24)
  x0 += ks2; x1 += ks0 + 2u;
  TF_RND(13) TF_RND(15) TF_RND(26) TF_RND(6)
  x0 += ks0; x1 += ks1 + 3u;
  TF_RND(17) TF_RND(29) TF_RND(16) TF_RND(24)
  x0 += ks1; x1 += ks2 + 4u;
  TF_RND(13) TF_RND(15) TF_RND(26) TF_RND(6)
  x0 += ks2; x1 += ks0 + 5u;
#undef TF_RND
  *o0 = x0; *o1 = x1;
}

__global__ void gen_idx_kernel(int* __restrict__ idx, uint32_t k0, uint32_t k1,
                               int n, int mask) {
  int j = blockIdx.x * 256 + threadIdx.x;
  if (j >= n) return;
  int half = n >> 1;
  uint32_t o0, o1;
  if (j < half) {
    tf2x32(k0, k1, (uint32_t)j, (uint32_t)(j + half), &o0, &o1);
    idx[j] = (int)(o0 & (uint32_t)mask);
  } else {
    tf2x32(k0, k1, (uint32_t)(j - half), (uint32_t)j, &o0, &o1);
    idx[j] = (int)(o1 & (uint32_t)mask);
  }
}

// ---------------- block reduce helpers (256 threads, wave64) ----------------
__device__ inline float blk_reduce_sum(float v) {
  __shared__ float s[4];
  for (int o = 32; o > 0; o >>= 1) v += __shfl_down(v, o);
  int lane = threadIdx.x & 63, w = threadIdx.x >> 6;
  if (lane == 0) s[w] = v;
  __syncthreads();
  float r = s[0] + s[1] + s[2] + s[3];
  __syncthreads();
  return r;
}

// ---------------- embedding ----------------
__global__ void embed_kernel(const float* __restrict__ x, const float* __restrict__ W,
                             const float* __restrict__ bias, float* __restrict__ h) {
  size_t gid = (size_t)blockIdx.x * 256 + threadIdx.x;
  int o = (int)(gid & 511);
  size_t bl = gid >> 9;
  const float* xr = x + bl * 7;
  float acc = bias[o];
#pragma unroll
  for (int i = 0; i < 7; ++i) acc += xr[i] * W[i * 512 + o];
  h[gid] = acc;
}

// ---------------- cast kernels ----------------
__global__ void cast_bf16(const float* __restrict__ src, ushort_t* __restrict__ dst,
                          size_t n) {
  size_t i = ((size_t)blockIdx.x * 256 + threadIdx.x) * 4;
  if (i >= n) return;
  float4 v = *(const float4*)(src + i);
  ushort4 o;
  o.x = f2b(v.x); o.y = f2b(v.y); o.z = f2b(v.z); o.w = f2b(v.w);
  *(ushort4*)(dst + i) = o;
}

// Bt[n*512+k] = bf16(W[k*512+n])   (512x512)
__global__ void castT512(const float* __restrict__ W, ushort_t* __restrict__ Bt) {
  int gid = blockIdx.x * 256 + threadIdx.x;
  int n = gid >> 9, k = gid & 511;
  Bt[gid] = f2b(W[(size_t)k * 512 + n]);
}

// Bt[n*1536 + dt*512 + i] = bf16(convW[n][i][dt])
__global__ void cast_convW(const float* __restrict__ W, ushort_t* __restrict__ Bt) {
  int gid = blockIdx.x * 256 + threadIdx.x;
  int n = gid / 1536, k = gid - n * 1536;
  int dt = k >> 9, ii = k & 511;
  Bt[gid] = f2b(W[((size_t)n * 512 + ii) * 3 + dt]);
}

// ---------------- bf16 MFMA GEMM (m97 structure) ----------------
__device__ __forceinline__ float gelu_exact(float c) {
  return 0.5f * c * (1.0f + erff(c * 0.70710678118654752f));
}

template <int CONVMODE, int EPI>
__global__ __launch_bounds__(256) void mfma_gemm(
    const ushort_t* __restrict__ A, const ushort_t* __restrict__ Bt,
    const float* __restrict__ bias, float* __restrict__ Cf,
    ushort_t* __restrict__ Cb, const float* __restrict__ bng,
    const float* __restrict__ bnb, int N, int K, int L) {
  __shared__ __align__(16) ushort_t As[128 * 64];
  __shared__ __align__(16) ushort_t Bs[128 * 64];
  const int tid = threadIdx.x;
  const int lane = tid & 63;
  const int wid = tid >> 6;
  const int wr = wid >> 1, wc = wid & 1;
  const int bm = blockIdx.y, bn = blockIdx.x;
  const int ln = lane & 15, lh = lane >> 4;

  f32x4 acc[4][4] = {};

  for (int k0 = 0; k0 < K; k0 += 64) {
    __syncthreads();
#pragma unroll
    for (int it = 0; it < 4; ++it) {
      int c = it * 256 + tid;
      int row = c >> 3, kc = (c & 7) * 8;
      size_t ga;
      if (CONVMODE) {
        int m = bm * 128 + row;
        int b = m / L, tpos = m - b * L;
        int k = k0 + kc;
        int dt = k >> 9, ii = k & 511;
        int tr2 = tpos + dt - 1;
        if (tr2 < 0) tr2 += L;
        if (tr2 >= L) tr2 -= L;
        ga = ((size_t)(b * L + tr2)) * 512 + ii;
      } else {
        ga = (size_t)(bm * 128 + row) * K + k0 + kc;
      }
      __builtin_amdgcn_global_load_lds(
          (const __attribute__((address_space(1))) void*)(A + ga),
          (__attribute__((address_space(3))) void*)(As + c * 8), 16, 0, 0);
      size_t gb = (size_t)(bn * 128 + row) * K + k0 + kc;
      __builtin_amdgcn_global_load_lds(
          (const __attribute__((address_space(1))) void*)(Bt + gb),
          (__attribute__((address_space(3))) void*)(Bs + c * 8), 16, 0, 0);
    }
    __syncthreads();
#pragma unroll
    for (int kk = 0; kk < 2; ++kk) {
      bf16x8 af[4], bf_[4];
#pragma unroll
      for (int m = 0; m < 4; ++m)
        af[m] = *(const bf16x8*)&As[(wr * 64 + m * 16 + ln) * 64 + kk * 32 + lh * 8];
#pragma unroll
      for (int n = 0; n < 4; ++n)
        bf_[n] = *(const bf16x8*)&Bs[(wc * 64 + n * 16 + ln) * 64 + kk * 32 + lh * 8];
#pragma unroll
      for (int m = 0; m < 4; ++m)
#pragma unroll
        for (int n = 0; n < 4; ++n)
          acc[m][n] =
              __builtin_amdgcn_mfma_f32_16x16x32_bf16(af[m], bf_[n], acc[m][n], 0, 0, 0);
    }
  }

  const float bnscale = 0.9999950000374996f;  // 1/sqrt(1+1e-5)
#pragma unroll
  for (int m = 0; m < 4; ++m) {
    int row = bm * 128 + wr * 64 + m * 16 + lh * 4;
#pragma unroll
    for (int n = 0; n < 4; ++n) {
      int col = bn * 128 + wc * 64 + n * 16 + ln;
      float bsv = bias[col];
#pragma unroll
      for (int r = 0; r < 4; ++r) {
        float cval = acc[m][n][r] + bsv;
        size_t oi = (size_t)(row + r) * N + col;
        if (EPI == 0) {
          Cb[oi] = f2b(cval);
        } else if (EPI == 1) {
          Cf[oi] += cval;
        } else if (EPI == 2) {
          Cb[oi] = f2b(gelu_exact(cval));
        } else {
          float c2 = cval * bnscale * bng[col] + bnb[col];
          Cf[oi] = c2 > 0.0f ? c2 : expm1f(c2);
        }
      }
    }
  }
}

// ---------------- LN (in-place, row = 512) ----------------
__global__ __launch_bounds__(256) void ln_inplace(float* __restrict__ h,
                                                  const float* __restrict__ g,
                                                  const float* __restrict__ b) {
  size_t row = blockIdx.x;
  float* hr = h + row * 512;
  int t = threadIdx.x;
  float x0 = hr[t], x1 = hr[t + 256];
  float mean = blk_reduce_sum(x0 + x1) * (1.0f / 512.0f);
  float d0 = x0 - mean, d1 = x1 - mean;
  float var = blk_reduce_sum(d0 * d0 + d1 * d1) * (1.0f / 512.0f);
  float rstd = rsqrtf(var + 1e-5f);
  hr[t] = d0 * rstd * g[t] + b[t];
  hr[t + 256] = d1 * rstd * g[t + 256] + b[t + 256];
}

// ---------------- prob-sparse M scores: one wave per (b,l), coalesced 1KB K rows ----
__global__ __launch_bounds__(256) void prob_scores_wave(const ushort_t* __restrict__ q,
                                                        const ushort_t* __restrict__ k,
                                                        const int* __restrict__ idx,
                                                        float* __restrict__ Mout,
                                                        int L, int S) {
  int wv = (blockIdx.x << 2) + ((threadIdx.x) >> 6);  // wave id over CB*L
  int lane = threadIdx.x & 63;
  int l = wv % L;
  int b = wv / L;
  const ushort_t* qr = q + ((size_t)(b * L + l)) * 512 + lane * 8;
  uint4 qu = *(const uint4*)qr;
  float qf[8];
  qf[0] = b2f_lo(qu.x); qf[1] = b2f_hi(qu.x);
  qf[2] = b2f_lo(qu.y); qf[3] = b2f_hi(qu.y);
  qf[4] = b2f_lo(qu.z); qf[5] = b2f_hi(qu.z);
  qf[6] = b2f_lo(qu.w); qf[7] = b2f_hi(qu.w);
  const int* il = idx + l * S;
  const ushort_t* kb = k + (size_t)b * L * 512 + lane * 8;
  float m = -INFINITY, ssum = 0.0f;
  for (int s = 0; s < S; ++s) {
    int j = il[s];
    uint4 ku = *(const uint4*)(kb + (size_t)j * 512);
    float dot = qf[0] * b2f_lo(ku.x) + qf[1] * b2f_hi(ku.x) +
                qf[2] * b2f_lo(ku.y) + qf[3] * b2f_hi(ku.y) +
                qf[4] * b2f_lo(ku.z) + qf[5] * b2f_hi(ku.z) +
                qf[6] * b2f_lo(ku.w) + qf[7] * b2f_hi(ku.w);
    dot += __shfl_xor(dot, 1);
    dot += __shfl_xor(dot, 2);
    dot += __shfl_xor(dot, 4);
    m = fmaxf(m, dot);
    ssum += dot;
  }
  if ((lane & 7) == 0) {
    int hh = lane >> 3;
    Mout[((size_t)(b * 8 + hh)) * L + l] = m - ssum / (float)L;
  }
}

// ---------------- top-k: register-cached iterative argmax ----------------
__global__ __launch_bounds__(256) void topk_kernel(const float* __restrict__ Mbuf,
                                                   int* __restrict__ top_idx,
                                                   int L, int S) {
  int bh = blockIdx.x;
  __shared__ float vals[4096];
  __shared__ float rw[4];
  __shared__ int ri2[4];
  const float* Mr = Mbuf + (size_t)bh * L;
  int t = threadIdx.x;
  int lane = t & 63, w = t >> 6;
  int chunk = L >> 8;  // L/256
  int base = t * chunk;
  for (int j = t; j < L; j += 256) vals[j] = Mr[j];
  __syncthreads();
  float lmax = -INFINITY;
  int lidx = 1 << 30;
  for (int i = 0; i < chunk; ++i) {
    float vv = vals[base + i];
    if (vv > lmax || (vv == lmax && base + i < lidx)) { lmax = vv; lidx = base + i; }
  }
  for (int it = 0; it < S; ++it) {
    float v2 = lmax;
    int i2 = lidx;
#pragma unroll
    for (int o2 = 1; o2 < 64; o2 <<= 1) {
      float ov = __shfl_xor(v2, o2);
      int oi = __shfl_xor(i2, o2);
      if (ov > v2 || (ov == v2 && oi < i2)) { v2 = ov; i2 = oi; }
    }
    if (lane == 0) { rw[w] = v2; ri2[w] = i2; }
    __syncthreads();
    float bv = rw[0];
    int bi = ri2[0];
#pragma unroll
    for (int ww = 1; ww < 4; ++ww) {
      float ov = rw[ww];
      int oi = ri2[ww];
      if (ov > bv || (ov == bv && oi < bi)) { bv = ov; bi = oi; }
    }
    if (t == 0) top_idx[bh * S + it] = bi;
    if (bi >= base && bi < base + chunk) {
      vals[bi] = -INFINITY;
      lmax = -INFINITY;
      lidx = 1 << 30;
      for (int i = 0; i < chunk; ++i) {
        float vv = vals[base + i];
        if (vv > lmax || (vv == lmax && base + i < lidx)) { lmax = vv; lidx = base + i; }
      }
    }
    __syncthreads();
  }
}

// ---------------- mean of V: stage 1 (coalesced column partial sums) ----------------
__global__ __launch_bounds__(256) void mean_v_partial(const ushort_t* __restrict__ v,
                                                      float* __restrict__ part, int L) {
  int b = blockIdx.x;
  int chunk = blockIdx.y;
  int t = threadIdx.x;
  int c = t * 2;
  const ushort_t* base = v + ((size_t)b * L + (size_t)chunk * 256) * 512 + c;
  float a0 = 0.0f, a1 = 0.0f;
#pragma unroll 8
  for (int r = 0; r < 256; ++r) {
    uint32_t u = *(const uint32_t*)(base + (size_t)r * 512);
    a0 += b2f_lo(u);
    a1 += b2f_hi(u);
  }
  float* p = part + ((size_t)b * 16 + chunk) * 512 + c;
  p[0] = a0;
  p[1] = a1;
}

// ---------------- mean of V: stage 2 ----------------
__global__ void mean_v_finish(const float* __restrict__ part, float* __restrict__ mv,
                              int L, int nchunks) {
  int b = blockIdx.x;
  int c = threadIdx.x;  // 512 threads
  float s = 0.0f;
  for (int k = 0; k < nchunks; ++k) s += part[((size_t)b * 16 + k) * 512 + c];
  mv[b * 512 + c] = s / (float)L;
}

// ---------------- fill ctx (bf16) with broadcast mean ----------------
__global__ void fill_ctx(ushort_t* __restrict__ ctx, const float* __restrict__ mv,
                         int L) {
  size_t gid = (size_t)blockIdx.x * 256 + threadIdx.x;  // CB*L*512
  int c = (int)(gid & 511);
  size_t bl = gid >> 9;
  int b = (int)(bl / (size_t)L);
  ctx[gid] = f2b(mv[b * 512 + c]);
}

// ---------------- fused flash attention over selected queries ----------------
// grid (fj = L/128, CBNH). Each block: 128 keys (2 tiles of 64) for all S
// queries of one bh. Online softmax; per-split partials (m, z, O-unnorm).
__global__ __launch_bounds__(256) void flash_attn(const ushort_t* __restrict__ q,
                                                  const ushort_t* __restrict__ k,
                                                  const ushort_t* __restrict__ v,
                                                  const int* __restrict__ top_idx,
                                                  float* __restrict__ pm,
                                                  float* __restrict__ pz,
                                                  float* __restrict__ po,
                                                  int L, int S, int CBNH) {
  __shared__ float qs[SMAX * 64];
  __shared__ float pt[SMAX * 64];
  __shared__ float srow[SMAX];
  int bh = blockIdx.y, js = blockIdx.x;
  int hh = bh & 7, b = bh >> 3;
  int t = threadIdx.x;
  int lane = t & 63, w = t >> 6;
  for (int e = t; e < S * 64; e += 256) {
    int u = e >> 6, d = e & 63;
    int l = top_idx[bh * S + u];
    qs[e] = bu2f(q[((size_t)(b * L + l)) * 512 + hh * 64 + d]);
  }
  __syncthreads();
  int j0 = js * 128;
  float m[12], z[12], oacc[12];
#pragma unroll
  for (int mi = 0; mi < 12; ++mi) { m[mi] = -INFINITY; z[mi] = 0.0f; oacc[mi] = 0.0f; }

#pragma unroll
  for (int jt = 0; jt < 128; jt += 64) {
    // stage A: lane = key; K row in registers; scores + online max + P -> LDS
    const ushort_t* kr = k + ((size_t)(b * L + j0 + jt + lane)) * 512 + hh * 64;
    uint4 kreg[8];
#pragma unroll
    for (int c = 0; c < 8; ++c) kreg[c] = ((const uint4*)kr)[c];
#pragma unroll
    for (int mi = 0; mi < 12; ++mi) {
      int u = w + mi * 4;
      if (u < S) {
        const float* qu = qs + u * 64;
        float dot = 0.0f;
#pragma unroll
        for (int c = 0; c < 8; ++c) {
          uint4 ku = kreg[c];
          const float* q8 = qu + c * 8;
          dot += q8[0] * b2f_lo(ku.x) + q8[1] * b2f_hi(ku.x) +
                 q8[2] * b2f_lo(ku.y) + q8[3] * b2f_hi(ku.y) +
                 q8[4] * b2f_lo(ku.z) + q8[5] * b2f_hi(ku.z) +
                 q8[6] * b2f_lo(ku.w) + q8[7] * b2f_hi(ku.w);
        }
        dot *= 0.125f;  // 1/sqrt(64)
        float tmax = dot;
#pragma unroll
        for (int o2 = 1; o2 < 64; o2 <<= 1) tmax = fmaxf(tmax, __shfl_xor(tmax, o2));
        float nm = fmaxf(m[mi], tmax);
        float sc2 = __expf(m[mi] - nm);  // first tile: exp(-inf) = 0
        float P = __expf(dot - nm);
        float ps = P;
#pragma unroll
        for (int o2 = 1; o2 < 64; o2 <<= 1) ps += __shfl_xor(ps, o2);
        z[mi] = z[mi] * sc2 + ps;
        m[mi] = nm;
        pt[u * 64 + lane] = P;
        if (lane == 0) srow[u] = sc2;
      }
    }
    __syncthreads();
    // stage B: lane = d; rescale O, accumulate P*V (coalesced V rows)
#pragma unroll
    for (int mi = 0; mi < 12; ++mi) {
      int u = w + mi * 4;
      if (u < S) oacc[mi] *= srow[u];
    }
    for (int jb = 0; jb < 64; jb += 4) {
      float vv[4];
#pragma unroll
      for (int r = 0; r < 4; ++r)
        vv[r] = bu2f(v[((size_t)(b * L + j0 + jt + jb + r)) * 512 + hh * 64 + lane]);
#pragma unroll
      for (int mi = 0; mi < 12; ++mi) {
        int u = w + mi * 4;
        if (u < S) {
          const float* p4 = &pt[u * 64 + jb];
          oacc[mi] += p4[0] * vv[0] + p4[1] * vv[1] + p4[2] * vv[2] + p4[3] * vv[3];
        }
      }
    }
    __syncthreads();
  }
  size_t base = (size_t)js * CBNH + bh;
#pragma unroll
  for (int mi = 0; mi < 12; ++mi) {
    int u = w + mi * 4;
    if (u < S) {
      po[(base * SMAX + u) * 64 + lane] = oacc[mi];
      if (lane == 0) { pm[base * SMAX + u] = m[mi]; pz[base * SMAX + u] = z[mi]; }
    }
  }
}

// ---------------- combine flash partials, /Z, scatter into ctx ----------------
__global__ void flash_finish(const float* __restrict__ pm, const float* __restrict__ pz,
                             const float* __restrict__ po, const int* __restrict__ top_idx,
                             ushort_t* __restrict__ ctx, int L, int S, int CBNH,
                             int fj) {
  int gid = blockIdx.x * 256 + threadIdx.x;  // over CBNH*S*64
  if (gid >= CBNH * S * 64) return;
  int d = gid & 63;
  int r = gid >> 6;  // bh*S + u
  int u = r % S, bh = r / S;
  int hh = bh & 7, b = bh >> 3;
  float M = -INFINITY;
  for (int js = 0; js < fj; ++js)
    M = fmaxf(M, pm[((size_t)js * CBNH + bh) * SMAX + u]);
  float Z = 0.0f, O = 0.0f;
  for (int js = 0; js < fj; ++js) {
    size_t pi = ((size_t)js * CBNH + bh) * SMAX + u;
    float e = __expf(pm[pi] - M);
    Z += pz[pi] * e;
    O += po[pi * 64 + d] * e;
  }
  int l = top_idx[bh * S + u];
  ctx[((size_t)(b * L + l)) * 512 + hh * 64 + d] = f2b(O / Z);
}

// ---------------- maxpool window 3 stride 2 ----------------
__global__ void maxpool_kernel(const float* __restrict__ y, float* __restrict__ hout,
                               int L) {
  size_t gid = (size_t)blockIdx.x * 256 + threadIdx.x;  // CB*(L/2)*512
  int Lh = L >> 1;
  int o = (int)(gid & 511);
  size_t bj = gid >> 9;
  int j = (int)(bj % (size_t)Lh);
  int b = (int)(bj / (size_t)Lh);
  const float* base = y + ((size_t)(b * L + 2 * j)) * 512 + o;
  float mx = base[0];
  if (j > 0) mx = fmaxf(mx, base[-512]);
  mx = fmaxf(mx, base[512]);
  hout[gid] = mx;
}

// ---------------- final LN + projection ----------------
__global__ __launch_bounds__(256) void final_ln_proj(const float* __restrict__ h,
                                                     const float* __restrict__ g,
                                                     const float* __restrict__ bb,
                                                     const float* __restrict__ pw,
                                                     const float* __restrict__ pb,
                                                     float* __restrict__ out, int L) {
  int b = blockIdx.x / 47, l = blockIdx.x % 47;
  const float* hr = h + ((size_t)(b * L + l)) * 512;
  int t = threadIdx.x;
  float x0 = hr[t], x1 = hr[t + 256];
  float mean = blk_reduce_sum(x0 + x1) * (1.0f / 512.0f);
  float d0 = x0 - mean, d1 = x1 - mean;
  float var = blk_reduce_sum(d0 * d0 + d1 * d1) * (1.0f / 512.0f);
  float rstd = rsqrtf(var + 1e-5f);
  float y0 = d0 * rstd * g[t] + bb[t];
  float y1 = d1 * rstd * g[t + 256] + bb[t + 256];
  float dot = blk_reduce_sum(y0 * pw[t] + y1 * pw[t + 256]);
  if (t == 0) out[b * 47 + l] = dot + pb[0];
}

// ---------------- launcher ----------------
extern "C" void kernel_launch(void* const* d_in, const int* in_sizes, int n_in,
                              void* d_out, int out_size, void* d_ws, size_t ws_size,
                              hipStream_t stream) {
  const float* x = (const float*)d_in[0];
  const float* emb_W = (const float*)d_in[1];
  const float* emb_b = (const float*)d_in[2];
  const float* Wq = (const float*)d_in[3];
  const float* bq = (const float*)d_in[4];
  const float* Wk = (const float*)d_in[5];
  const float* bk = (const float*)d_in[6];
  const float* Wv = (const float*)d_in[7];
  const float* bv = (const float*)d_in[8];
  const float* Wo = (const float*)d_in[9];
  const float* bo = (const float*)d_in[10];
  const float* fW1 = (const float*)d_in[11];
  const float* fb1 = (const float*)d_in[12];
  const float* fW2 = (const float*)d_in[13];
  const float* fb2 = (const float*)d_in[14];
  const float* ln1g = (const float*)d_in[15];
  const float* ln1b = (const float*)d_in[16];
  const float* ln2g = (const float*)d_in[17];
  const float* ln2b = (const float*)d_in[18];
  const float* cW = (const float*)d_in[19];
  const float* cb = (const float*)d_in[20];
  const float* bng = (const float*)d_in[21];
  const float* bnb = (const float*)d_in[22];
  const float* flng = (const float*)d_in[23];
  const float* flnb = (const float*)d_in[24];
  const float* pW = (const float*)d_in[25];
  const float* pb = (const float*)d_in[26];
  float* out = (float*)d_out;

  // batch-group size from ws_size (try 16, 8, 4, 2, 1)
  int CB = 16;
  while (CB > 1) {
    size_t need = 35719168ull + (size_t)CB * 6066048ull;
    if (need * 4 <= ws_size) break;
    CB >>= 1;
  }
  const size_t CBseg = (size_t)CB * 2097152ull;  // CB*4096*512 (bf16 elems)
  const int CBNH = CB * NH;

  float* ws = (float*)d_ws;
  size_t off = 0;
  float* h = ws;                           off += 33554432ull;
  ushort_t* wbase = (ushort_t*)(ws + off); off += 1966080ull;
  ushort_t* WqT = wbase;
  ushort_t* WkT = wbase + 262144;
  ushort_t* WvT = wbase + 524288;
  ushort_t* WoT = wbase + 786432;
  ushort_t* W1b = wbase + 1048576;
  ushort_t* W2b = wbase + 2097152;
  ushort_t* Wcb = wbase + 3145728;
  ushort_t* gArea = (ushort_t*)(ws + off); off += (5ull * CBseg) / 2;
  ushort_t* hb = gArea;
  ushort_t* qb = gArea + CBseg;
  ushort_t* kbuf = gArea + 2 * CBseg;
  ushort_t* vb = gArea + 3 * CBseg;
  ushort_t* ctxb = gArea + 4 * CBseg;
  ushort_t* ybuf = qb;           // spans qb..ctxb (4*CBseg bf16)
  float* convY = (float*)qb;     // spans qb,kbuf (CBseg f32)
  float* Mbuf = ws + off;                  off += (size_t)CB * 32768;
  float* mv = ws + off;                    off += (size_t)CB * 512;
  int* topidx = (int*)(ws + off);          off += (size_t)CB * 384;
  int* idxbuf = (int*)(ws + off);          off += 196608ull;
  float* pmb = ws + off;                   off += (size_t)CB * 11520;   // FJMAX*NH*SMAX
  float* pzb = ws + off;                   off += (size_t)CB * 11520;
  float* pob = ws + off;                   off += (size_t)CB * 737280;  // FJMAX*NH*SMAX*64
  float* mvpart = ws + off;                off += (size_t)CB * 8192;    // CB*16*512

  // embedding
  {
    size_t total = (size_t)NB * 4096 * DM;
    embed_kernel<<<(int)(total / 256), 256, 0, stream>>>(x, emb_W, emb_b, h);
  }

  int L = 4096;
  for (int i = 0; i < 3; ++i) {
    int S = (i == 0) ? 45 : (i == 1) ? 40 : 35;
    int ngroups = NB / CB;
    int Mg = CB * L;
    size_t segL = (size_t)Mg * 512;
    int fj = L / 128;  // key splits: 32 / 16 / 8

    // per-layer weight casts
    castT512<<<1024, 256, 0, stream>>>(Wq + (size_t)i * 262144, WqT);
    castT512<<<1024, 256, 0, stream>>>(Wk + (size_t)i * 262144, WkT);
    castT512<<<1024, 256, 0, stream>>>(Wv + (size_t)i * 262144, WvT);
    castT512<<<1024, 256, 0, stream>>>(Wo + (size_t)i * 262144, WoT);
    cast_bf16<<<1024, 256, 0, stream>>>(fW1 + (size_t)i * 1048576, W1b, 1048576);
    cast_bf16<<<1024, 256, 0, stream>>>(fW2 + (size_t)i * 1048576, W2b, 1048576);
    if (i < 2) cast_convW<<<3072, 256, 0, stream>>>(cW + (size_t)i * 786432, Wcb);

    // JAX randint key
    uint32_t fa, fbk;
    tf2x32(0u, 42u, 0u, (uint32_t)i, &fa, &fbk);
    uint32_t a0, b0, a1, b1;
    tf2x32(fa, fbk, 0u, 2u, &a0, &b0);
    tf2x32(fa, fbk, 1u, 3u, &a1, &b1);
    int n = L * S;
    gen_idx_kernel<<<(n + 255) / 256, 256, 0, stream>>>(idxbuf, b0, b1, n, L - 1);

    // ---- attention per batch group ----
    for (int g = 0; g < ngroups; ++g) {
      float* hg = h + (size_t)g * segL;
      cast_bf16<<<(int)(segL / 1024), 256, 0, stream>>>(hg, hb, segL);
      dim3 gq(4, Mg / 128);
      mfma_gemm<0, 0><<<gq, 256, 0, stream>>>(hb, WqT, bq + i * DM, nullptr, qb,
                                              nullptr, nullptr, 512, 512, 0);
      mfma_gemm<0, 0><<<gq, 256, 0, stream>>>(hb, WkT, bk + i * DM, nullptr, kbuf,
                                              nullptr, nullptr, 512, 512, 0);
      mfma_gemm<0, 0><<<gq, 256, 0, stream>>>(hb, WvT, bv + i * DM, nullptr, vb,
                                              nullptr, nullptr, 512, 512, 0);

      prob_scores_wave<<<(CB * L) / 4, 256, 0, stream>>>(qb, kbuf, idxbuf, Mbuf, L, S);
      topk_kernel<<<CBNH, 256, 0, stream>>>(Mbuf, topidx, L, S);

      mean_v_partial<<<dim3(CB, L / 256), 256, 0, stream>>>(vb, mvpart, L);
      mean_v_finish<<<CB, 512, 0, stream>>>(mvpart, mv, L, L / 256);
      fill_ctx<<<(int)(segL / 256), 256, 0, stream>>>(ctxb, mv, L);
      flash_attn<<<dim3(fj, CBNH), 256, 0, stream>>>(qb, kbuf, vb, topidx,
                                                     pmb, pzb, pob, L, S, CBNH);
      flash_finish<<<(CBNH * S * 64 + 255) / 256, 256, 0, stream>>>(
          pmb, pzb, pob, topidx, ctxb, L, S, CBNH, fj);

      mfma_gemm<0, 1><<<gq, 256, 0, stream>>>(ctxb, WoT, bo + i * DM, hg, nullptr,
                                              nullptr, nullptr, 512, 512, 0);
    }
    ln_inplace<<<NB * L, 256, 0, stream>>>(h, ln1g + i * DM, ln1b + i * DM);

    // ---- FF row-chunked ----
    int rows = NB * L;
    int R = CB * 4096;
    if (R > rows) R = rows;
    for (int r0 = 0; r0 < rows; r0 += R) {
      float* hr = h + (size_t)r0 * 512;
      size_t rseg = (size_t)R * 512;
      cast_bf16<<<(int)(rseg / 1024), 256, 0, stream>>>(hr, hb, rseg);
      dim3 g1(16, R / 128);
      mfma_gemm<0, 2><<<g1, 256, 0, stream>>>(hb, W1b, fb1 + i * DFF_, nullptr, ybuf,
                                              nullptr, nullptr, 2048, 512, 0);
      dim3 g2(4, R / 128);
      mfma_gemm<0, 1><<<g2, 256, 0, stream>>>(ybuf, W2b, fb2 + i * DM, hr, nullptr,
                                              nullptr, nullptr, 512, 2048, 0);
    }
    ln_inplace<<<NB * L, 256, 0, stream>>>(h, ln2g + i * DM, ln2b + i * DM);

    // ---- conv + maxpool per batch group ----
    if (i < 2) {
      int Lh = L / 2;
      for (int g = 0; g < ngroups; ++g) {
        float* hg = h + (size_t)g * segL;
        cast_bf16<<<(int)(segL / 1024), 256, 0, stream>>>(hg, hb, segL);
        dim3 gc(4, Mg / 128);
        mfma_gemm<1, 3><<<gc, 256, 0, stream>>>(hb, Wcb, cb + i * DM, convY, nullptr,
                                                bng + i * DM, bnb + i * DM, 512, 1536, L);
        size_t tot = (size_t)CB * Lh * 512;
        maxpool_kernel<<<(int)(tot / 256), 256, 0, stream>>>(
            convY, h + (size_t)g * CB * Lh * 512, L);
      }
      L = Lh;
    }
  }

  final_ln_proj<<<NB * 47, 256, 0, stream>>>(h, flng, flnb, pW, pb, out, L);
}

// Round 10
// 5002.734 us; speedup vs baseline: 1.8893x; 1.0918x over previous
//
#include <hip/hip_runtime.h>
#include <cstdint>
#include <math.h>

#define NB 16
#define DM 512
#define NH 8
#define DFF_ 2048
#define SMAX 45
#define FJMAX 64

typedef unsigned short ushort_t;
typedef __bf16 bf16x8 __attribute__((ext_vector_type(8)));
typedef float f32x4 __attribute__((ext_vector_type(4)));

// ---------------- bf16 helpers ----------------
__device__ __forceinline__ ushort_t f2b(float f) {  // RNE f32 -> bf16 bits
  uint32_t u = __float_as_uint(f);
  uint32_t r = (u + 0x7FFFu + ((u >> 16) & 1u)) >> 16;
  return (ushort_t)r;
}
__device__ __forceinline__ float bu2f(ushort_t x) {
  return __uint_as_float((uint32_t)x << 16);
}
__device__ __forceinline__ float b2f_lo(uint32_t u) { return __uint_as_float(u << 16); }
__device__ __forceinline__ float b2f_hi(uint32_t u) { return __uint_as_float(u & 0xFFFF0000u); }

// ---------------- threefry2x32 (JAX-compatible) ----------------
__host__ __device__ inline void tf2x32(uint32_t k0, uint32_t k1,
                                       uint32_t x0, uint32_t x1,
                                       uint32_t* o0, uint32_t* o1) {
  uint32_t ks0 = k0, ks1 = k1, ks2 = k0 ^ k1 ^ 0x1BD11BDAu;
  x0 += ks0; x1 += ks1;
#define TF_RND(r) { x0 += x1; x1 = (x1 << (r)) | (x1 >> (32 - (r))); x1 ^= x0; }
  TF_RND(13) TF_RND(15) TF_RND(26) TF_RND(6)
  x0 += ks1; x1 += ks2 + 1u;
  TF_RND(17) TF_RND(29) TF_RND(16) TF_RND(24)
  x0 += ks2; x1 += ks0 + 2u;
  TF_RND(13) TF_RND(15) TF_RND(26) TF_RND(6)
  x0 += ks0; x1 += ks1 + 3u;
  TF_RND(17) TF_RND(29) TF_RND(16) TF_RND(24)
  x0 += ks1; x1 += ks2 + 4u;
  TF_RND(13) TF_RND(15) TF_RND(26) TF_RND(6)
  x0 += ks2; x1 += ks0 + 5u;
#undef TF_RND
  *o0 = x0; *o1 = x1;
}

__global__ void gen_idx_kernel(int* __restrict__ idx, uint32_t k0, uint32_t k1,
                               int n, int mask) {
  int j = blockIdx.x * 256 + threadIdx.x;
  if (j >= n) return;
  int half = n >> 1;
  uint32_t o0, o1;
  if (j < half) {
    tf2x32(k0, k1, (uint32_t)j, (uint32_t)(j + half), &o0, &o1);
    idx[j] = (int)(o0 & (uint32_t)mask);
  } else {
    tf2x32(k0, k1, (uint32_t)(j - half), (uint32_t)j, &o0, &o1);
    idx[j] = (int)(o1 & (uint32_t)mask);
  }
}

// ---------------- block reduce helpers (256 threads, wave64) ----------------
__device__ inline float blk_reduce_sum(float v) {
  __shared__ float s[4];
  for (int o = 32; o > 0; o >>= 1) v += __shfl_down(v, o);
  int lane = threadIdx.x & 63, w = threadIdx.x >> 6;
  if (lane == 0) s[w] = v;
  __syncthreads();
  float r = s[0] + s[1] + s[2] + s[3];
  __syncthreads();
  return r;
}

// ---------------- embedding ----------------
__global__ void embed_kernel(const float* __restrict__ x, const float* __restrict__ W,
                             const float* __restrict__ bias, float* __restrict__ h) {
  size_t gid = (size_t)blockIdx.x * 256 + threadIdx.x;
  int o = (int)(gid & 511);
  size_t bl = gid >> 9;
  const float* xr = x + bl * 7;
  float acc = bias[o];
#pragma unroll
  for (int i = 0; i < 7; ++i) acc += xr[i] * W[i * 512 + o];
  h[gid] = acc;
}

// ---------------- cast kernels ----------------
__global__ void cast_bf16(const float* __restrict__ src, ushort_t* __restrict__ dst,
                          size_t n) {
  size_t i = ((size_t)blockIdx.x * 256 + threadIdx.x) * 4;
  if (i >= n) return;
  float4 v = *(const float4*)(src + i);
  ushort4 o;
  o.x = f2b(v.x); o.y = f2b(v.y); o.z = f2b(v.z); o.w = f2b(v.w);
  *(ushort4*)(dst + i) = o;
}

// Bt[n*512+k] = bf16(W[k*512+n])   (512x512)
__global__ void castT512(const float* __restrict__ W, ushort_t* __restrict__ Bt) {
  int gid = blockIdx.x * 256 + threadIdx.x;
  int n = gid >> 9, k = gid & 511;
  Bt[gid] = f2b(W[(size_t)k * 512 + n]);
}

// Bt[n*1536 + dt*512 + i] = bf16(convW[n][i][dt])
__global__ void cast_convW(const float* __restrict__ W, ushort_t* __restrict__ Bt) {
  int gid = blockIdx.x * 256 + threadIdx.x;
  int n = gid / 1536, k = gid - n * 1536;
  int dt = k >> 9, ii = k & 511;
  Bt[gid] = f2b(W[((size_t)n * 512 + ii) * 3 + dt]);
}

// concat 3x512 bias -> 1536
__global__ void concat3(const float* __restrict__ a, const float* __restrict__ b,
                        const float* __restrict__ c, float* __restrict__ o) {
  int t = blockIdx.x * 256 + threadIdx.x;
  if (t >= 1536) return;
  o[t] = t < 512 ? a[t] : (t < 1024 ? b[t - 512] : c[t - 1024]);
}

// ---------------- bf16 MFMA GEMM (m97 structure) ----------------
// MODE 0: standard  1: conv circular-A  2: QKV fused (route by bn>>2 into
//         three CBseg-strided bf16 buffers; L param carries CBseg)
__device__ __forceinline__ float gelu_exact(float c) {
  return 0.5f * c * (1.0f + erff(c * 0.70710678118654752f));
}

template <int MODE, int EPI>
__global__ __launch_bounds__(256) void mfma_gemm(
    const ushort_t* __restrict__ A, const ushort_t* __restrict__ Bt,
    const float* __restrict__ bias, float* __restrict__ Cf,
    ushort_t* __restrict__ Cb, const float* __restrict__ bng,
    const float* __restrict__ bnb, int N, int K, int L) {
  __shared__ __align__(16) ushort_t As[128 * 64];
  __shared__ __align__(16) ushort_t Bs[128 * 64];
  const int tid = threadIdx.x;
  const int lane = tid & 63;
  const int wid = tid >> 6;
  const int wr = wid >> 1, wc = wid & 1;
  const int bm = blockIdx.y, bn = blockIdx.x;
  const int ln = lane & 15, lh = lane >> 4;

  f32x4 acc[4][4] = {};

  for (int k0 = 0; k0 < K; k0 += 64) {
    __syncthreads();
#pragma unroll
    for (int it = 0; it < 4; ++it) {
      int c = it * 256 + tid;
      int row = c >> 3, kc = (c & 7) * 8;
      size_t ga;
      if (MODE == 1) {
        int m = bm * 128 + row;
        int b = m / L, tpos = m - b * L;
        int k = k0 + kc;
        int dt = k >> 9, ii = k & 511;
        int tr2 = tpos + dt - 1;
        if (tr2 < 0) tr2 += L;
        if (tr2 >= L) tr2 -= L;
        ga = ((size_t)(b * L + tr2)) * 512 + ii;
      } else {
        ga = (size_t)(bm * 128 + row) * K + k0 + kc;
      }
      __builtin_amdgcn_global_load_lds(
          (const __attribute__((address_space(1))) void*)(A + ga),
          (__attribute__((address_space(3))) void*)(As + c * 8), 16, 0, 0);
      size_t gb = (size_t)(bn * 128 + row) * K + k0 + kc;
      __builtin_amdgcn_global_load_lds(
          (const __attribute__((address_space(1))) void*)(Bt + gb),
          (__attribute__((address_space(3))) void*)(Bs + c * 8), 16, 0, 0);
    }
    __syncthreads();
#pragma unroll
    for (int kk = 0; kk < 2; ++kk) {
      bf16x8 af[4], bf_[4];
#pragma unroll
      for (int m = 0; m < 4; ++m)
        af[m] = *(const bf16x8*)&As[(wr * 64 + m * 16 + ln) * 64 + kk * 32 + lh * 8];
#pragma unroll
      for (int n = 0; n < 4; ++n)
        bf_[n] = *(const bf16x8*)&Bs[(wc * 64 + n * 16 + ln) * 64 + kk * 32 + lh * 8];
#pragma unroll
      for (int m = 0; m < 4; ++m)
#pragma unroll
        for (int n = 0; n < 4; ++n)
          acc[m][n] =
              __builtin_amdgcn_mfma_f32_16x16x32_bf16(af[m], bf_[n], acc[m][n], 0, 0, 0);
    }
  }

  const float bnscale = 0.9999950000374996f;  // 1/sqrt(1+1e-5)
#pragma unroll
  for (int m = 0; m < 4; ++m) {
    int row = bm * 128 + wr * 64 + m * 16 + lh * 4;
#pragma unroll
    for (int n = 0; n < 4; ++n) {
      int col = bn * 128 + wc * 64 + n * 16 + ln;
      float bsv = bias[col];
#pragma unroll
      for (int r = 0; r < 4; ++r) {
        float cval = acc[m][n][r] + bsv;
        if (MODE == 2) {
          ushort_t* dst = Cb + (size_t)(bn >> 2) * (size_t)L;  // L = CBseg
          dst[(size_t)(row + r) * 512 + (col & 511)] = f2b(cval);
        } else {
          size_t oi = (size_t)(row + r) * N + col;
          if (EPI == 0) {
            Cb[oi] = f2b(cval);
          } else if (EPI == 1) {
            Cf[oi] += cval;
          } else if (EPI == 2) {
            Cb[oi] = f2b(gelu_exact(cval));
          } else {
            float c2 = cval * bnscale * bng[col] + bnb[col];
            Cf[oi] = c2 > 0.0f ? c2 : expm1f(c2);
          }
        }
      }
    }
  }
}

// ---------------- LN (in-place, row = 512) ----------------
__global__ __launch_bounds__(256) void ln_inplace(float* __restrict__ h,
                                                  const float* __restrict__ g,
                                                  const float* __restrict__ b) {
  size_t row = blockIdx.x;
  float* hr = h + row * 512;
  int t = threadIdx.x;
  float x0 = hr[t], x1 = hr[t + 256];
  float mean = blk_reduce_sum(x0 + x1) * (1.0f / 512.0f);
  float d0 = x0 - mean, d1 = x1 - mean;
  float var = blk_reduce_sum(d0 * d0 + d1 * d1) * (1.0f / 512.0f);
  float rstd = rsqrtf(var + 1e-5f);
  hr[t] = d0 * rstd * g[t] + b[t];
  hr[t + 256] = d1 * rstd * g[t + 256] + b[t + 256];
}

// ---------------- prob-sparse M scores: one wave per (b,l), coalesced 1KB K rows ----
__global__ __launch_bounds__(256) void prob_scores_wave(const ushort_t* __restrict__ q,
                                                        const ushort_t* __restrict__ k,
                                                        const int* __restrict__ idx,
                                                        float* __restrict__ Mout,
                                                        int L, int S) {
  int wv = (blockIdx.x << 2) + ((threadIdx.x) >> 6);  // wave id over CB*L
  int lane = threadIdx.x & 63;
  int l = wv % L;
  int b = wv / L;
  const ushort_t* qr = q + ((size_t)(b * L + l)) * 512 + lane * 8;
  uint4 qu = *(const uint4*)qr;
  float qf[8];
  qf[0] = b2f_lo(qu.x); qf[1] = b2f_hi(qu.x);
  qf[2] = b2f_lo(qu.y); qf[3] = b2f_hi(qu.y);
  qf[4] = b2f_lo(qu.z); qf[5] = b2f_hi(qu.z);
  qf[6] = b2f_lo(qu.w); qf[7] = b2f_hi(qu.w);
  const int* il = idx + l * S;
  const ushort_t* kb = k + (size_t)b * L * 512 + lane * 8;
  float m = -INFINITY, ssum = 0.0f;
  for (int s = 0; s < S; ++s) {
    int j = il[s];
    uint4 ku = *(const uint4*)(kb + (size_t)j * 512);
    float dot = qf[0] * b2f_lo(ku.x) + qf[1] * b2f_hi(ku.x) +
                qf[2] * b2f_lo(ku.y) + qf[3] * b2f_hi(ku.y) +
                qf[4] * b2f_lo(ku.z) + qf[5] * b2f_hi(ku.z) +
                qf[6] * b2f_lo(ku.w) + qf[7] * b2f_hi(ku.w);
    dot += __shfl_xor(dot, 1);
    dot += __shfl_xor(dot, 2);
    dot += __shfl_xor(dot, 4);
    m = fmaxf(m, dot);
    ssum += dot;
  }
  if ((lane & 7) == 0) {
    int hh = lane >> 3;
    Mout[((size_t)(b * 8 + hh)) * L + l] = m - ssum / (float)L;
  }
}

// ---------------- top-k: register-cached iterative argmax ----------------
__global__ __launch_bounds__(256) void topk_kernel(const float* __restrict__ Mbuf,
                                                   int* __restrict__ top_idx,
                                                   int L, int S) {
  int bh = blockIdx.x;
  __shared__ float vals[4096];
  __shared__ float rw[4];
  __shared__ int ri2[4];
  const float* Mr = Mbuf + (size_t)bh * L;
  int t = threadIdx.x;
  int lane = t & 63, w = t >> 6;
  int chunk = L >> 8;  // L/256
  int base = t * chunk;
  for (int j = t; j < L; j += 256) vals[j] = Mr[j];
  __syncthreads();
  float lmax = -INFINITY;
  int lidx = 1 << 30;
  for (int i = 0; i < chunk; ++i) {
    float vv = vals[base + i];
    if (vv > lmax || (vv == lmax && base + i < lidx)) { lmax = vv; lidx = base + i; }
  }
  for (int it = 0; it < S; ++it) {
    float v2 = lmax;
    int i2 = lidx;
#pragma unroll
    for (int o2 = 1; o2 < 64; o2 <<= 1) {
      float ov = __shfl_xor(v2, o2);
      int oi = __shfl_xor(i2, o2);
      if (ov > v2 || (ov == v2 && oi < i2)) { v2 = ov; i2 = oi; }
    }
    if (lane == 0) { rw[w] = v2; ri2[w] = i2; }
    __syncthreads();
    float bv = rw[0];
    int bi = ri2[0];
#pragma unroll
    for (int ww = 1; ww < 4; ++ww) {
      float ov = rw[ww];
      int oi = ri2[ww];
      if (ov > bv || (ov == bv && oi < bi)) { bv = ov; bi = oi; }
    }
    if (t == 0) top_idx[bh * S + it] = bi;
    if (bi >= base && bi < base + chunk) {
      vals[bi] = -INFINITY;
      lmax = -INFINITY;
      lidx = 1 << 30;
      for (int i = 0; i < chunk; ++i) {
        float vv = vals[base + i];
        if (vv > lmax || (vv == lmax && base + i < lidx)) { lmax = vv; lidx = base + i; }
      }
    }
    __syncthreads();
  }
}

// ---------------- mean of V: stage 1 (coalesced column partial sums) ----------------
__global__ __launch_bounds__(256) void mean_v_partial(const ushort_t* __restrict__ v,
                                                      float* __restrict__ part, int L) {
  int b = blockIdx.x;
  int chunk = blockIdx.y;
  int t = threadIdx.x;
  int c = t * 2;
  const ushort_t* base = v + ((size_t)b * L + (size_t)chunk * 256) * 512 + c;
  float a0 = 0.0f, a1 = 0.0f;
#pragma unroll 8
  for (int r = 0; r < 256; ++r) {
    uint32_t u = *(const uint32_t*)(base + (size_t)r * 512);
    a0 += b2f_lo(u);
    a1 += b2f_hi(u);
  }
  float* p = part + ((size_t)b * 16 + chunk) * 512 + c;
  p[0] = a0;
  p[1] = a1;
}

// ---------------- mean of V: stage 2 ----------------
__global__ void mean_v_finish(const float* __restrict__ part, float* __restrict__ mv,
                              int L, int nchunks) {
  int b = blockIdx.x;
  int c = threadIdx.x;  // 512 threads
  float s = 0.0f;
  for (int k = 0; k < nchunks; ++k) s += part[((size_t)b * 16 + k) * 512 + c];
  mv[b * 512 + c] = s / (float)L;
}

// ---------------- fill ctx (bf16) with broadcast mean ----------------
__global__ void fill_ctx(ushort_t* __restrict__ ctx, const float* __restrict__ mv,
                         int L) {
  size_t gid = (size_t)blockIdx.x * 256 + threadIdx.x;  // CB*L*512
  int c = (int)(gid & 511);
  size_t bl = gid >> 9;
  int b = (int)(bl / (size_t)L);
  ctx[gid] = f2b(mv[b * 512 + c]);
}

// ---------------- fused flash attention (no-max softmax: scores bounded) ----------
// grid (fj = L/64, CBNH). Each block: 64 keys for all S queries of one bh.
// P = exp(score) directly; per-split partials (z, O-unnormalized).
__global__ __launch_bounds__(256) void flash_attn(const ushort_t* __restrict__ q,
                                                  const ushort_t* __restrict__ k,
                                                  const ushort_t* __restrict__ v,
                                                  const int* __restrict__ top_idx,
                                                  float* __restrict__ pz,
                                                  float* __restrict__ po,
                                                  int L, int S, int CBNH) {
  __shared__ float qs[SMAX * 64];
  __shared__ ushort_t pt[SMAX * 64];
  int bh = blockIdx.y, js = blockIdx.x;
  int hh = bh & 7, b = bh >> 3;
  int t = threadIdx.x;
  int lane = t & 63, w = t >> 6;
  for (int e = t; e < S * 64; e += 256) {
    int u = e >> 6, d = e & 63;
    int l = top_idx[bh * S + u];
    qs[e] = bu2f(q[((size_t)(b * L + l)) * 512 + hh * 64 + d]);
  }
  __syncthreads();
  int j0 = js * 64;
  // stage A: lane = key; K row in registers; P = exp(score) -> LDS (bf16)
  const ushort_t* kr = k + ((size_t)(b * L + j0 + lane)) * 512 + hh * 64;
  uint4 kreg[8];
#pragma unroll
  for (int c = 0; c < 8; ++c) kreg[c] = ((const uint4*)kr)[c];
  float zs[12];
#pragma unroll
  for (int mi = 0; mi < 12; ++mi) {
    int u = w + mi * 4;
    if (u < S) {
      const float* qu = qs + u * 64;
      float dot = 0.0f;
#pragma unroll
      for (int c = 0; c < 8; ++c) {
        uint4 ku = kreg[c];
        const float* q8 = qu + c * 8;
        dot += q8[0] * b2f_lo(ku.x) + q8[1] * b2f_hi(ku.x) +
               q8[2] * b2f_lo(ku.y) + q8[3] * b2f_hi(ku.y) +
               q8[4] * b2f_lo(ku.z) + q8[5] * b2f_hi(ku.z) +
               q8[6] * b2f_lo(ku.w) + q8[7] * b2f_hi(ku.w);
      }
      float P = __expf(dot * 0.125f);
      ushort_t Pb = f2b(P);
      pt[u * 64 + lane] = Pb;
      float ps = bu2f(Pb);  // sum the rounded value for num/denom consistency
#pragma unroll
      for (int o2 = 1; o2 < 64; o2 <<= 1) ps += __shfl_xor(ps, o2);
      zs[mi] = ps;
    }
  }
  __syncthreads();
  // stage B: lane = d; accumulate P*V (coalesced V rows)
  float oacc[12] = {};
  for (int jb = 0; jb < 64; jb += 4) {
    float vv[4];
#pragma unroll
    for (int r = 0; r < 4; ++r)
      vv[r] = bu2f(v[((size_t)(b * L + j0 + jb + r)) * 512 + hh * 64 + lane]);
#pragma unroll
    for (int mi = 0; mi < 12; ++mi) {
      int u = w + mi * 4;
      if (u < S) {
        const ushort_t* p4 = &pt[u * 64 + jb];
        oacc[mi] += bu2f(p4[0]) * vv[0] + bu2f(p4[1]) * vv[1] +
                    bu2f(p4[2]) * vv[2] + bu2f(p4[3]) * vv[3];
      }
    }
  }
  size_t base = (size_t)js * CBNH + bh;
#pragma unroll
  for (int mi = 0; mi < 12; ++mi) {
    int u = w + mi * 4;
    if (u < S) {
      po[(base * SMAX + u) * 64 + lane] = oacc[mi];
      if (lane == 0) pz[base * SMAX + u] = zs[mi];
    }
  }
}

// ---------------- combine flash partials, /Z, scatter into ctx ----------------
__global__ void flash_finish(const float* __restrict__ pz, const float* __restrict__ po,
                             const int* __restrict__ top_idx, ushort_t* __restrict__ ctx,
                             int L, int S, int CBNH, int fj) {
  int gid = blockIdx.x * 256 + threadIdx.x;  // over CBNH*S*64
  if (gid >= CBNH * S * 64) return;
  int d = gid & 63;
  int r = gid >> 6;  // bh*S + u
  int u = r % S, bh = r / S;
  int hh = bh & 7, b = bh >> 3;
  float Z = 0.0f, O = 0.0f;
  for (int js = 0; js < fj; ++js) {
    size_t pi = ((size_t)js * CBNH + bh) * SMAX + u;
    Z += pz[pi];
    O += po[pi * 64 + d];
  }
  int l = top_idx[bh * S + u];
  ctx[((size_t)(b * L + l)) * 512 + hh * 64 + d] = f2b(O / Z);
}

// ---------------- maxpool window 3 stride 2 ----------------
__global__ void maxpool_kernel(const float* __restrict__ y, float* __restrict__ hout,
                               int L) {
  size_t gid = (size_t)blockIdx.x * 256 + threadIdx.x;  // CB*(L/2)*512
  int Lh = L >> 1;
  int o = (int)(gid & 511);
  size_t bj = gid >> 9;
  int j = (int)(bj % (size_t)Lh);
  int b = (int)(bj / (size_t)Lh);
  const float* base = y + ((size_t)(b * L + 2 * j)) * 512 + o;
  float mx = base[0];
  if (j > 0) mx = fmaxf(mx, base[-512]);
  mx = fmaxf(mx, base[512]);
  hout[gid] = mx;
}

// ---------------- final LN + projection ----------------
__global__ __launch_bounds__(256) void final_ln_proj(const float* __restrict__ h,
                                                     const float* __restrict__ g,
                                                     const float* __restrict__ bb,
                                                     const float* __restrict__ pw,
                                                     const float* __restrict__ pb,
                                                     float* __restrict__ out, int L) {
  int b = blockIdx.x / 47, l = blockIdx.x % 47;
  const float* hr = h + ((size_t)(b * L + l)) * 512;
  int t = threadIdx.x;
  float x0 = hr[t], x1 = hr[t + 256];
  float mean = blk_reduce_sum(x0 + x1) * (1.0f / 512.0f);
  float d0 = x0 - mean, d1 = x1 - mean;
  float var = blk_reduce_sum(d0 * d0 + d1 * d1) * (1.0f / 512.0f);
  float rstd = rsqrtf(var + 1e-5f);
  float y0 = d0 * rstd * g[t] + bb[t];
  float y1 = d1 * rstd * g[t + 256] + bb[t + 256];
  float dot = blk_reduce_sum(y0 * pw[t] + y1 * pw[t + 256]);
  if (t == 0) out[b * 47 + l] = dot + pb[0];
}

// ---------------- launcher ----------------
extern "C" void kernel_launch(void* const* d_in, const int* in_sizes, int n_in,
                              void* d_out, int out_size, void* d_ws, size_t ws_size,
                              hipStream_t stream) {
  const float* x = (const float*)d_in[0];
  const float* emb_W = (const float*)d_in[1];
  const float* emb_b = (const float*)d_in[2];
  const float* Wq = (const float*)d_in[3];
  const float* bq = (const float*)d_in[4];
  const float* Wk = (const float*)d_in[5];
  const float* bk = (const float*)d_in[6];
  const float* Wv = (const float*)d_in[7];
  const float* bv = (const float*)d_in[8];
  const float* Wo = (const float*)d_in[9];
  const float* bo = (const float*)d_in[10];
  const float* fW1 = (const float*)d_in[11];
  const float* fb1 = (const float*)d_in[12];
  const float* fW2 = (const float*)d_in[13];
  const float* fb2 = (const float*)d_in[14];
  const float* ln1g = (const float*)d_in[15];
  const float* ln1b = (const float*)d_in[16];
  const float* ln2g = (const float*)d_in[17];
  const float* ln2b = (const float*)d_in[18];
  const float* cW = (const float*)d_in[19];
  const float* cb = (const float*)d_in[20];
  const float* bng = (const float*)d_in[21];
  const float* bnb = (const float*)d_in[22];
  const float* flng = (const float*)d_in[23];
  const float* flnb = (const float*)d_in[24];
  const float* pW = (const float*)d_in[25];
  const float* pb = (const float*)d_in[26];
  float* out = (float*)d_out;

  // batch-group size from ws_size (try 16, 8, 4, 2, 1)
  int CB = 16;
  while (CB > 1) {
    size_t need = 35720704ull + (size_t)CB * 6782336ull;
    if (need * 4 <= ws_size) break;
    CB >>= 1;
  }
  const size_t CBseg = (size_t)CB * 2097152ull;  // CB*4096*512 (bf16 elems)
  const int CBNH = CB * NH;

  float* ws = (float*)d_ws;
  size_t off = 0;
  float* h = ws;                           off += 33554432ull;
  ushort_t* wbase = (ushort_t*)(ws + off); off += 1966080ull;
  ushort_t* WqkvT = wbase;                 // 1536 x 512 (q rows, k rows, v rows)
  ushort_t* WoT = wbase + 786432;
  ushort_t* W1b = wbase + 1048576;
  ushort_t* W2b = wbase + 2097152;
  ushort_t* Wcb = wbase + 3145728;
  float* bqkv = ws + off;                  off += 1536ull;
  ushort_t* gArea = (ushort_t*)(ws + off); off += (5ull * CBseg) / 2;
  ushort_t* hb = gArea;
  ushort_t* qb = gArea + CBseg;
  ushort_t* kbuf = gArea + 2 * CBseg;
  ushort_t* vb = gArea + 3 * CBseg;
  ushort_t* ctxb = gArea + 4 * CBseg;
  ushort_t* ybuf = qb;           // spans qb..ctxb (4*CBseg bf16)
  float* convY = (float*)qb;     // spans qb,kbuf (CBseg f32)
  float* Mbuf = ws + off;                  off += (size_t)CB * 32768;
  float* mv = ws + off;                    off += (size_t)CB * 512;
  int* topidx = (int*)(ws + off);          off += (size_t)CB * 384;
  int* idxbuf = (int*)(ws + off);          off += 196608ull;
  float* pzb = ws + off;                   off += (size_t)CB * 23040;   // FJMAX*NH*SMAX
  float* pob = ws + off;                   off += (size_t)CB * 1474560; // FJMAX*NH*SMAX*64
  float* mvpart = ws + off;                off += (size_t)CB * 8192;    // CB*16*512

  // embedding
  {
    size_t total = (size_t)NB * 4096 * DM;
    embed_kernel<<<(int)(total / 256), 256, 0, stream>>>(x, emb_W, emb_b, h);
  }

  int L = 4096;
  for (int i = 0; i < 3; ++i) {
    int S = (i == 0) ? 45 : (i == 1) ? 40 : 35;
    int ngroups = NB / CB;
    int Mg = CB * L;
    size_t segL = (size_t)Mg * 512;
    int fj = L / 64;  // key splits: 64 / 32 / 16

    // per-layer weight casts
    castT512<<<1024, 256, 0, stream>>>(Wq + (size_t)i * 262144, WqkvT);
    castT512<<<1024, 256, 0, stream>>>(Wk + (size_t)i * 262144, WqkvT + 262144);
    castT512<<<1024, 256, 0, stream>>>(Wv + (size_t)i * 262144, WqkvT + 524288);
    castT512<<<1024, 256, 0, stream>>>(Wo + (size_t)i * 262144, WoT);
    cast_bf16<<<1024, 256, 0, stream>>>(fW1 + (size_t)i * 1048576, W1b, 1048576);
    cast_bf16<<<1024, 256, 0, stream>>>(fW2 + (size_t)i * 1048576, W2b, 1048576);
    if (i < 2) cast_convW<<<3072, 256, 0, stream>>>(cW + (size_t)i * 786432, Wcb);
    concat3<<<6, 256, 0, stream>>>(bq + i * DM, bk + i * DM, bv + i * DM, bqkv);

    // JAX randint key
    uint32_t fa, fbk;
    tf2x32(0u, 42u, 0u, (uint32_t)i, &fa, &fbk);
    uint32_t a0, b0, a1, b1;
    tf2x32(fa, fbk, 0u, 2u, &a0, &b0);
    tf2x32(fa, fbk, 1u, 3u, &a1, &b1);
    int n = L * S;
    gen_idx_kernel<<<(n + 255) / 256, 256, 0, stream>>>(idxbuf, b0, b1, n, L - 1);

    // ---- attention per batch group ----
    for (int g = 0; g < ngroups; ++g) {
      float* hg = h + (size_t)g * segL;
      cast_bf16<<<(int)(segL / 1024), 256, 0, stream>>>(hg, hb, segL);
      dim3 gqkv(12, Mg / 128);
      mfma_gemm<2, 0><<<gqkv, 256, 0, stream>>>(hb, WqkvT, bqkv, nullptr, qb,
                                                nullptr, nullptr, 1536, 512,
                                                (int)CBseg);

      prob_scores_wave<<<(CB * L) / 4, 256, 0, stream>>>(qb, kbuf, idxbuf, Mbuf, L, S);
      topk_kernel<<<CBNH, 256, 0, stream>>>(Mbuf, topidx, L, S);

      mean_v_partial<<<dim3(CB, L / 256), 256, 0, stream>>>(vb, mvpart, L);
      mean_v_finish<<<CB, 512, 0, stream>>>(mvpart, mv, L, L / 256);
      fill_ctx<<<(int)(segL / 256), 256, 0, stream>>>(ctxb, mv, L);
      flash_attn<<<dim3(fj, CBNH), 256, 0, stream>>>(qb, kbuf, vb, topidx,
                                                     pzb, pob, L, S, CBNH);
      flash_finish<<<(CBNH * S * 64 + 255) / 256, 256, 0, stream>>>(
          pzb, pob, topidx, ctxb, L, S, CBNH, fj);

      dim3 gq(4, Mg / 128);
      mfma_gemm<0, 1><<<gq, 256, 0, stream>>>(ctxb, WoT, bo + i * DM, hg, nullptr,
                                              nullptr, nullptr, 512, 512, 0);
    }
    ln_inplace<<<NB * L, 256, 0, stream>>>(h, ln1g + i * DM, ln1b + i * DM);

    // ---- FF row-chunked ----
    int rows = NB * L;
    int R = CB * 4096;
    if (R > rows) R = rows;
    for (int r0 = 0; r0 < rows; r0 += R) {
      float* hr = h + (size_t)r0 * 512;
      size_t rseg = (size_t)R * 512;
      cast_bf16<<<(int)(rseg / 1024), 256, 0, stream>>>(hr, hb, rseg);
      dim3 g1(16, R / 128);
      mfma_gemm<0, 2><<<g1, 256, 0, stream>>>(hb, W1b, fb1 + i * DFF_, nullptr, ybuf,
                                              nullptr, nullptr, 2048, 512, 0);
      dim3 g2(4, R / 128);
      mfma_gemm<0, 1><<<g2, 256, 0, stream>>>(ybuf, W2b, fb2 + i * DM, hr, nullptr,
                                              nullptr, nullptr, 512, 2048, 0);
    }
    ln_inplace<<<NB * L, 256, 0, stream>>>(h, ln2g + i * DM, ln2b + i * DM);

    // ---- conv + maxpool per batch group ----
    if (i < 2) {
      int Lh = L / 2;
      for (int g = 0; g < ngroups; ++g) {
        float* hg = h + (size_t)g * segL;
        cast_bf16<<<(int)(segL / 1024), 256, 0, stream>>>(hg, hb, segL);
        dim3 gc(4, Mg / 128);
        mfma_gemm<1, 3><<<gc, 256, 0, stream>>>(hb, Wcb, cb + i * DM, convY, nullptr,
                                                bng + i * DM, bnb + i * DM, 512, 1536, L);
        size_t tot = (size_t)CB * Lh * 512;
        maxpool_kernel<<<(int)(tot / 256), 256, 0, stream>>>(
            convY, h + (size_t)g * CB * Lh * 512, L);
      }
      L = Lh;
    }
  }

  final_ln_proj<<<NB * 47, 256, 0, stream>>>(h, flng, flnb, pW, pb, out, L);
}

// Round 11
// 4247.564 us; speedup vs baseline: 2.2252x; 1.1778x over previous
//
#include <hip/hip_runtime.h>
#include <cstdint>
#include <math.h>

#define NB 16
#define DM 512
#define NH 8
#define DFF_ 2048
#define SMAX 45

typedef unsigned short ushort_t;
typedef __bf16 bf16x8 __attribute__((ext_vector_type(8)));
typedef float f32x4 __attribute__((ext_vector_type(4)));

// ---------------- bf16 helpers ----------------
__device__ __forceinline__ ushort_t f2b(float f) {  // RNE f32 -> bf16 bits
  uint32_t u = __float_as_uint(f);
  uint32_t r = (u + 0x7FFFu + ((u >> 16) & 1u)) >> 16;
  return (ushort_t)r;
}
__device__ __forceinline__ float bu2f(ushort_t x) {
  return __uint_as_float((uint32_t)x << 16);
}
__device__ __forceinline__ float b2f_lo(uint32_t u) { return __uint_as_float(u << 16); }
__device__ __forceinline__ float b2f_hi(uint32_t u) { return __uint_as_float(u & 0xFFFF0000u); }

// ---------------- threefry2x32 (JAX-compatible) ----------------
__host__ __device__ inline void tf2x32(uint32_t k0, uint32_t k1,
                                       uint32_t x0, uint32_t x1,
                                       uint32_t* o0, uint32_t* o1) {
  uint32_t ks0 = k0, ks1 = k1, ks2 = k0 ^ k1 ^ 0x1BD11BDAu;
  x0 += ks0; x1 += ks1;
#define TF_RND(r) { x0 += x1; x1 = (x1 << (r)) | (x1 >> (32 - (r))); x1 ^= x0; }
  TF_RND(13) TF_RND(15) TF_RND(26) TF_RND(6)
  x0 += ks1; x1 += ks2 + 1u;
  TF_RND(17) TF_RND(29) TF_RND(16) TF_RND(24)
  x0 += ks2; x1 += ks0 + 2u;
  TF_RND(13) TF_RND(15) TF_RND(26) TF_RND(6)
  x0 += ks0; x1 += ks1 + 3u;
  TF_RND(17) TF_RND(29) TF_RND(16) TF_RND(24)
  x0 += ks1; x1 += ks2 + 4u;
  TF_RND(13) TF_RND(15) TF_RND(26) TF_RND(6)
  x0 += ks2; x1 += ks0 + 5u;
#undef TF_RND
  *o0 = x0; *o1 = x1;
}

__global__ void gen_idx_kernel(int* __restrict__ idx, uint32_t k0, uint32_t k1,
                               int n, int mask) {
  int j = blockIdx.x * 256 + threadIdx.x;
  if (j >= n) return;
  int half = n >> 1;
  uint32_t o0, o1;
  if (j < half) {
    tf2x32(k0, k1, (uint32_t)j, (uint32_t)(j + half), &o0, &o1);
    idx[j] = (int)(o0 & (uint32_t)mask);
  } else {
    tf2x32(k0, k1, (uint32_t)(j - half), (uint32_t)j, &o0, &o1);
    idx[j] = (int)(o1 & (uint32_t)mask);
  }
}

// ---------------- block reduce helpers (256 threads, wave64) ----------------
__device__ inline float blk_reduce_sum(float v) {
  __shared__ float s[4];
  for (int o = 32; o > 0; o >>= 1) v += __shfl_down(v, o);
  int lane = threadIdx.x & 63, w = threadIdx.x >> 6;
  if (lane == 0) s[w] = v;
  __syncthreads();
  float r = s[0] + s[1] + s[2] + s[3];
  __syncthreads();
  return r;
}

// ---------------- embedding (float4 per thread) ----------------
__global__ void embed_kernel(const float* __restrict__ x, const float* __restrict__ W,
                             const float* __restrict__ bias, float* __restrict__ h) {
  size_t gid = (size_t)blockIdx.x * 256 + threadIdx.x;  // over NB*4096*128 quads
  int o4 = (int)(gid & 127) * 4;
  size_t bl = gid >> 7;
  const float* xr = x + bl * 7;
  float xv[7];
#pragma unroll
  for (int i = 0; i < 7; ++i) xv[i] = xr[i];
  float4 acc = *(const float4*)(bias + o4);
#pragma unroll
  for (int i = 0; i < 7; ++i) {
    float4 w4 = *(const float4*)(W + i * 512 + o4);
    acc.x += xv[i] * w4.x;
    acc.y += xv[i] * w4.y;
    acc.z += xv[i] * w4.z;
    acc.w += xv[i] * w4.w;
  }
  *(float4*)(h + bl * 512 + o4) = acc;
}

// ---------------- cast kernels ----------------
__global__ void cast_bf16(const float* __restrict__ src, ushort_t* __restrict__ dst,
                          size_t n) {
  size_t i = ((size_t)blockIdx.x * 256 + threadIdx.x) * 4;
  if (i >= n) return;
  float4 v = *(const float4*)(src + i);
  ushort4 o;
  o.x = f2b(v.x); o.y = f2b(v.y); o.z = f2b(v.z); o.w = f2b(v.w);
  *(ushort4*)(dst + i) = o;
}

// Bt[n*512+k] = bf16(W[k*512+n])   (512x512)
__global__ void castT512(const float* __restrict__ W, ushort_t* __restrict__ Bt) {
  int gid = blockIdx.x * 256 + threadIdx.x;
  int n = gid >> 9, k = gid & 511;
  Bt[gid] = f2b(W[(size_t)k * 512 + n]);
}

// Bt[n*1536 + dt*512 + i] = bf16(convW[n][i][dt])
__global__ void cast_convW(const float* __restrict__ W, ushort_t* __restrict__ Bt) {
  int gid = blockIdx.x * 256 + threadIdx.x;
  int n = gid / 1536, k = gid - n * 1536;
  int dt = k >> 9, ii = k & 511;
  Bt[gid] = f2b(W[((size_t)n * 512 + ii) * 3 + dt]);
}

// concat 3x512 bias -> 1536
__global__ void concat3(const float* __restrict__ a, const float* __restrict__ b,
                        const float* __restrict__ c, float* __restrict__ o) {
  int t = blockIdx.x * 256 + threadIdx.x;
  if (t >= 1536) return;
  o[t] = t < 512 ? a[t] : (t < 1024 ? b[t - 512] : c[t - 1024]);
}

// ---------------- bf16 MFMA GEMM (m97 structure) ----------------
// MODE 0: standard  1: conv circular-A  2: QKV fused (route by bn>>2 into
//         three CBseg-strided bf16 buffers; L param carries CBseg)
__device__ __forceinline__ float gelu_exact(float c) {
  return 0.5f * c * (1.0f + erff(c * 0.70710678118654752f));
}

template <int MODE, int EPI>
__global__ __launch_bounds__(256) void mfma_gemm(
    const ushort_t* __restrict__ A, const ushort_t* __restrict__ Bt,
    const float* __restrict__ bias, float* __restrict__ Cf,
    ushort_t* __restrict__ Cb, const float* __restrict__ bng,
    const float* __restrict__ bnb, int N, int K, int L) {
  __shared__ __align__(16) ushort_t As[128 * 64];
  __shared__ __align__(16) ushort_t Bs[128 * 64];
  const int tid = threadIdx.x;
  const int lane = tid & 63;
  const int wid = tid >> 6;
  const int wr = wid >> 1, wc = wid & 1;
  const int bm = blockIdx.y, bn = blockIdx.x;
  const int ln = lane & 15, lh = lane >> 4;

  f32x4 acc[4][4] = {};

  for (int k0 = 0; k0 < K; k0 += 64) {
    __syncthreads();
#pragma unroll
    for (int it = 0; it < 4; ++it) {
      int c = it * 256 + tid;
      int row = c >> 3, kc = (c & 7) * 8;
      size_t ga;
      if (MODE == 1) {
        int m = bm * 128 + row;
        int b = m / L, tpos = m - b * L;
        int k = k0 + kc;
        int dt = k >> 9, ii = k & 511;
        int tr2 = tpos + dt - 1;
        if (tr2 < 0) tr2 += L;
        if (tr2 >= L) tr2 -= L;
        ga = ((size_t)(b * L + tr2)) * 512 + ii;
      } else {
        ga = (size_t)(bm * 128 + row) * K + k0 + kc;
      }
      __builtin_amdgcn_global_load_lds(
          (const __attribute__((address_space(1))) void*)(A + ga),
          (__attribute__((address_space(3))) void*)(As + c * 8), 16, 0, 0);
      size_t gb = (size_t)(bn * 128 + row) * K + k0 + kc;
      __builtin_amdgcn_global_load_lds(
          (const __attribute__((address_space(1))) void*)(Bt + gb),
          (__attribute__((address_space(3))) void*)(Bs + c * 8), 16, 0, 0);
    }
    __syncthreads();
#pragma unroll
    for (int kk = 0; kk < 2; ++kk) {
      bf16x8 af[4], bf_[4];
#pragma unroll
      for (int m = 0; m < 4; ++m)
        af[m] = *(const bf16x8*)&As[(wr * 64 + m * 16 + ln) * 64 + kk * 32 + lh * 8];
#pragma unroll
      for (int n = 0; n < 4; ++n)
        bf_[n] = *(const bf16x8*)&Bs[(wc * 64 + n * 16 + ln) * 64 + kk * 32 + lh * 8];
#pragma unroll
      for (int m = 0; m < 4; ++m)
#pragma unroll
        for (int n = 0; n < 4; ++n)
          acc[m][n] =
              __builtin_amdgcn_mfma_f32_16x16x32_bf16(af[m], bf_[n], acc[m][n], 0, 0, 0);
    }
  }

  const float bnscale = 0.9999950000374996f;  // 1/sqrt(1+1e-5)
#pragma unroll
  for (int m = 0; m < 4; ++m) {
    int row = bm * 128 + wr * 64 + m * 16 + lh * 4;
#pragma unroll
    for (int n = 0; n < 4; ++n) {
      int col = bn * 128 + wc * 64 + n * 16 + ln;
      float bsv = bias[col];
#pragma unroll
      for (int r = 0; r < 4; ++r) {
        float cval = acc[m][n][r] + bsv;
        if (MODE == 2) {
          ushort_t* dst = Cb + (size_t)(bn >> 2) * (size_t)L;  // L = CBseg
          dst[(size_t)(row + r) * 512 + (col & 511)] = f2b(cval);
        } else {
          size_t oi = (size_t)(row + r) * N + col;
          if (EPI == 0) {
            Cb[oi] = f2b(cval);
          } else if (EPI == 1) {
            Cf[oi] += cval;
          } else if (EPI == 2) {
            Cb[oi] = f2b(gelu_exact(cval));
          } else {
            float c2 = cval * bnscale * bng[col] + bnb[col];
            Cf[oi] = c2 > 0.0f ? c2 : expm1f(c2);
          }
        }
      }
    }
  }
}

// ---------------- LN (in-place, row = 512) ----------------
__global__ __launch_bounds__(256) void ln_inplace(float* __restrict__ h,
                                                  const float* __restrict__ g,
                                                  const float* __restrict__ b) {
  size_t row = blockIdx.x;
  float* hr = h + row * 512;
  int t = threadIdx.x;
  float x0 = hr[t], x1 = hr[t + 256];
  float mean = blk_reduce_sum(x0 + x1) * (1.0f / 512.0f);
  float d0 = x0 - mean, d1 = x1 - mean;
  float var = blk_reduce_sum(d0 * d0 + d1 * d1) * (1.0f / 512.0f);
  float rstd = rsqrtf(var + 1e-5f);
  hr[t] = d0 * rstd * g[t] + b[t];
  hr[t + 256] = d1 * rstd * g[t + 256] + b[t + 256];
}

// ---------------- prob-sparse M scores: one wave per (b,l), coalesced 1KB K rows ----
__global__ __launch_bounds__(256) void prob_scores_wave(const ushort_t* __restrict__ q,
                                                        const ushort_t* __restrict__ k,
                                                        const int* __restrict__ idx,
                                                        float* __restrict__ Mout,
                                                        int L, int S) {
  int wv = (blockIdx.x << 2) + ((threadIdx.x) >> 6);  // wave id over CB*L
  int lane = threadIdx.x & 63;
  int l = wv % L;
  int b = wv / L;
  const ushort_t* qr = q + ((size_t)(b * L + l)) * 512 + lane * 8;
  uint4 qu = *(const uint4*)qr;
  float qf[8];
  qf[0] = b2f_lo(qu.x); qf[1] = b2f_hi(qu.x);
  qf[2] = b2f_lo(qu.y); qf[3] = b2f_hi(qu.y);
  qf[4] = b2f_lo(qu.z); qf[5] = b2f_hi(qu.z);
  qf[6] = b2f_lo(qu.w); qf[7] = b2f_hi(qu.w);
  const int* il = idx + l * S;
  const ushort_t* kb = k + (size_t)b * L * 512 + lane * 8;
  float m = -INFINITY, ssum = 0.0f;
  for (int s = 0; s < S; ++s) {
    int j = il[s];
    uint4 ku = *(const uint4*)(kb + (size_t)j * 512);
    float dot = qf[0] * b2f_lo(ku.x) + qf[1] * b2f_hi(ku.x) +
                qf[2] * b2f_lo(ku.y) + qf[3] * b2f_hi(ku.y) +
                qf[4] * b2f_lo(ku.z) + qf[5] * b2f_hi(ku.z) +
                qf[6] * b2f_lo(ku.w) + qf[7] * b2f_hi(ku.w);
    dot += __shfl_xor(dot, 1);
    dot += __shfl_xor(dot, 2);
    dot += __shfl_xor(dot, 4);
    m = fmaxf(m, dot);
    ssum += dot;
  }
  if ((lane & 7) == 0) {
    int hh = lane >> 3;
    Mout[((size_t)(b * 8 + hh)) * L + l] = m - ssum / (float)L;
  }
}

// ---------------- top-k: register-cached iterative argmax ----------------
__global__ __launch_bounds__(256) void topk_kernel(const float* __restrict__ Mbuf,
                                                   int* __restrict__ top_idx,
                                                   int L, int S) {
  int bh = blockIdx.x;
  __shared__ float vals[4096];
  __shared__ float rw[4];
  __shared__ int ri2[4];
  const float* Mr = Mbuf + (size_t)bh * L;
  int t = threadIdx.x;
  int lane = t & 63, w = t >> 6;
  int chunk = L >> 8;  // L/256
  int base = t * chunk;
  for (int j = t; j < L; j += 256) vals[j] = Mr[j];
  __syncthreads();
  float lmax = -INFINITY;
  int lidx = 1 << 30;
  for (int i = 0; i < chunk; ++i) {
    float vv = vals[base + i];
    if (vv > lmax || (vv == lmax && base + i < lidx)) { lmax = vv; lidx = base + i; }
  }
  for (int it = 0; it < S; ++it) {
    float v2 = lmax;
    int i2 = lidx;
#pragma unroll
    for (int o2 = 1; o2 < 64; o2 <<= 1) {
      float ov = __shfl_xor(v2, o2);
      int oi = __shfl_xor(i2, o2);
      if (ov > v2 || (ov == v2 && oi < i2)) { v2 = ov; i2 = oi; }
    }
    if (lane == 0) { rw[w] = v2; ri2[w] = i2; }
    __syncthreads();
    float bv = rw[0];
    int bi = ri2[0];
#pragma unroll
    for (int ww = 1; ww < 4; ++ww) {
      float ov = rw[ww];
      int oi = ri2[ww];
      if (ov > bv || (ov == bv && oi < bi)) { bv = ov; bi = oi; }
    }
    if (t == 0) top_idx[bh * S + it] = bi;
    if (bi >= base && bi < base + chunk) {
      vals[bi] = -INFINITY;
      lmax = -INFINITY;
      lidx = 1 << 30;
      for (int i = 0; i < chunk; ++i) {
        float vv = vals[base + i];
        if (vv > lmax || (vv == lmax && base + i < lidx)) { lmax = vv; lidx = base + i; }
      }
    }
    __syncthreads();
  }
}

// ---------------- mean of V: stage 1 (coalesced column partial sums) ----------------
__global__ __launch_bounds__(256) void mean_v_partial(const ushort_t* __restrict__ v,
                                                      float* __restrict__ part, int L) {
  int b = blockIdx.x;
  int chunk = blockIdx.y;
  int t = threadIdx.x;
  int c = t * 2;
  const ushort_t* base = v + ((size_t)b * L + (size_t)chunk * 256) * 512 + c;
  float a0 = 0.0f, a1 = 0.0f;
#pragma unroll 8
  for (int r = 0; r < 256; ++r) {
    uint32_t u = *(const uint32_t*)(base + (size_t)r * 512);
    a0 += b2f_lo(u);
    a1 += b2f_hi(u);
  }
  float* p = part + ((size_t)b * 16 + chunk) * 512 + c;
  p[0] = a0;
  p[1] = a1;
}

// ---------------- mean of V: stage 2 ----------------
__global__ void mean_v_finish(const float* __restrict__ part, float* __restrict__ mv,
                              int L, int nchunks) {
  int b = blockIdx.x;
  int c = threadIdx.x;  // 512 threads
  float s = 0.0f;
  for (int k = 0; k < nchunks; ++k) s += part[((size_t)b * 16 + k) * 512 + c];
  mv[b * 512 + c] = s / (float)L;
}

// ---------------- fill ctx (bf16) with broadcast mean ----------------
__global__ void fill_ctx(ushort_t* __restrict__ ctx, const float* __restrict__ mv,
                         int L) {
  size_t gid = (size_t)blockIdx.x * 256 + threadIdx.x;  // CB*L*512
  int c = (int)(gid & 511);
  size_t bl = gid >> 9;
  int b = (int)(bl / (size_t)L);
  ctx[gid] = f2b(mv[b * 512 + c]);
}

// ---------------- fused flash attention (no-max softmax: scores bounded) ----------
// grid (fj = L/64, CBNH). Each block: 64 keys for all S queries of one bh.
// P = exp(score) directly; per-split partials (z, O-unnormalized).
__global__ __launch_bounds__(256) void flash_attn(const ushort_t* __restrict__ q,
                                                  const ushort_t* __restrict__ k,
                                                  const ushort_t* __restrict__ v,
                                                  const int* __restrict__ top_idx,
                                                  float* __restrict__ pz,
                                                  float* __restrict__ po,
                                                  int L, int S, int CBNH) {
  __shared__ float qs[SMAX * 64];
  __shared__ ushort_t pt[SMAX * 64];
  int bh = blockIdx.y, js = blockIdx.x;
  int hh = bh & 7, b = bh >> 3;
  int t = threadIdx.x;
  int lane = t & 63, w = t >> 6;
  for (int e = t; e < S * 64; e += 256) {
    int u = e >> 6, d = e & 63;
    int l = top_idx[bh * S + u];
    qs[e] = bu2f(q[((size_t)(b * L + l)) * 512 + hh * 64 + d]);
  }
  __syncthreads();
  int j0 = js * 64;
  // stage A: lane = key; K row in registers; P = exp(score) -> LDS (bf16)
  const ushort_t* kr = k + ((size_t)(b * L + j0 + lane)) * 512 + hh * 64;
  uint4 kreg[8];
#pragma unroll
  for (int c = 0; c < 8; ++c) kreg[c] = ((const uint4*)kr)[c];
  float zs[12];
#pragma unroll
  for (int mi = 0; mi < 12; ++mi) {
    int u = w + mi * 4;
    if (u < S) {
      const float* qu = qs + u * 64;
      float dot = 0.0f;
#pragma unroll
      for (int c = 0; c < 8; ++c) {
        uint4 ku = kreg[c];
        const float* q8 = qu + c * 8;
        dot += q8[0] * b2f_lo(ku.x) + q8[1] * b2f_hi(ku.x) +
               q8[2] * b2f_lo(ku.y) + q8[3] * b2f_hi(ku.y) +
               q8[4] * b2f_lo(ku.z) + q8[5] * b2f_hi(ku.z) +
               q8[6] * b2f_lo(ku.w) + q8[7] * b2f_hi(ku.w);
      }
      float P = __expf(dot * 0.125f);
      ushort_t Pb = f2b(P);
      pt[u * 64 + lane] = Pb;
      float ps = bu2f(Pb);  // sum the rounded value for num/denom consistency
#pragma unroll
      for (int o2 = 1; o2 < 64; o2 <<= 1) ps += __shfl_xor(ps, o2);
      zs[mi] = ps;
    }
  }
  __syncthreads();
  // stage B: lane = d; accumulate P*V (coalesced V rows)
  float oacc[12] = {};
  for (int jb = 0; jb < 64; jb += 4) {
    float vv[4];
#pragma unroll
    for (int r = 0; r < 4; ++r)
      vv[r] = bu2f(v[((size_t)(b * L + j0 + jb + r)) * 512 + hh * 64 + lane]);
#pragma unroll
    for (int mi = 0; mi < 12; ++mi) {
      int u = w + mi * 4;
      if (u < S) {
        const ushort_t* p4 = &pt[u * 64 + jb];
        oacc[mi] += bu2f(p4[0]) * vv[0] + bu2f(p4[1]) * vv[1] +
                    bu2f(p4[2]) * vv[2] + bu2f(p4[3]) * vv[3];
      }
    }
  }
  size_t base = (size_t)js * CBNH + bh;
#pragma unroll
  for (int mi = 0; mi < 12; ++mi) {
    int u = w + mi * 4;
    if (u < S) {
      po[(base * SMAX + u) * 64 + lane] = oacc[mi];
      if (lane == 0) pz[base * SMAX + u] = zs[mi];
    }
  }
}

// ---------------- combine flash partials, /Z, scatter into ctx ----------------
__global__ void flash_finish(const float* __restrict__ pz, const float* __restrict__ po,
                             const int* __restrict__ top_idx, ushort_t* __restrict__ ctx,
                             int L, int S, int CBNH, int fj) {
  int gid = blockIdx.x * 256 + threadIdx.x;  // over CBNH*S*64
  if (gid >= CBNH * S * 64) return;
  int d = gid & 63;
  int r = gid >> 6;  // bh*S + u
  int u = r % S, bh = r / S;
  int hh = bh & 7, b = bh >> 3;
  float Z = 0.0f, O = 0.0f;
  for (int js = 0; js < fj; ++js) {
    size_t pi = ((size_t)js * CBNH + bh) * SMAX + u;
    Z += pz[pi];
    O += po[pi * 64 + d];
  }
  int l = top_idx[bh * S + u];
  ctx[((size_t)(b * L + l)) * 512 + hh * 64 + d] = f2b(O / Z);
}

// ---------------- maxpool window 3 stride 2 ----------------
__global__ void maxpool_kernel(const float* __restrict__ y, float* __restrict__ hout,
                               int L) {
  size_t gid = (size_t)blockIdx.x * 256 + threadIdx.x;  // CB*(L/2)*512
  int Lh = L >> 1;
  int o = (int)(gid & 511);
  size_t bj = gid >> 9;
  int j = (int)(bj % (size_t)Lh);
  int b = (int)(bj / (size_t)Lh);
  const float* base = y + ((size_t)(b * L + 2 * j)) * 512 + o;
  float mx = base[0];
  if (j > 0) mx = fmaxf(mx, base[-512]);
  mx = fmaxf(mx, base[512]);
  hout[gid] = mx;
}

// ---------------- final LN + projection ----------------
__global__ __launch_bounds__(256) void final_ln_proj(const float* __restrict__ h,
                                                     const float* __restrict__ g,
                                                     const float* __restrict__ bb,
                                                     const float* __restrict__ pw,
                                                     const float* __restrict__ pb,
                                                     float* __restrict__ out, int L) {
  int b = blockIdx.x / 47, l = blockIdx.x % 47;
  const float* hr = h + ((size_t)(b * L + l)) * 512;
  int t = threadIdx.x;
  float x0 = hr[t], x1 = hr[t + 256];
  float mean = blk_reduce_sum(x0 + x1) * (1.0f / 512.0f);
  float d0 = x0 - mean, d1 = x1 - mean;
  float var = blk_reduce_sum(d0 * d0 + d1 * d1) * (1.0f / 512.0f);
  float rstd = rsqrtf(var + 1e-5f);
  float y0 = d0 * rstd * g[t] + bb[t];
  float y1 = d1 * rstd * g[t + 256] + bb[t + 256];
  float dot = blk_reduce_sum(y0 * pw[t] + y1 * pw[t + 256]);
  if (t == 0) out[b * 47 + l] = dot + pb[0];
}

// ---------------- launcher ----------------
extern "C" void kernel_launch(void* const* d_in, const int* in_sizes, int n_in,
                              void* d_out, int out_size, void* d_ws, size_t ws_size,
                              hipStream_t stream) {
  const float* x = (const float*)d_in[0];
  const float* emb_W = (const float*)d_in[1];
  const float* emb_b = (const float*)d_in[2];
  const float* Wq = (const float*)d_in[3];
  const float* bq = (const float*)d_in[4];
  const float* Wk = (const float*)d_in[5];
  const float* bk = (const float*)d_in[6];
  const float* Wv = (const float*)d_in[7];
  const float* bv = (const float*)d_in[8];
  const float* Wo = (const float*)d_in[9];
  const float* bo = (const float*)d_in[10];
  const float* fW1 = (const float*)d_in[11];
  const float* fb1 = (const float*)d_in[12];
  const float* fW2 = (const float*)d_in[13];
  const float* fb2 = (const float*)d_in[14];
  const float* ln1g = (const float*)d_in[15];
  const float* ln1b = (const float*)d_in[16];
  const float* ln2g = (const float*)d_in[17];
  const float* ln2b = (const float*)d_in[18];
  const float* cW = (const float*)d_in[19];
  const float* cb = (const float*)d_in[20];
  const float* bng = (const float*)d_in[21];
  const float* bnb = (const float*)d_in[22];
  const float* flng = (const float*)d_in[23];
  const float* flnb = (const float*)d_in[24];
  const float* pW = (const float*)d_in[25];
  const float* pb = (const float*)d_in[26];
  float* out = (float*)d_out;

  // base batch-group size from ws_size (try 16, 8, 4, 2, 1)
  // need(CB0) = 35,732,992 + CB0 * 6,806,016 floats (layer-adaptive buffers const in bytes)
  int CB0 = 16;
  while (CB0 > 1) {
    size_t need = 35732992ull + (size_t)CB0 * 6806016ull;
    if (need * 4 <= ws_size) break;
    CB0 >>= 1;
  }
  const size_t CBseg = (size_t)CB0 * 2097152ull;  // CB0*4096*512 (bf16 elems)

  float* ws = (float*)d_ws;
  size_t off = 0;
  float* h = ws;                           off += 33554432ull;
  ushort_t* wbase = (ushort_t*)(ws + off); off += 1966080ull;
  ushort_t* WqkvT = wbase;                 // 1536 x 512 (q rows, k rows, v rows)
  ushort_t* WoT = wbase + 786432;
  ushort_t* W1b = wbase + 1048576;
  ushort_t* W2b = wbase + 2097152;
  ushort_t* Wcb = wbase + 3145728;
  float* bqkv = ws + off;                  off += 1536ull;
  ushort_t* gArea = (ushort_t*)(ws + off); off += (5ull * CBseg) / 2;
  ushort_t* hb = gArea;
  ushort_t* qb = gArea + CBseg;
  ushort_t* kbuf = gArea + 2 * CBseg;
  ushort_t* vb = gArea + 3 * CBseg;
  ushort_t* ctxb = gArea + 4 * CBseg;
  ushort_t* ybuf = qb;           // spans qb..ctxb (4*CBseg bf16)
  float* convY = (float*)qb;     // spans qb,kbuf (CBseg f32)
  float* Mbuf = ws + off;                  off += (size_t)CB0 * 32768;
  float* mv = ws + off;                    off += 8192ull;               // 16*512
  int* topidx = (int*)(ws + off);          off += 6144ull;               // 16*8*48
  int* idxbuf = (int*)(ws + off);          off += 196608ull;
  float* pzb = ws + off;                   off += (size_t)CB0 * 23040;   // (fj*CBNH=512*CB0)*SMAX
  float* pob = ws + off;                   off += (size_t)CB0 * 1474560; // ... *64
  float* mvpart = ws + off;                off += 131072ull;             // 16*16*512

  // embedding (float4 per thread)
  {
    size_t total = (size_t)NB * 4096 * 128;
    embed_kernel<<<(int)(total / 256), 256, 0, stream>>>(x, emb_W, emb_b, h);
  }

  int L = 4096;
  for (int i = 0; i < 3; ++i) {
    int S = (i == 0) ? 45 : (i == 1) ? 40 : 35;
    // layer-adaptive group size: same bytes per group across layers
    int CBl = CB0 * (4096 / L);
    if (CBl > NB) CBl = NB;
    int ngroups = NB / CBl;
    int CBNHl = CBl * NH;
    int Mg = CBl * L;                      // rows per group (const when uncapped)
    size_t segL = (size_t)Mg * 512;
    int fj = L / 64;                       // key splits: 64 / 32 / 16

    // per-layer weight casts
    castT512<<<1024, 256, 0, stream>>>(Wq + (size_t)i * 262144, WqkvT);
    castT512<<<1024, 256, 0, stream>>>(Wk + (size_t)i * 262144, WqkvT + 262144);
    castT512<<<1024, 256, 0, stream>>>(Wv + (size_t)i * 262144, WqkvT + 524288);
    castT512<<<1024, 256, 0, stream>>>(Wo + (size_t)i * 262144, WoT);
    cast_bf16<<<1024, 256, 0, stream>>>(fW1 + (size_t)i * 1048576, W1b, 1048576);
    cast_bf16<<<1024, 256, 0, stream>>>(fW2 + (size_t)i * 1048576, W2b, 1048576);
    if (i < 2) cast_convW<<<3072, 256, 0, stream>>>(cW + (size_t)i * 786432, Wcb);
    concat3<<<6, 256, 0, stream>>>(bq + i * DM, bk + i * DM, bv + i * DM, bqkv);

    // JAX randint key
    uint32_t fa, fbk;
    tf2x32(0u, 42u, 0u, (uint32_t)i, &fa, &fbk);
    uint32_t a0, b0, a1, b1;
    tf2x32(fa, fbk, 0u, 2u, &a0, &b0);
    tf2x32(fa, fbk, 1u, 3u, &a1, &b1);
    int n = L * S;
    gen_idx_kernel<<<(n + 255) / 256, 256, 0, stream>>>(idxbuf, b0, b1, n, L - 1);

    // ---- attention per batch group ----
    for (int g = 0; g < ngroups; ++g) {
      float* hg = h + (size_t)g * segL;
      cast_bf16<<<(int)(segL / 1024), 256, 0, stream>>>(hg, hb, segL);
      dim3 gqkv(12, Mg / 128);
      mfma_gemm<2, 0><<<gqkv, 256, 0, stream>>>(hb, WqkvT, bqkv, nullptr, qb,
                                                nullptr, nullptr, 1536, 512,
                                                (int)CBseg);

      prob_scores_wave<<<(CBl * L) / 4, 256, 0, stream>>>(qb, kbuf, idxbuf, Mbuf, L, S);
      topk_kernel<<<CBNHl, 256, 0, stream>>>(Mbuf, topidx, L, S);

      mean_v_partial<<<dim3(CBl, L / 256), 256, 0, stream>>>(vb, mvpart, L);
      mean_v_finish<<<CBl, 512, 0, stream>>>(mvpart, mv, L, L / 256);
      fill_ctx<<<(int)(segL / 256), 256, 0, stream>>>(ctxb, mv, L);
      flash_attn<<<dim3(fj, CBNHl), 256, 0, stream>>>(qb, kbuf, vb, topidx,
                                                      pzb, pob, L, S, CBNHl);
      flash_finish<<<(CBNHl * S * 64 + 255) / 256, 256, 0, stream>>>(
          pzb, pob, topidx, ctxb, L, S, CBNHl, fj);

      dim3 gq(4, Mg / 128);
      mfma_gemm<0, 1><<<gq, 256, 0, stream>>>(ctxb, WoT, bo + i * DM, hg, nullptr,
                                              nullptr, nullptr, 512, 512, 0);
    }
    ln_inplace<<<NB * L, 256, 0, stream>>>(h, ln1g + i * DM, ln1b + i * DM);

    // ---- FF row-chunked ----
    int rows = NB * L;
    int R = CB0 * 4096;
    if (R > rows) R = rows;
    for (int r0 = 0; r0 < rows; r0 += R) {
      float* hr = h + (size_t)r0 * 512;
      size_t rseg = (size_t)R * 512;
      cast_bf16<<<(int)(rseg / 1024), 256, 0, stream>>>(hr, hb, rseg);
      dim3 g1(16, R / 128);
      mfma_gemm<0, 2><<<g1, 256, 0, stream>>>(hb, W1b, fb1 + i * DFF_, nullptr, ybuf,
                                              nullptr, nullptr, 2048, 512, 0);
      dim3 g2(4, R / 128);
      mfma_gemm<0, 1><<<g2, 256, 0, stream>>>(ybuf, W2b, fb2 + i * DM, hr, nullptr,
                                              nullptr, nullptr, 512, 2048, 0);
    }
    ln_inplace<<<NB * L, 256, 0, stream>>>(h, ln2g + i * DM, ln2b + i * DM);

    // ---- conv + maxpool per batch group ----
    if (i < 2) {
      int Lh = L / 2;
      for (int g = 0; g < ngroups; ++g) {
        float* hg = h + (size_t)g * segL;
        cast_bf16<<<(int)(segL / 1024), 256, 0, stream>>>(hg, hb, segL);
        dim3 gc(4, Mg / 128);
        mfma_gemm<1, 3><<<gc, 256, 0, stream>>>(hb, Wcb, cb + i * DM, convY, nullptr,
                                                bng + i * DM, bnb + i * DM, 512, 1536, L);
        size_t tot = (size_t)CBl * Lh * 512;
        maxpool_kernel<<<(int)(tot / 256), 256, 0, stream>>>(
            convY, h + (size_t)g * CBl * Lh * 512, L);
      }
      L = Lh;
    }
  }

  final_ln_proj<<<NB * 47, 256, 0, stream>>>(h, flng, flnb, pW, pb, out, L);
}

// Round 12
// 3821.566 us; speedup vs baseline: 2.4733x; 1.1115x over previous
//
#include <hip/hip_runtime.h>
#include <cstdint>
#include <math.h>

#define NB 16
#define DM 512
#define NH 8
#define DFF_ 2048
#define SMAX 45

typedef unsigned short ushort_t;
typedef __bf16 bf16x8 __attribute__((ext_vector_type(8)));
typedef float f32x4 __attribute__((ext_vector_type(4)));

// ---------------- bf16 helpers ----------------
__device__ __forceinline__ ushort_t f2b(float f) {  // RNE f32 -> bf16 bits
  uint32_t u = __float_as_uint(f);
  uint32_t r = (u + 0x7FFFu + ((u >> 16) & 1u)) >> 16;
  return (ushort_t)r;
}
__device__ __forceinline__ float bu2f(ushort_t x) {
  return __uint_as_float((uint32_t)x << 16);
}
__device__ __forceinline__ float b2f_lo(uint32_t u) { return __uint_as_float(u << 16); }
__device__ __forceinline__ float b2f_hi(uint32_t u) { return __uint_as_float(u & 0xFFFF0000u); }

// ---------------- threefry2x32 (JAX-compatible) ----------------
__host__ __device__ inline void tf2x32(uint32_t k0, uint32_t k1,
                                       uint32_t x0, uint32_t x1,
                                       uint32_t* o0, uint32_t* o1) {
  uint32_t ks0 = k0, ks1 = k1, ks2 = k0 ^ k1 ^ 0x1BD11BDAu;
  x0 += ks0; x1 += ks1;
#define TF_RND(r) { x0 += x1; x1 = (x1 << (r)) | (x1 >> (32 - (r))); x1 ^= x0; }
  TF_RND(13) TF_RND(15) TF_RND(26) TF_RND(6)
  x0 += ks1; x1 += ks2 + 1u;
  TF_RND(17) TF_RND(29) TF_RND(16) TF_RND(24)
  x0 += ks2; x1 += ks0 + 2u;
  TF_RND(13) TF_RND(15) TF_RND(26) TF_RND(6)
  x0 += ks0; x1 += ks1 + 3u;
  TF_RND(17) TF_RND(29) TF_RND(16) TF_RND(24)
  x0 += ks1; x1 += ks2 + 4u;
  TF_RND(13) TF_RND(15) TF_RND(26) TF_RND(6)
  x0 += ks2; x1 += ks0 + 5u;
#undef TF_RND
  *o0 = x0; *o1 = x1;
}

__global__ void gen_idx_kernel(int* __restrict__ idx, uint32_t k0, uint32_t k1,
                               int n, int mask) {
  int j = blockIdx.x * 256 + threadIdx.x;
  if (j >= n) return;
  int half = n >> 1;
  uint32_t o0, o1;
  if (j < half) {
    tf2x32(k0, k1, (uint32_t)j, (uint32_t)(j + half), &o0, &o1);
    idx[j] = (int)(o0 & (uint32_t)mask);
  } else {
    tf2x32(k0, k1, (uint32_t)(j - half), (uint32_t)j, &o0, &o1);
    idx[j] = (int)(o1 & (uint32_t)mask);
  }
}

// ---------------- block reduce helpers (256 threads, wave64) ----------------
__device__ inline float blk_reduce_sum(float v) {
  __shared__ float s[4];
  for (int o = 32; o > 0; o >>= 1) v += __shfl_down(v, o);
  int lane = threadIdx.x & 63, w = threadIdx.x >> 6;
  if (lane == 0) s[w] = v;
  __syncthreads();
  float r = s[0] + s[1] + s[2] + s[3];
  __syncthreads();
  return r;
}

// ---------------- embedding (float4 per thread) ----------------
__global__ void embed_kernel(const float* __restrict__ x, const float* __restrict__ W,
                             const float* __restrict__ bias, float* __restrict__ h) {
  size_t gid = (size_t)blockIdx.x * 256 + threadIdx.x;  // over NB*4096*128 quads
  int o4 = (int)(gid & 127) * 4;
  size_t bl = gid >> 7;
  const float* xr = x + bl * 7;
  float xv[7];
#pragma unroll
  for (int i = 0; i < 7; ++i) xv[i] = xr[i];
  float4 acc = *(const float4*)(bias + o4);
#pragma unroll
  for (int i = 0; i < 7; ++i) {
    float4 w4 = *(const float4*)(W + i * 512 + o4);
    acc.x += xv[i] * w4.x;
    acc.y += xv[i] * w4.y;
    acc.z += xv[i] * w4.z;
    acc.w += xv[i] * w4.w;
  }
  *(float4*)(h + bl * 512 + o4) = acc;
}

// ---------------- cast kernels ----------------
__global__ void cast_bf16(const float* __restrict__ src, ushort_t* __restrict__ dst,
                          size_t n) {
  size_t i = ((size_t)blockIdx.x * 256 + threadIdx.x) * 4;
  if (i >= n) return;
  float4 v = *(const float4*)(src + i);
  ushort4 o;
  o.x = f2b(v.x); o.y = f2b(v.y); o.z = f2b(v.z); o.w = f2b(v.w);
  *(ushort4*)(dst + i) = o;
}

// Bt[n*512+k] = bf16(W[k*512+n])   (512x512)
__global__ void castT512(const float* __restrict__ W, ushort_t* __restrict__ Bt) {
  int gid = blockIdx.x * 256 + threadIdx.x;
  int n = gid >> 9, k = gid & 511;
  Bt[gid] = f2b(W[(size_t)k * 512 + n]);
}

// Bt[n*1536 + dt*512 + i] = bf16(convW[n][i][dt])
__global__ void cast_convW(const float* __restrict__ W, ushort_t* __restrict__ Bt) {
  int gid = blockIdx.x * 256 + threadIdx.x;
  int n = gid / 1536, k = gid - n * 1536;
  int dt = k >> 9, ii = k & 511;
  Bt[gid] = f2b(W[((size_t)n * 512 + ii) * 3 + dt]);
}

// concat 3x512 bias -> 1536
__global__ void concat3(const float* __restrict__ a, const float* __restrict__ b,
                        const float* __restrict__ c, float* __restrict__ o) {
  int t = blockIdx.x * 256 + threadIdx.x;
  if (t >= 1536) return;
  o[t] = t < 512 ? a[t] : (t < 1024 ? b[t - 512] : c[t - 1024]);
}

// ---------------- bf16 MFMA GEMM (m97 structure) ----------------
// MODE 0: standard  1: conv circular-A  2: QKV fused (route by bn>>2 into
//         three CBseg-strided bf16 buffers; L param carries CBseg)
__device__ __forceinline__ float gelu_exact(float c) {
  return 0.5f * c * (1.0f + erff(c * 0.70710678118654752f));
}

template <int MODE, int EPI>
__global__ __launch_bounds__(256) void mfma_gemm(
    const ushort_t* __restrict__ A, const ushort_t* __restrict__ Bt,
    const float* __restrict__ bias, float* __restrict__ Cf,
    ushort_t* __restrict__ Cb, const float* __restrict__ bng,
    const float* __restrict__ bnb, int N, int K, int L) {
  __shared__ __align__(16) ushort_t As[128 * 64];
  __shared__ __align__(16) ushort_t Bs[128 * 64];
  const int tid = threadIdx.x;
  const int lane = tid & 63;
  const int wid = tid >> 6;
  const int wr = wid >> 1, wc = wid & 1;
  const int bm = blockIdx.y, bn = blockIdx.x;
  const int ln = lane & 15, lh = lane >> 4;

  f32x4 acc[4][4] = {};

  for (int k0 = 0; k0 < K; k0 += 64) {
    __syncthreads();
#pragma unroll
    for (int it = 0; it < 4; ++it) {
      int c = it * 256 + tid;
      int row = c >> 3, kc = (c & 7) * 8;
      size_t ga;
      if (MODE == 1) {
        int m = bm * 128 + row;
        int b = m / L, tpos = m - b * L;
        int k = k0 + kc;
        int dt = k >> 9, ii = k & 511;
        int tr2 = tpos + dt - 1;
        if (tr2 < 0) tr2 += L;
        if (tr2 >= L) tr2 -= L;
        ga = ((size_t)(b * L + tr2)) * 512 + ii;
      } else {
        ga = (size_t)(bm * 128 + row) * K + k0 + kc;
      }
      __builtin_amdgcn_global_load_lds(
          (const __attribute__((address_space(1))) void*)(A + ga),
          (__attribute__((address_space(3))) void*)(As + c * 8), 16, 0, 0);
      size_t gb = (size_t)(bn * 128 + row) * K + k0 + kc;
      __builtin_amdgcn_global_load_lds(
          (const __attribute__((address_space(1))) void*)(Bt + gb),
          (__attribute__((address_space(3))) void*)(Bs + c * 8), 16, 0, 0);
    }
    __syncthreads();
#pragma unroll
    for (int kk = 0; kk < 2; ++kk) {
      bf16x8 af[4], bf_[4];
#pragma unroll
      for (int m = 0; m < 4; ++m)
        af[m] = *(const bf16x8*)&As[(wr * 64 + m * 16 + ln) * 64 + kk * 32 + lh * 8];
#pragma unroll
      for (int n = 0; n < 4; ++n)
        bf_[n] = *(const bf16x8*)&Bs[(wc * 64 + n * 16 + ln) * 64 + kk * 32 + lh * 8];
#pragma unroll
      for (int m = 0; m < 4; ++m)
#pragma unroll
        for (int n = 0; n < 4; ++n)
          acc[m][n] =
              __builtin_amdgcn_mfma_f32_16x16x32_bf16(af[m], bf_[n], acc[m][n], 0, 0, 0);
    }
  }

  const float bnscale = 0.9999950000374996f;  // 1/sqrt(1+1e-5)
#pragma unroll
  for (int m = 0; m < 4; ++m) {
    int row = bm * 128 + wr * 64 + m * 16 + lh * 4;
#pragma unroll
    for (int n = 0; n < 4; ++n) {
      int col = bn * 128 + wc * 64 + n * 16 + ln;
      float bsv = bias[col];
#pragma unroll
      for (int r = 0; r < 4; ++r) {
        float cval = acc[m][n][r] + bsv;
        if (MODE == 2) {
          ushort_t* dst = Cb + (size_t)(bn >> 2) * (size_t)L;  // L = CBseg
          dst[(size_t)(row + r) * 512 + (col & 511)] = f2b(cval);
        } else {
          size_t oi = (size_t)(row + r) * N + col;
          if (EPI == 0) {
            Cb[oi] = f2b(cval);
          } else if (EPI == 1) {
            Cf[oi] += cval;
          } else if (EPI == 2) {
            Cb[oi] = f2b(gelu_exact(cval));
          } else {
            float c2 = cval * bnscale * bng[col] + bnb[col];
            Cf[oi] = c2 > 0.0f ? c2 : expm1f(c2);
          }
        }
      }
    }
  }
}

// ---------------- LN (in-place, row = 512) ----------------
__global__ __launch_bounds__(256) void ln_inplace(float* __restrict__ h,
                                                  const float* __restrict__ g,
                                                  const float* __restrict__ b) {
  size_t row = blockIdx.x;
  float* hr = h + row * 512;
  int t = threadIdx.x;
  float x0 = hr[t], x1 = hr[t + 256];
  float mean = blk_reduce_sum(x0 + x1) * (1.0f / 512.0f);
  float d0 = x0 - mean, d1 = x1 - mean;
  float var = blk_reduce_sum(d0 * d0 + d1 * d1) * (1.0f / 512.0f);
  float rstd = rsqrtf(var + 1e-5f);
  hr[t] = d0 * rstd * g[t] + b[t];
  hr[t + 256] = d1 * rstd * g[t + 256] + b[t + 256];
}

// ---------------- prob-sparse M scores: one wave per (b,l), coalesced 1KB K rows ----
__global__ __launch_bounds__(256) void prob_scores_wave(const ushort_t* __restrict__ q,
                                                        const ushort_t* __restrict__ k,
                                                        const int* __restrict__ idx,
                                                        float* __restrict__ Mout,
                                                        int L, int S) {
  int wv = (blockIdx.x << 2) + ((threadIdx.x) >> 6);  // wave id over CB*L
  int lane = threadIdx.x & 63;
  int l = wv % L;
  int b = wv / L;
  const ushort_t* qr = q + ((size_t)(b * L + l)) * 512 + lane * 8;
  uint4 qu = *(const uint4*)qr;
  float qf[8];
  qf[0] = b2f_lo(qu.x); qf[1] = b2f_hi(qu.x);
  qf[2] = b2f_lo(qu.y); qf[3] = b2f_hi(qu.y);
  qf[4] = b2f_lo(qu.z); qf[5] = b2f_hi(qu.z);
  qf[6] = b2f_lo(qu.w); qf[7] = b2f_hi(qu.w);
  const int* il = idx + l * S;
  const ushort_t* kb = k + (size_t)b * L * 512 + lane * 8;
  float m = -INFINITY, ssum = 0.0f;
  for (int s = 0; s < S; ++s) {
    int j = il[s];
    uint4 ku = *(const uint4*)(kb + (size_t)j * 512);
    float dot = qf[0] * b2f_lo(ku.x) + qf[1] * b2f_hi(ku.x) +
                qf[2] * b2f_lo(ku.y) + qf[3] * b2f_hi(ku.y) +
                qf[4] * b2f_lo(ku.z) + qf[5] * b2f_hi(ku.z) +
                qf[6] * b2f_lo(ku.w) + qf[7] * b2f_hi(ku.w);
    dot += __shfl_xor(dot, 1);
    dot += __shfl_xor(dot, 2);
    dot += __shfl_xor(dot, 4);
    m = fmaxf(m, dot);
    ssum += dot;
  }
  if ((lane & 7) == 0) {
    int hh = lane >> 3;
    Mout[((size_t)(b * 8 + hh)) * L + l] = m - ssum / (float)L;
  }
}

// ---------------- top-k via 4-pass radix select ----------------
// Selects the top-S index SET with lax.top_k tie semantics (at the threshold
// value, lowest indices win). Output order within top_idx is arbitrary —
// downstream consumers are order-invariant (per-l scatter).
__global__ __launch_bounds__(256) void topk_kernel(const float* __restrict__ Mbuf,
                                                   int* __restrict__ top_idx,
                                                   int L, int S) {
  int bh = blockIdx.x;
  __shared__ uint32_t keys[4096];
  __shared__ int hist[256];
  __shared__ int sh_bin, sh_found, sh_cnt;
  const float* Mr = Mbuf + (size_t)bh * L;
  int t = threadIdx.x;

  // load + monotonic float->uint transform (larger float => larger key)
  for (int j = t; j < L; j += 256) {
    uint32_t u = __float_as_uint(Mr[j]);
    keys[j] = (u & 0x80000000u) ? ~u : (u | 0x80000000u);
  }
  if (t == 0) sh_cnt = 0;
  __syncthreads();

  uint32_t prefix = 0;
  int found = 0;
  for (int p = 24; p >= 0; p -= 8) {
    hist[t] = 0;
    __syncthreads();
    for (int j = t; j < L; j += 256) {
      uint32_t key = keys[j];
      bool match = (p == 24) || ((key >> (p + 8)) == (prefix >> (p + 8)));
      if (match) atomicAdd(&hist[(key >> p) & 255], 1);
    }
    __syncthreads();
    // inclusive suffix scan (Hillis-Steele)
    for (int o = 1; o < 256; o <<= 1) {
      int add = (t + o < 256) ? hist[t + o] : 0;
      __syncthreads();
      hist[t] += add;
      __syncthreads();
    }
    int sufIncl = hist[t];
    int sufExcl = (t < 255) ? hist[t + 1] : 0;
    int needv = S - found;
    if (sufExcl < needv && needv <= sufIncl) { sh_bin = t; sh_found = found + sufExcl; }
    __syncthreads();
    prefix |= (uint32_t)sh_bin << p;
    found = sh_found;
    __syncthreads();
  }

  uint32_t tau = prefix;
  int r = S - found;  // #threshold-equal elements to take, lowest indices first
  // per-thread contiguous chunks give index-ordered ranks for equals
  int chunk = L >> 8;
  int base = t * chunk;
  int localEq = 0;
  for (int i = 0; i < chunk; ++i) localEq += (keys[base + i] == tau) ? 1 : 0;
  hist[t] = localEq;
  __syncthreads();
  for (int o = 1; o < 256; o <<= 1) {
    int add = (t >= o) ? hist[t - o] : 0;
    __syncthreads();
    hist[t] += add;
    __syncthreads();
  }
  int myRank = hist[t] - localEq;  // exclusive prefix (index-ordered)
  for (int i = 0; i < chunk; ++i) {
    uint32_t key = keys[base + i];
    bool isEq = (key == tau);
    bool sel = (key > tau) || (isEq && myRank < r);
    if (isEq) myRank++;
    if (sel) {
      int slot = atomicAdd(&sh_cnt, 1);
      top_idx[bh * S + slot] = base + i;
    }
  }
}

// ---------------- mean of V: stage 1 (coalesced column partial sums) ----------------
__global__ __launch_bounds__(256) void mean_v_partial(const ushort_t* __restrict__ v,
                                                      float* __restrict__ part, int L) {
  int b = blockIdx.x;
  int chunk = blockIdx.y;
  int t = threadIdx.x;
  int c = t * 2;
  const ushort_t* base = v + ((size_t)b * L + (size_t)chunk * 256) * 512 + c;
  float a0 = 0.0f, a1 = 0.0f;
#pragma unroll 8
  for (int r = 0; r < 256; ++r) {
    uint32_t u = *(const uint32_t*)(base + (size_t)r * 512);
    a0 += b2f_lo(u);
    a1 += b2f_hi(u);
  }
  float* p = part + ((size_t)b * 16 + chunk) * 512 + c;
  p[0] = a0;
  p[1] = a1;
}

// ---------------- mean of V: stage 2 ----------------
__global__ void mean_v_finish(const float* __restrict__ part, float* __restrict__ mv,
                              int L, int nchunks) {
  int b = blockIdx.x;
  int c = threadIdx.x;  // 512 threads
  float s = 0.0f;
  for (int k = 0; k < nchunks; ++k) s += part[((size_t)b * 16 + k) * 512 + c];
  mv[b * 512 + c] = s / (float)L;
}

// ---------------- fill ctx (bf16) with broadcast mean ----------------
__global__ void fill_ctx(ushort_t* __restrict__ ctx, const float* __restrict__ mv,
                         int L) {
  size_t gid = (size_t)blockIdx.x * 256 + threadIdx.x;  // CB*L*512
  int c = (int)(gid & 511);
  size_t bl = gid >> 9;
  int b = (int)(bl / (size_t)L);
  ctx[gid] = f2b(mv[b * 512 + c]);
}

// ---------------- fused flash attention (no-max softmax: scores bounded) ----------
// grid (fj = L/64, CBNH). Each block: 64 keys for all S queries of one bh.
// P = exp(score) directly; per-split partials (z, O-unnormalized).
__global__ __launch_bounds__(256) void flash_attn(const ushort_t* __restrict__ q,
                                                  const ushort_t* __restrict__ k,
                                                  const ushort_t* __restrict__ v,
                                                  const int* __restrict__ top_idx,
                                                  float* __restrict__ pz,
                                                  float* __restrict__ po,
                                                  int L, int S, int CBNH) {
  __shared__ float qs[SMAX * 64];
  __shared__ ushort_t pt[SMAX * 64];
  int bh = blockIdx.y, js = blockIdx.x;
  int hh = bh & 7, b = bh >> 3;
  int t = threadIdx.x;
  int lane = t & 63, w = t >> 6;
  for (int e = t; e < S * 64; e += 256) {
    int u = e >> 6, d = e & 63;
    int l = top_idx[bh * S + u];
    qs[e] = bu2f(q[((size_t)(b * L + l)) * 512 + hh * 64 + d]);
  }
  __syncthreads();
  int j0 = js * 64;
  // stage A: lane = key; K row in registers; P = exp(score) -> LDS (bf16)
  const ushort_t* kr = k + ((size_t)(b * L + j0 + lane)) * 512 + hh * 64;
  uint4 kreg[8];
#pragma unroll
  for (int c = 0; c < 8; ++c) kreg[c] = ((const uint4*)kr)[c];
  float zs[12];
#pragma unroll
  for (int mi = 0; mi < 12; ++mi) {
    int u = w + mi * 4;
    if (u < S) {
      const float* qu = qs + u * 64;
      float dot = 0.0f;
#pragma unroll
      for (int c = 0; c < 8; ++c) {
        uint4 ku = kreg[c];
        const float* q8 = qu + c * 8;
        dot += q8[0] * b2f_lo(ku.x) + q8[1] * b2f_hi(ku.x) +
               q8[2] * b2f_lo(ku.y) + q8[3] * b2f_hi(ku.y) +
               q8[4] * b2f_lo(ku.z) + q8[5] * b2f_hi(ku.z) +
               q8[6] * b2f_lo(ku.w) + q8[7] * b2f_hi(ku.w);
      }
      float P = __expf(dot * 0.125f);
      ushort_t Pb = f2b(P);
      pt[u * 64 + lane] = Pb;
      float ps = bu2f(Pb);  // sum the rounded value for num/denom consistency
#pragma unroll
      for (int o2 = 1; o2 < 64; o2 <<= 1) ps += __shfl_xor(ps, o2);
      zs[mi] = ps;
    }
  }
  __syncthreads();
  // stage B: lane = d; accumulate P*V (coalesced V rows)
  float oacc[12] = {};
  for (int jb = 0; jb < 64; jb += 4) {
    float vv[4];
#pragma unroll
    for (int r = 0; r < 4; ++r)
      vv[r] = bu2f(v[((size_t)(b * L + j0 + jb + r)) * 512 + hh * 64 + lane]);
#pragma unroll
    for (int mi = 0; mi < 12; ++mi) {
      int u = w + mi * 4;
      if (u < S) {
        const ushort_t* p4 = &pt[u * 64 + jb];
        oacc[mi] += bu2f(p4[0]) * vv[0] + bu2f(p4[1]) * vv[1] +
                    bu2f(p4[2]) * vv[2] + bu2f(p4[3]) * vv[3];
      }
    }
  }
  size_t base = (size_t)js * CBNH + bh;
#pragma unroll
  for (int mi = 0; mi < 12; ++mi) {
    int u = w + mi * 4;
    if (u < S) {
      po[(base * SMAX + u) * 64 + lane] = oacc[mi];
      if (lane == 0) pz[base * SMAX + u] = zs[mi];
    }
  }
}

// ---------------- combine flash partials, /Z, scatter into ctx ----------------
__global__ void flash_finish(const float* __restrict__ pz, const float* __restrict__ po,
                             const int* __restrict__ top_idx, ushort_t* __restrict__ ctx,
                             int L, int S, int CBNH, int fj) {
  int gid = blockIdx.x * 256 + threadIdx.x;  // over CBNH*S*64
  if (gid >= CBNH * S * 64) return;
  int d = gid & 63;
  int r = gid >> 6;  // bh*S + u
  int u = r % S, bh = r / S;
  int hh = bh & 7, b = bh >> 3;
  float Z = 0.0f, O = 0.0f;
  for (int js = 0; js < fj; ++js) {
    size_t pi = ((size_t)js * CBNH + bh) * SMAX + u;
    Z += pz[pi];
    O += po[pi * 64 + d];
  }
  int l = top_idx[bh * S + u];
  ctx[((size_t)(b * L + l)) * 512 + hh * 64 + d] = f2b(O / Z);
}

// ---------------- maxpool window 3 stride 2 ----------------
__global__ void maxpool_kernel(const float* __restrict__ y, float* __restrict__ hout,
                               int L) {
  size_t gid = (size_t)blockIdx.x * 256 + threadIdx.x;  // CB*(L/2)*512
  int Lh = L >> 1;
  int o = (int)(gid & 511);
  size_t bj = gid >> 9;
  int j = (int)(bj % (size_t)Lh);
  int b = (int)(bj / (size_t)Lh);
  const float* base = y + ((size_t)(b * L + 2 * j)) * 512 + o;
  float mx = base[0];
  if (j > 0) mx = fmaxf(mx, base[-512]);
  mx = fmaxf(mx, base[512]);
  hout[gid] = mx;
}

// ---------------- final LN + projection ----------------
__global__ __launch_bounds__(256) void final_ln_proj(const float* __restrict__ h,
                                                     const float* __restrict__ g,
                                                     const float* __restrict__ bb,
                                                     const float* __restrict__ pw,
                                                     const float* __restrict__ pb,
                                                     float* __restrict__ out, int L) {
  int b = blockIdx.x / 47, l = blockIdx.x % 47;
  const float* hr = h + ((size_t)(b * L + l)) * 512;
  int t = threadIdx.x;
  float x0 = hr[t], x1 = hr[t + 256];
  float mean = blk_reduce_sum(x0 + x1) * (1.0f / 512.0f);
  float d0 = x0 - mean, d1 = x1 - mean;
  float var = blk_reduce_sum(d0 * d0 + d1 * d1) * (1.0f / 512.0f);
  float rstd = rsqrtf(var + 1e-5f);
  float y0 = d0 * rstd * g[t] + bb[t];
  float y1 = d1 * rstd * g[t + 256] + bb[t + 256];
  float dot = blk_reduce_sum(y0 * pw[t] + y1 * pw[t + 256]);
  if (t == 0) out[b * 47 + l] = dot + pb[0];
}

// ---------------- launcher ----------------
extern "C" void kernel_launch(void* const* d_in, const int* in_sizes, int n_in,
                              void* d_out, int out_size, void* d_ws, size_t ws_size,
                              hipStream_t stream) {
  const float* x = (const float*)d_in[0];
  const float* emb_W = (const float*)d_in[1];
  const float* emb_b = (const float*)d_in[2];
  const float* Wq = (const float*)d_in[3];
  const float* bq = (const float*)d_in[4];
  const float* Wk = (const float*)d_in[5];
  const float* bk = (const float*)d_in[6];
  const float* Wv = (const float*)d_in[7];
  const float* bv = (const float*)d_in[8];
  const float* Wo = (const float*)d_in[9];
  const float* bo = (const float*)d_in[10];
  const float* fW1 = (const float*)d_in[11];
  const float* fb1 = (const float*)d_in[12];
  const float* fW2 = (const float*)d_in[13];
  const float* fb2 = (const float*)d_in[14];
  const float* ln1g = (const float*)d_in[15];
  const float* ln1b = (const float*)d_in[16];
  const float* ln2g = (const float*)d_in[17];
  const float* ln2b = (const float*)d_in[18];
  const float* cW = (const float*)d_in[19];
  const float* cb = (const float*)d_in[20];
  const float* bng = (const float*)d_in[21];
  const float* bnb = (const float*)d_in[22];
  const float* flng = (const float*)d_in[23];
  const float* flnb = (const float*)d_in[24];
  const float* pW = (const float*)d_in[25];
  const float* pb = (const float*)d_in[26];
  float* out = (float*)d_out;

  // base batch-group size from ws_size (try 16, 8, 4, 2, 1)
  int CB0 = 16;
  while (CB0 > 1) {
    size_t need = 35732992ull + (size_t)CB0 * 6806016ull;
    if (need * 4 <= ws_size) break;
    CB0 >>= 1;
  }
  const size_t CBseg = (size_t)CB0 * 2097152ull;  // CB0*4096*512 (bf16 elems)

  float* ws = (float*)d_ws;
  size_t off = 0;
  float* h = ws;                           off += 33554432ull;
  ushort_t* wbase = (ushort_t*)(ws + off); off += 1966080ull;
  ushort_t* WqkvT = wbase;                 // 1536 x 512 (q rows, k rows, v rows)
  ushort_t* WoT = wbase + 786432;
  ushort_t* W1b = wbase + 1048576;
  ushort_t* W2b = wbase + 2097152;
  ushort_t* Wcb = wbase + 3145728;
  float* bqkv = ws + off;                  off += 1536ull;
  ushort_t* gArea = (ushort_t*)(ws + off); off += (5ull * CBseg) / 2;
  ushort_t* hb = gArea;
  ushort_t* qb = gArea + CBseg;
  ushort_t* kbuf = gArea + 2 * CBseg;
  ushort_t* vb = gArea + 3 * CBseg;
  ushort_t* ctxb = gArea + 4 * CBseg;
  ushort_t* ybuf = qb;           // spans qb..ctxb (4*CBseg bf16)
  float* convY = (float*)qb;     // spans qb,kbuf (CBseg f32)
  float* Mbuf = ws + off;                  off += (size_t)CB0 * 32768;
  float* mv = ws + off;                    off += 8192ull;               // 16*512
  int* topidx = (int*)(ws + off);          off += 6144ull;               // 16*8*48
  int* idxbuf = (int*)(ws + off);          off += 196608ull;
  float* pzb = ws + off;                   off += (size_t)CB0 * 23040;   // (fj*CBNH=512*CB0)*SMAX
  float* pob = ws + off;                   off += (size_t)CB0 * 1474560; // ... *64
  float* mvpart = ws + off;                off += 131072ull;             // 16*16*512

  // embedding (float4 per thread)
  {
    size_t total = (size_t)NB * 4096 * 128;
    embed_kernel<<<(int)(total / 256), 256, 0, stream>>>(x, emb_W, emb_b, h);
  }

  int L = 4096;
  for (int i = 0; i < 3; ++i) {
    int S = (i == 0) ? 45 : (i == 1) ? 40 : 35;
    // layer-adaptive group size: same bytes per group across layers
    int CBl = CB0 * (4096 / L);
    if (CBl > NB) CBl = NB;
    int ngroups = NB / CBl;
    int CBNHl = CBl * NH;
    int Mg = CBl * L;                      // rows per group (const when uncapped)
    size_t segL = (size_t)Mg * 512;
    int fj = L / 64;                       // key splits: 64 / 32 / 16

    // per-layer weight casts
    castT512<<<1024, 256, 0, stream>>>(Wq + (size_t)i * 262144, WqkvT);
    castT512<<<1024, 256, 0, stream>>>(Wk + (size_t)i * 262144, WqkvT + 262144);
    castT512<<<1024, 256, 0, stream>>>(Wv + (size_t)i * 262144, WqkvT + 524288);
    castT512<<<1024, 256, 0, stream>>>(Wo + (size_t)i * 262144, WoT);
    cast_bf16<<<1024, 256, 0, stream>>>(fW1 + (size_t)i * 1048576, W1b, 1048576);
    cast_bf16<<<1024, 256, 0, stream>>>(fW2 + (size_t)i * 1048576, W2b, 1048576);
    if (i < 2) cast_convW<<<3072, 256, 0, stream>>>(cW + (size_t)i * 786432, Wcb);
    concat3<<<6, 256, 0, stream>>>(bq + i * DM, bk + i * DM, bv + i * DM, bqkv);

    // JAX randint key
    uint32_t fa, fbk;
    tf2x32(0u, 42u, 0u, (uint32_t)i, &fa, &fbk);
    uint32_t a0, b0, a1, b1;
    tf2x32(fa, fbk, 0u, 2u, &a0, &b0);
    tf2x32(fa, fbk, 1u, 3u, &a1, &b1);
    int n = L * S;
    gen_idx_kernel<<<(n + 255) / 256, 256, 0, stream>>>(idxbuf, b0, b1, n, L - 1);

    // ---- attention per batch group ----
    for (int g = 0; g < ngroups; ++g) {
      float* hg = h + (size_t)g * segL;
      cast_bf16<<<(int)(segL / 1024), 256, 0, stream>>>(hg, hb, segL);
      dim3 gqkv(12, Mg / 128);
      mfma_gemm<2, 0><<<gqkv, 256, 0, stream>>>(hb, WqkvT, bqkv, nullptr, qb,
                                                nullptr, nullptr, 1536, 512,
                                                (int)CBseg);

      prob_scores_wave<<<(CBl * L) / 4, 256, 0, stream>>>(qb, kbuf, idxbuf, Mbuf, L, S);
      topk_kernel<<<CBNHl, 256, 0, stream>>>(Mbuf, topidx, L, S);

      mean_v_partial<<<dim3(CBl, L / 256), 256, 0, stream>>>(vb, mvpart, L);
      mean_v_finish<<<CBl, 512, 0, stream>>>(mvpart, mv, L, L / 256);
      fill_ctx<<<(int)(segL / 256), 256, 0, stream>>>(ctxb, mv, L);
      flash_attn<<<dim3(fj, CBNHl), 256, 0, stream>>>(qb, kbuf, vb, topidx,
                                                      pzb, pob, L, S, CBNHl);
      flash_finish<<<(CBNHl * S * 64 + 255) / 256, 256, 0, stream>>>(
          pzb, pob, topidx, ctxb, L, S, CBNHl, fj);

      dim3 gq(4, Mg / 128);
      mfma_gemm<0, 1><<<gq, 256, 0, stream>>>(ctxb, WoT, bo + i * DM, hg, nullptr,
                                              nullptr, nullptr, 512, 512, 0);
    }
    ln_inplace<<<NB * L, 256, 0, stream>>>(h, ln1g + i * DM, ln1b + i * DM);

    // ---- FF row-chunked ----
    int rows = NB * L;
    int R = CB0 * 4096;
    if (R > rows) R = rows;
    for (int r0 = 0; r0 < rows; r0 += R) {
      float* hr = h + (size_t)r0 * 512;
      size_t rseg = (size_t)R * 512;
      cast_bf16<<<(int)(rseg / 1024), 256, 0, stream>>>(hr, hb, rseg);
      dim3 g1(16, R / 128);
      mfma_gemm<0, 2><<<g1, 256, 0, stream>>>(hb, W1b, fb1 + i * DFF_, nullptr, ybuf,
                                              nullptr, nullptr, 2048, 512, 0);
      dim3 g2(4, R / 128);
      mfma_gemm<0, 1><<<g2, 256, 0, stream>>>(ybuf, W2b, fb2 + i * DM, hr, nullptr,
                                              nullptr, nullptr, 512, 2048, 0);
    }
    ln_inplace<<<NB * L, 256, 0, stream>>>(h, ln2g + i * DM, ln2b + i * DM);

    // ---- conv + maxpool per batch group ----
    if (i < 2) {
      int Lh = L / 2;
      for (int g = 0; g < ngroups; ++g) {
        float* hg = h + (size_t)g * segL;
        cast_bf16<<<(int)(segL / 1024), 256, 0, stream>>>(hg, hb, segL);
        dim3 gc(4, Mg / 128);
        mfma_gemm<1, 3><<<gc, 256, 0, stream>>>(hb, Wcb, cb + i * DM, convY, nullptr,
                                                bng + i * DM, bnb + i * DM, 512, 1536, L);
        size_t tot = (size_t)CBl * Lh * 512;
        maxpool_kernel<<<(int)(tot / 256), 256, 0, stream>>>(
            convY, h + (size_t)g * CBl * Lh * 512, L);
      }
      L = Lh;
    }
  }

  final_ln_proj<<<NB * 47, 256, 0, stream>>>(h, flng, flnb, pW, pb, out, L);
}

// Round 13
// 3629.280 us; speedup vs baseline: 2.6043x; 1.0530x over previous
//
#include <hip/hip_runtime.h>
#include <cstdint>
#include <math.h>

#define NB 16
#define DM 512
#define NH 8
#define DFF_ 2048
#define SMAX 45

typedef unsigned short ushort_t;
typedef __bf16 bf16x8 __attribute__((ext_vector_type(8)));
typedef float f32x4 __attribute__((ext_vector_type(4)));

// ---------------- bf16 helpers ----------------
__device__ __forceinline__ ushort_t f2b(float f) {  // RNE f32 -> bf16 bits
  uint32_t u = __float_as_uint(f);
  uint32_t r = (u + 0x7FFFu + ((u >> 16) & 1u)) >> 16;
  return (ushort_t)r;
}
__device__ __forceinline__ float bu2f(ushort_t x) {
  return __uint_as_float((uint32_t)x << 16);
}
__device__ __forceinline__ float b2f_lo(uint32_t u) { return __uint_as_float(u << 16); }
__device__ __forceinline__ float b2f_hi(uint32_t u) { return __uint_as_float(u & 0xFFFF0000u); }

// ---------------- threefry2x32 (JAX-compatible) ----------------
__host__ __device__ inline void tf2x32(uint32_t k0, uint32_t k1,
                                       uint32_t x0, uint32_t x1,
                                       uint32_t* o0, uint32_t* o1) {
  uint32_t ks0 = k0, ks1 = k1, ks2 = k0 ^ k1 ^ 0x1BD11BDAu;
  x0 += ks0; x1 += ks1;
#define TF_RND(r) { x0 += x1; x1 = (x1 << (r)) | (x1 >> (32 - (r))); x1 ^= x0; }
  TF_RND(13) TF_RND(15) TF_RND(26) TF_RND(6)
  x0 += ks1; x1 += ks2 + 1u;
  TF_RND(17) TF_RND(29) TF_RND(16) TF_RND(24)
  x0 += ks2; x1 += ks0 + 2u;
  TF_RND(13) TF_RND(15) TF_RND(26) TF_RND(6)
  x0 += ks0; x1 += ks1 + 3u;
  TF_RND(17) TF_RND(29) TF_RND(16) TF_RND(24)
  x0 += ks1; x1 += ks2 + 4u;
  TF_RND(13) TF_RND(15) TF_RND(26) TF_RND(6)
  x0 += ks2; x1 += ks0 + 5u;
#undef TF_RND
  *o0 = x0; *o1 = x1;
}

__global__ void gen_idx_kernel(int* __restrict__ idx, uint32_t k0, uint32_t k1,
                               int n, int mask) {
  int j = blockIdx.x * 256 + threadIdx.x;
  if (j >= n) return;
  int half = n >> 1;
  uint32_t o0, o1;
  if (j < half) {
    tf2x32(k0, k1, (uint32_t)j, (uint32_t)(j + half), &o0, &o1);
    idx[j] = (int)(o0 & (uint32_t)mask);
  } else {
    tf2x32(k0, k1, (uint32_t)(j - half), (uint32_t)j, &o0, &o1);
    idx[j] = (int)(o1 & (uint32_t)mask);
  }
}

// ---------------- block reduce helpers (256 threads, wave64) ----------------
__device__ inline float blk_reduce_sum(float v) {
  __shared__ float s[4];
  for (int o = 32; o > 0; o >>= 1) v += __shfl_down(v, o);
  int lane = threadIdx.x & 63, w = threadIdx.x >> 6;
  if (lane == 0) s[w] = v;
  __syncthreads();
  float r = s[0] + s[1] + s[2] + s[3];
  __syncthreads();
  return r;
}

// ---------------- embedding (float4 per thread) ----------------
__global__ void embed_kernel(const float* __restrict__ x, const float* __restrict__ W,
                             const float* __restrict__ bias, float* __restrict__ h) {
  size_t gid = (size_t)blockIdx.x * 256 + threadIdx.x;  // over NB*4096*128 quads
  int o4 = (int)(gid & 127) * 4;
  size_t bl = gid >> 7;
  const float* xr = x + bl * 7;
  float xv[7];
#pragma unroll
  for (int i = 0; i < 7; ++i) xv[i] = xr[i];
  float4 acc = *(const float4*)(bias + o4);
#pragma unroll
  for (int i = 0; i < 7; ++i) {
    float4 w4 = *(const float4*)(W + i * 512 + o4);
    acc.x += xv[i] * w4.x;
    acc.y += xv[i] * w4.y;
    acc.z += xv[i] * w4.z;
    acc.w += xv[i] * w4.w;
  }
  *(float4*)(h + bl * 512 + o4) = acc;
}

// ---------------- cast kernels ----------------
__global__ void cast_bf16(const float* __restrict__ src, ushort_t* __restrict__ dst,
                          size_t n) {
  size_t i = ((size_t)blockIdx.x * 256 + threadIdx.x) * 4;
  if (i >= n) return;
  float4 v = *(const float4*)(src + i);
  ushort4 o;
  o.x = f2b(v.x); o.y = f2b(v.y); o.z = f2b(v.z); o.w = f2b(v.w);
  *(ushort4*)(dst + i) = o;
}

// Bt[n*512+k] = bf16(W[k*512+n])   (512x512)
__global__ void castT512(const float* __restrict__ W, ushort_t* __restrict__ Bt) {
  int gid = blockIdx.x * 256 + threadIdx.x;
  int n = gid >> 9, k = gid & 511;
  Bt[gid] = f2b(W[(size_t)k * 512 + n]);
}

// Bt[n*1536 + dt*512 + i] = bf16(convW[n][i][dt])
__global__ void cast_convW(const float* __restrict__ W, ushort_t* __restrict__ Bt) {
  int gid = blockIdx.x * 256 + threadIdx.x;
  int n = gid / 1536, k = gid - n * 1536;
  int dt = k >> 9, ii = k & 511;
  Bt[gid] = f2b(W[((size_t)n * 512 + ii) * 3 + dt]);
}

// concat 3x512 bias -> 1536
__global__ void concat3(const float* __restrict__ a, const float* __restrict__ b,
                        const float* __restrict__ c, float* __restrict__ o) {
  int t = blockIdx.x * 256 + threadIdx.x;
  if (t >= 1536) return;
  o[t] = t < 512 ? a[t] : (t < 1024 ? b[t - 512] : c[t - 1024]);
}

// ---------------- bf16 MFMA GEMM (m97 structure + T2 XOR swizzle) ----------------
// LDS tiles are [128 rows][8 chunks of 8 bf16]; chunk j of row r is stored at
// physical chunk j ^ (r&7) (bank-conflict-free fragment reads). Since
// global_load_lds writes linearly, the GLOBAL source chunk is pre-swizzled
// (rule: swizzle both sides or neither).
// MODE 0: standard  1: conv circular-A  2: QKV fused (route by bn>>2)
__device__ __forceinline__ float gelu_exact(float c) {
  return 0.5f * c * (1.0f + erff(c * 0.70710678118654752f));
}

template <int MODE, int EPI>
__global__ __launch_bounds__(256) void mfma_gemm(
    const ushort_t* __restrict__ A, const ushort_t* __restrict__ Bt,
    const float* __restrict__ bias, float* __restrict__ Cf,
    ushort_t* __restrict__ Cb, const float* __restrict__ bng,
    const float* __restrict__ bnb, int N, int K, int L) {
  __shared__ __align__(16) ushort_t As[128 * 64];
  __shared__ __align__(16) ushort_t Bs[128 * 64];
  const int tid = threadIdx.x;
  const int lane = tid & 63;
  const int wid = tid >> 6;
  const int wr = wid >> 1, wc = wid & 1;
  const int bm = blockIdx.y, bn = blockIdx.x;
  const int ln = lane & 15, lh = lane >> 4;

  f32x4 acc[4][4] = {};

  for (int k0 = 0; k0 < K; k0 += 64) {
    __syncthreads();
#pragma unroll
    for (int it = 0; it < 4; ++it) {
      int c = it * 256 + tid;
      int row = c >> 3;
      int kc = (((c & 7) ^ (row & 7)) << 3);  // swizzled source chunk
      size_t ga;
      if (MODE == 1) {
        int m = bm * 128 + row;
        int b = m / L, tpos = m - b * L;
        int k = k0 + kc;
        int dt = k >> 9, ii = k & 511;
        int tr2 = tpos + dt - 1;
        if (tr2 < 0) tr2 += L;
        if (tr2 >= L) tr2 -= L;
        ga = ((size_t)(b * L + tr2)) * 512 + ii;
      } else {
        ga = (size_t)(bm * 128 + row) * K + k0 + kc;
      }
      __builtin_amdgcn_global_load_lds(
          (const __attribute__((address_space(1))) void*)(A + ga),
          (__attribute__((address_space(3))) void*)(As + c * 8), 16, 0, 0);
      size_t gb = (size_t)(bn * 128 + row) * K + k0 + kc;
      __builtin_amdgcn_global_load_lds(
          (const __attribute__((address_space(1))) void*)(Bt + gb),
          (__attribute__((address_space(3))) void*)(Bs + c * 8), 16, 0, 0);
    }
    __syncthreads();
#pragma unroll
    for (int kk = 0; kk < 2; ++kk) {
      bf16x8 af[4], bf_[4];
#pragma unroll
      for (int m = 0; m < 4; ++m) {
        int ar = wr * 64 + m * 16 + ln;
        int aoff = (kk * 32 + lh * 8) ^ ((ar & 7) << 3);
        af[m] = *(const bf16x8*)&As[ar * 64 + aoff];
      }
#pragma unroll
      for (int n = 0; n < 4; ++n) {
        int br = wc * 64 + n * 16 + ln;
        int boff = (kk * 32 + lh * 8) ^ ((br & 7) << 3);
        bf_[n] = *(const bf16x8*)&Bs[br * 64 + boff];
      }
#pragma unroll
      for (int m = 0; m < 4; ++m)
#pragma unroll
        for (int n = 0; n < 4; ++n)
          acc[m][n] =
              __builtin_amdgcn_mfma_f32_16x16x32_bf16(af[m], bf_[n], acc[m][n], 0, 0, 0);
    }
  }

  const float bnscale = 0.9999950000374996f;  // 1/sqrt(1+1e-5)
#pragma unroll
  for (int m = 0; m < 4; ++m) {
    int row = bm * 128 + wr * 64 + m * 16 + lh * 4;
#pragma unroll
    for (int n = 0; n < 4; ++n) {
      int col = bn * 128 + wc * 64 + n * 16 + ln;
      float bsv = bias[col];
#pragma unroll
      for (int r = 0; r < 4; ++r) {
        float cval = acc[m][n][r] + bsv;
        if (MODE == 2) {
          ushort_t* dst = Cb + (size_t)(bn >> 2) * (size_t)L;  // L = CBseg
          dst[(size_t)(row + r) * 512 + (col & 511)] = f2b(cval);
        } else {
          size_t oi = (size_t)(row + r) * N + col;
          if (EPI == 0) {
            Cb[oi] = f2b(cval);
          } else if (EPI == 1) {
            Cf[oi] += cval;
          } else if (EPI == 2) {
            Cb[oi] = f2b(gelu_exact(cval));
          } else {
            float c2 = cval * bnscale * bng[col] + bnb[col];
            Cf[oi] = c2 > 0.0f ? c2 : expm1f(c2);
          }
        }
      }
    }
  }
}

// ---------------- LN (in-place, row = 512) ----------------
__global__ __launch_bounds__(256) void ln_inplace(float* __restrict__ h,
                                                  const float* __restrict__ g,
                                                  const float* __restrict__ b) {
  size_t row = blockIdx.x;
  float* hr = h + row * 512;
  int t = threadIdx.x;
  float x0 = hr[t], x1 = hr[t + 256];
  float mean = blk_reduce_sum(x0 + x1) * (1.0f / 512.0f);
  float d0 = x0 - mean, d1 = x1 - mean;
  float var = blk_reduce_sum(d0 * d0 + d1 * d1) * (1.0f / 512.0f);
  float rstd = rsqrtf(var + 1e-5f);
  hr[t] = d0 * rstd * g[t] + b[t];
  hr[t + 256] = d1 * rstd * g[t + 256] + b[t + 256];
}

// ---------------- prob-sparse M scores: one wave per (b,l), coalesced 1KB K rows ----
__global__ __launch_bounds__(256) void prob_scores_wave(const ushort_t* __restrict__ q,
                                                        const ushort_t* __restrict__ k,
                                                        const int* __restrict__ idx,
                                                        float* __restrict__ Mout,
                                                        int L, int S) {
  int wv = (blockIdx.x << 2) + ((threadIdx.x) >> 6);  // wave id over CB*L
  int lane = threadIdx.x & 63;
  int l = wv % L;
  int b = wv / L;
  const ushort_t* qr = q + ((size_t)(b * L + l)) * 512 + lane * 8;
  uint4 qu = *(const uint4*)qr;
  float qf[8];
  qf[0] = b2f_lo(qu.x); qf[1] = b2f_hi(qu.x);
  qf[2] = b2f_lo(qu.y); qf[3] = b2f_hi(qu.y);
  qf[4] = b2f_lo(qu.z); qf[5] = b2f_hi(qu.z);
  qf[6] = b2f_lo(qu.w); qf[7] = b2f_hi(qu.w);
  const int* il = idx + l * S;
  const ushort_t* kb = k + (size_t)b * L * 512 + lane * 8;
  float m = -INFINITY, ssum = 0.0f;
  for (int s = 0; s < S; ++s) {
    int j = il[s];
    uint4 ku = *(const uint4*)(kb + (size_t)j * 512);
    float dot = qf[0] * b2f_lo(ku.x) + qf[1] * b2f_hi(ku.x) +
                qf[2] * b2f_lo(ku.y) + qf[3] * b2f_hi(ku.y) +
                qf[4] * b2f_lo(ku.z) + qf[5] * b2f_hi(ku.z) +
                qf[6] * b2f_lo(ku.w) + qf[7] * b2f_hi(ku.w);
    dot += __shfl_xor(dot, 1);
    dot += __shfl_xor(dot, 2);
    dot += __shfl_xor(dot, 4);
    m = fmaxf(m, dot);
    ssum += dot;
  }
  if ((lane & 7) == 0) {
    int hh = lane >> 3;
    Mout[((size_t)(b * 8 + hh)) * L + l] = m - ssum / (float)L;
  }
}

// ---------------- top-k via 4-pass radix select ----------------
__global__ __launch_bounds__(256) void topk_kernel(const float* __restrict__ Mbuf,
                                                   int* __restrict__ top_idx,
                                                   int L, int S) {
  int bh = blockIdx.x;
  __shared__ uint32_t keys[4096];
  __shared__ int hist[256];
  __shared__ int sh_bin, sh_found, sh_cnt;
  const float* Mr = Mbuf + (size_t)bh * L;
  int t = threadIdx.x;

  for (int j = t; j < L; j += 256) {
    uint32_t u = __float_as_uint(Mr[j]);
    keys[j] = (u & 0x80000000u) ? ~u : (u | 0x80000000u);
  }
  if (t == 0) sh_cnt = 0;
  __syncthreads();

  uint32_t prefix = 0;
  int found = 0;
  for (int p = 24; p >= 0; p -= 8) {
    hist[t] = 0;
    __syncthreads();
    for (int j = t; j < L; j += 256) {
      uint32_t key = keys[j];
      bool match = (p == 24) || ((key >> (p + 8)) == (prefix >> (p + 8)));
      if (match) atomicAdd(&hist[(key >> p) & 255], 1);
    }
    __syncthreads();
    for (int o = 1; o < 256; o <<= 1) {
      int add = (t + o < 256) ? hist[t + o] : 0;
      __syncthreads();
      hist[t] += add;
      __syncthreads();
    }
    int sufIncl = hist[t];
    int sufExcl = (t < 255) ? hist[t + 1] : 0;
    int needv = S - found;
    if (sufExcl < needv && needv <= sufIncl) { sh_bin = t; sh_found = found + sufExcl; }
    __syncthreads();
    prefix |= (uint32_t)sh_bin << p;
    found = sh_found;
    __syncthreads();
  }

  uint32_t tau = prefix;
  int r = S - found;
  int chunk = L >> 8;
  int base = t * chunk;
  int localEq = 0;
  for (int i = 0; i < chunk; ++i) localEq += (keys[base + i] == tau) ? 1 : 0;
  hist[t] = localEq;
  __syncthreads();
  for (int o = 1; o < 256; o <<= 1) {
    int add = (t >= o) ? hist[t - o] : 0;
    __syncthreads();
    hist[t] += add;
    __syncthreads();
  }
  int myRank = hist[t] - localEq;
  for (int i = 0; i < chunk; ++i) {
    uint32_t key = keys[base + i];
    bool isEq = (key == tau);
    bool sel = (key > tau) || (isEq && myRank < r);
    if (isEq) myRank++;
    if (sel) {
      int slot = atomicAdd(&sh_cnt, 1);
      top_idx[bh * S + slot] = base + i;
    }
  }
}

// ---------------- mean of V: stage 1 (coalesced column partial sums) ----------------
__global__ __launch_bounds__(256) void mean_v_partial(const ushort_t* __restrict__ v,
                                                      float* __restrict__ part, int L) {
  int b = blockIdx.x;
  int chunk = blockIdx.y;
  int t = threadIdx.x;
  int c = t * 2;
  const ushort_t* base = v + ((size_t)b * L + (size_t)chunk * 256) * 512 + c;
  float a0 = 0.0f, a1 = 0.0f;
#pragma unroll 8
  for (int r = 0; r < 256; ++r) {
    uint32_t u = *(const uint32_t*)(base + (size_t)r * 512);
    a0 += b2f_lo(u);
    a1 += b2f_hi(u);
  }
  float* p = part + ((size_t)b * 16 + chunk) * 512 + c;
  p[0] = a0;
  p[1] = a1;
}

// ---------------- mean of V: stage 2 ----------------
__global__ void mean_v_finish(const float* __restrict__ part, float* __restrict__ mv,
                              int L, int nchunks) {
  int b = blockIdx.x;
  int c = threadIdx.x;  // 512 threads
  float s = 0.0f;
  for (int k = 0; k < nchunks; ++k) s += part[((size_t)b * 16 + k) * 512 + c];
  mv[b * 512 + c] = s / (float)L;
}

// ---------------- fill ctx (bf16) with broadcast mean ----------------
__global__ void fill_ctx(ushort_t* __restrict__ ctx, const float* __restrict__ mv,
                         int L) {
  size_t gid = (size_t)blockIdx.x * 256 + threadIdx.x;  // CB*L*512
  int c = (int)(gid & 511);
  size_t bl = gid >> 9;
  int b = (int)(bl / (size_t)L);
  ctx[gid] = f2b(mv[b * 512 + c]);
}

// ---------------- fused flash attention (no-max softmax: scores bounded) ----------
__global__ __launch_bounds__(256) void flash_attn(const ushort_t* __restrict__ q,
                                                  const ushort_t* __restrict__ k,
                                                  const ushort_t* __restrict__ v,
                                                  const int* __restrict__ top_idx,
                                                  float* __restrict__ pz,
                                                  float* __restrict__ po,
                                                  int L, int S, int CBNH) {
  __shared__ float qs[SMAX * 64];
  __shared__ ushort_t pt[SMAX * 64];
  int bh = blockIdx.y, js = blockIdx.x;
  int hh = bh & 7, b = bh >> 3;
  int t = threadIdx.x;
  int lane = t & 63, w = t >> 6;
  for (int e = t; e < S * 64; e += 256) {
    int u = e >> 6, d = e & 63;
    int l = top_idx[bh * S + u];
    qs[e] = bu2f(q[((size_t)(b * L + l)) * 512 + hh * 64 + d]);
  }
  __syncthreads();
  int j0 = js * 64;
  const ushort_t* kr = k + ((size_t)(b * L + j0 + lane)) * 512 + hh * 64;
  uint4 kreg[8];
#pragma unroll
  for (int c = 0; c < 8; ++c) kreg[c] = ((const uint4*)kr)[c];
  float zs[12];
#pragma unroll
  for (int mi = 0; mi < 12; ++mi) {
    int u = w + mi * 4;
    if (u < S) {
      const float* qu = qs + u * 64;
      float dot = 0.0f;
#pragma unroll
      for (int c = 0; c < 8; ++c) {
        uint4 ku = kreg[c];
        const float* q8 = qu + c * 8;
        dot += q8[0] * b2f_lo(ku.x) + q8[1] * b2f_hi(ku.x) +
               q8[2] * b2f_lo(ku.y) + q8[3] * b2f_hi(ku.y) +
               q8[4] * b2f_lo(ku.z) + q8[5] * b2f_hi(ku.z) +
               q8[6] * b2f_lo(ku.w) + q8[7] * b2f_hi(ku.w);
      }
      float P = __expf(dot * 0.125f);
      ushort_t Pb = f2b(P);
      pt[u * 64 + lane] = Pb;
      float ps = bu2f(Pb);
#pragma unroll
      for (int o2 = 1; o2 < 64; o2 <<= 1) ps += __shfl_xor(ps, o2);
      zs[mi] = ps;
    }
  }
  __syncthreads();
  float oacc[12] = {};
  for (int jb = 0; jb < 64; jb += 4) {
    float vv[4];
#pragma unroll
    for (int r = 0; r < 4; ++r)
      vv[r] = bu2f(v[((size_t)(b * L + j0 + jb + r)) * 512 + hh * 64 + lane]);
#pragma unroll
    for (int mi = 0; mi < 12; ++mi) {
      int u = w + mi * 4;
      if (u < S) {
        const ushort_t* p4 = &pt[u * 64 + jb];
        oacc[mi] += bu2f(p4[0]) * vv[0] + bu2f(p4[1]) * vv[1] +
                    bu2f(p4[2]) * vv[2] + bu2f(p4[3]) * vv[3];
      }
    }
  }
  size_t base = (size_t)js * CBNH + bh;
#pragma unroll
  for (int mi = 0; mi < 12; ++mi) {
    int u = w + mi * 4;
    if (u < S) {
      po[(base * SMAX + u) * 64 + lane] = oacc[mi];
      if (lane == 0) pz[base * SMAX + u] = zs[mi];
    }
  }
}

// ---------------- combine flash partials, /Z, scatter into ctx ----------------
__global__ void flash_finish(const float* __restrict__ pz, const float* __restrict__ po,
                             const int* __restrict__ top_idx, ushort_t* __restrict__ ctx,
                             int L, int S, int CBNH, int fj) {
  int gid = blockIdx.x * 256 + threadIdx.x;  // over CBNH*S*64
  if (gid >= CBNH * S * 64) return;
  int d = gid & 63;
  int r = gid >> 6;  // bh*S + u
  int u = r % S, bh = r / S;
  int hh = bh & 7, b = bh >> 3;
  float Z = 0.0f, O = 0.0f;
  for (int js = 0; js < fj; ++js) {
    size_t pi = ((size_t)js * CBNH + bh) * SMAX + u;
    Z += pz[pi];
    O += po[pi * 64 + d];
  }
  int l = top_idx[bh * S + u];
  ctx[((size_t)(b * L + l)) * 512 + hh * 64 + d] = f2b(O / Z);
}

// ---------------- maxpool window 3 stride 2 ----------------
__global__ void maxpool_kernel(const float* __restrict__ y, float* __restrict__ hout,
                               int L) {
  size_t gid = (size_t)blockIdx.x * 256 + threadIdx.x;  // CB*(L/2)*512
  int Lh = L >> 1;
  int o = (int)(gid & 511);
  size_t bj = gid >> 9;
  int j = (int)(bj % (size_t)Lh);
  int b = (int)(bj / (size_t)Lh);
  const float* base = y + ((size_t)(b * L + 2 * j)) * 512 + o;
  float mx = base[0];
  if (j > 0) mx = fmaxf(mx, base[-512]);
  mx = fmaxf(mx, base[512]);
  hout[gid] = mx;
}

// ---------------- final LN + projection ----------------
__global__ __launch_bounds__(256) void final_ln_proj(const float* __restrict__ h,
                                                     const float* __restrict__ g,
                                                     const float* __restrict__ bb,
                                                     const float* __restrict__ pw,
                                                     const float* __restrict__ pb,
                                                     float* __restrict__ out, int L) {
  int b = blockIdx.x / 47, l = blockIdx.x % 47;
  const float* hr = h + ((size_t)(b * L + l)) * 512;
  int t = threadIdx.x;
  float x0 = hr[t], x1 = hr[t + 256];
  float mean = blk_reduce_sum(x0 + x1) * (1.0f / 512.0f);
  float d0 = x0 - mean, d1 = x1 - mean;
  float var = blk_reduce_sum(d0 * d0 + d1 * d1) * (1.0f / 512.0f);
  float rstd = rsqrtf(var + 1e-5f);
  float y0 = d0 * rstd * g[t] + bb[t];
  float y1 = d1 * rstd * g[t + 256] + bb[t + 256];
  float dot = blk_reduce_sum(y0 * pw[t] + y1 * pw[t + 256]);
  if (t == 0) out[b * 47 + l] = dot + pb[0];
}

// ---------------- launcher ----------------
extern "C" void kernel_launch(void* const* d_in, const int* in_sizes, int n_in,
                              void* d_out, int out_size, void* d_ws, size_t ws_size,
                              hipStream_t stream) {
  const float* x = (const float*)d_in[0];
  const float* emb_W = (const float*)d_in[1];
  const float* emb_b = (const float*)d_in[2];
  const float* Wq = (const float*)d_in[3];
  const float* bq = (const float*)d_in[4];
  const float* Wk = (const float*)d_in[5];
  const float* bk = (const float*)d_in[6];
  const float* Wv = (const float*)d_in[7];
  const float* bv = (const float*)d_in[8];
  const float* Wo = (const float*)d_in[9];
  const float* bo = (const float*)d_in[10];
  const float* fW1 = (const float*)d_in[11];
  const float* fb1 = (const float*)d_in[12];
  const float* fW2 = (const float*)d_in[13];
  const float* fb2 = (const float*)d_in[14];
  const float* ln1g = (const float*)d_in[15];
  const float* ln1b = (const float*)d_in[16];
  const float* ln2g = (const float*)d_in[17];
  const float* ln2b = (const float*)d_in[18];
  const float* cW = (const float*)d_in[19];
  const float* cb = (const float*)d_in[20];
  const float* bng = (const float*)d_in[21];
  const float* bnb = (const float*)d_in[22];
  const float* flng = (const float*)d_in[23];
  const float* flnb = (const float*)d_in[24];
  const float* pW = (const float*)d_in[25];
  const float* pb = (const float*)d_in[26];
  float* out = (float*)d_out;

  // base batch-group size from ws_size (try 16, 8, 4, 2, 1)
  int CB0 = 16;
  while (CB0 > 1) {
    size_t need = 35732992ull + (size_t)CB0 * 6806016ull;
    if (need * 4 <= ws_size) break;
    CB0 >>= 1;
  }
  const size_t CBseg = (size_t)CB0 * 2097152ull;  // CB0*4096*512 (bf16 elems)

  float* ws = (float*)d_ws;
  size_t off = 0;
  float* h = ws;                           off += 33554432ull;
  ushort_t* wbase = (ushort_t*)(ws + off); off += 1966080ull;
  ushort_t* WqkvT = wbase;                 // 1536 x 512 (q rows, k rows, v rows)
  ushort_t* WoT = wbase + 786432;
  ushort_t* W1b = wbase + 1048576;
  ushort_t* W2b = wbase + 2097152;
  ushort_t* Wcb = wbase + 3145728;
  float* bqkv = ws + off;                  off += 1536ull;
  ushort_t* gArea = (ushort_t*)(ws + off); off += (5ull * CBseg) / 2;
  ushort_t* hb = gArea;
  ushort_t* qb = gArea + CBseg;
  ushort_t* kbuf = gArea + 2 * CBseg;
  ushort_t* vb = gArea + 3 * CBseg;
  ushort_t* ctxb = gArea + 4 * CBseg;
  ushort_t* ybuf = qb;           // spans qb..ctxb (4*CBseg bf16)
  float* convY = (float*)qb;     // spans qb,kbuf (CBseg f32)
  float* Mbuf = ws + off;                  off += (size_t)CB0 * 32768;
  float* mv = ws + off;                    off += 8192ull;               // 16*512
  int* topidx = (int*)(ws + off);          off += 6144ull;               // 16*8*48
  int* idxbuf = (int*)(ws + off);          off += 196608ull;
  float* pzb = ws + off;                   off += (size_t)CB0 * 23040;   // (fj*CBNH=512*CB0)*SMAX
  float* pob = ws + off;                   off += (size_t)CB0 * 1474560; // ... *64
  float* mvpart = ws + off;                off += 131072ull;             // 16*16*512

  // embedding (float4 per thread)
  {
    size_t total = (size_t)NB * 4096 * 128;
    embed_kernel<<<(int)(total / 256), 256, 0, stream>>>(x, emb_W, emb_b, h);
  }

  int L = 4096;
  for (int i = 0; i < 3; ++i) {
    int S = (i == 0) ? 45 : (i == 1) ? 40 : 35;
    // layer-adaptive group size: same bytes per group across layers
    int CBl = CB0 * (4096 / L);
    if (CBl > NB) CBl = NB;
    int ngroups = NB / CBl;
    int CBNHl = CBl * NH;
    int Mg = CBl * L;                      // rows per group (const when uncapped)
    size_t segL = (size_t)Mg * 512;
    int fj = L / 64;                       // key splits: 64 / 32 / 16

    // per-layer weight casts
    castT512<<<1024, 256, 0, stream>>>(Wq + (size_t)i * 262144, WqkvT);
    castT512<<<1024, 256, 0, stream>>>(Wk + (size_t)i * 262144, WqkvT + 262144);
    castT512<<<1024, 256, 0, stream>>>(Wv + (size_t)i * 262144, WqkvT + 524288);
    castT512<<<1024, 256, 0, stream>>>(Wo + (size_t)i * 262144, WoT);
    cast_bf16<<<1024, 256, 0, stream>>>(fW1 + (size_t)i * 1048576, W1b, 1048576);
    cast_bf16<<<1024, 256, 0, stream>>>(fW2 + (size_t)i * 1048576, W2b, 1048576);
    if (i < 2) cast_convW<<<3072, 256, 0, stream>>>(cW + (size_t)i * 786432, Wcb);
    concat3<<<6, 256, 0, stream>>>(bq + i * DM, bk + i * DM, bv + i * DM, bqkv);

    // JAX randint key
    uint32_t fa, fbk;
    tf2x32(0u, 42u, 0u, (uint32_t)i, &fa, &fbk);
    uint32_t a0, b0, a1, b1;
    tf2x32(fa, fbk, 0u, 2u, &a0, &b0);
    tf2x32(fa, fbk, 1u, 3u, &a1, &b1);
    int n = L * S;
    gen_idx_kernel<<<(n + 255) / 256, 256, 0, stream>>>(idxbuf, b0, b1, n, L - 1);

    // ---- attention per batch group ----
    for (int g = 0; g < ngroups; ++g) {
      float* hg = h + (size_t)g * segL;
      cast_bf16<<<(int)(segL / 1024), 256, 0, stream>>>(hg, hb, segL);
      dim3 gqkv(12, Mg / 128);
      mfma_gemm<2, 0><<<gqkv, 256, 0, stream>>>(hb, WqkvT, bqkv, nullptr, qb,
                                                nullptr, nullptr, 1536, 512,
                                                (int)CBseg);

      prob_scores_wave<<<(CBl * L) / 4, 256, 0, stream>>>(qb, kbuf, idxbuf, Mbuf, L, S);
      topk_kernel<<<CBNHl, 256, 0, stream>>>(Mbuf, topidx, L, S);

      mean_v_partial<<<dim3(CBl, L / 256), 256, 0, stream>>>(vb, mvpart, L);
      mean_v_finish<<<CBl, 512, 0, stream>>>(mvpart, mv, L, L / 256);
      fill_ctx<<<(int)(segL / 256), 256, 0, stream>>>(ctxb, mv, L);
      flash_attn<<<dim3(fj, CBNHl), 256, 0, stream>>>(qb, kbuf, vb, topidx,
                                                      pzb, pob, L, S, CBNHl);
      flash_finish<<<(CBNHl * S * 64 + 255) / 256, 256, 0, stream>>>(
          pzb, pob, topidx, ctxb, L, S, CBNHl, fj);

      dim3 gq(4, Mg / 128);
      mfma_gemm<0, 1><<<gq, 256, 0, stream>>>(ctxb, WoT, bo + i * DM, hg, nullptr,
                                              nullptr, nullptr, 512, 512, 0);
    }
    ln_inplace<<<NB * L, 256, 0, stream>>>(h, ln1g + i * DM, ln1b + i * DM);

    // ---- FF row-chunked ----
    int rows = NB * L;
    int R = CB0 * 4096;
    if (R > rows) R = rows;
    for (int r0 = 0; r0 < rows; r0 += R) {
      float* hr = h + (size_t)r0 * 512;
      size_t rseg = (size_t)R * 512;
      cast_bf16<<<(int)(rseg / 1024), 256, 0, stream>>>(hr, hb, rseg);
      dim3 g1(16, R / 128);
      mfma_gemm<0, 2><<<g1, 256, 0, stream>>>(hb, W1b, fb1 + i * DFF_, nullptr, ybuf,
                                              nullptr, nullptr, 2048, 512, 0);
      dim3 g2(4, R / 128);
      mfma_gemm<0, 1><<<g2, 256, 0, stream>>>(ybuf, W2b, fb2 + i * DM, hr, nullptr,
                                              nullptr, nullptr, 512, 2048, 0);
    }
    ln_inplace<<<NB * L, 256, 0, stream>>>(h, ln2g + i * DM, ln2b + i * DM);

    // ---- conv + maxpool per batch group ----
    if (i < 2) {
      int Lh = L / 2;
      for (int g = 0; g < ngroups; ++g) {
        float* hg = h + (size_t)g * segL;
        cast_bf16<<<(int)(segL / 1024), 256, 0, stream>>>(hg, hb, segL);
        dim3 gc(4, Mg / 128);
        mfma_gemm<1, 3><<<gc, 256, 0, stream>>>(hb, Wcb, cb + i * DM, convY, nullptr,
                                                bng + i * DM, bnb + i * DM, 512, 1536, L);
        size_t tot = (size_t)CBl * Lh * 512;
        maxpool_kernel<<<(int)(tot / 256), 256, 0, stream>>>(
            convY, h + (size_t)g * CBl * Lh * 512, L);
      }
      L = Lh;
    }
  }

  final_ln_proj<<<NB * 47, 256, 0, stream>>>(h, flng, flnb, pW, pb, out, L);
}

// Round 14
// 3508.429 us; speedup vs baseline: 2.6940x; 1.0344x over previous
//
#include <hip/hip_runtime.h>
#include <cstdint>
#include <math.h>

#define NB 16
#define DM 512
#define NH 8
#define DFF_ 2048
#define SMAX 45

typedef unsigned short ushort_t;
typedef __bf16 bf16x8 __attribute__((ext_vector_type(8)));
typedef float f32x4 __attribute__((ext_vector_type(4)));

// ---------------- bf16 helpers ----------------
__device__ __forceinline__ ushort_t f2b(float f) {  // RNE f32 -> bf16 bits
  uint32_t u = __float_as_uint(f);
  uint32_t r = (u + 0x7FFFu + ((u >> 16) & 1u)) >> 16;
  return (ushort_t)r;
}
__device__ __forceinline__ float bu2f(ushort_t x) {
  return __uint_as_float((uint32_t)x << 16);
}
__device__ __forceinline__ float b2f_lo(uint32_t u) { return __uint_as_float(u << 16); }
__device__ __forceinline__ float b2f_hi(uint32_t u) { return __uint_as_float(u & 0xFFFF0000u); }

// ---------------- threefry2x32 (JAX-compatible) ----------------
__host__ __device__ inline void tf2x32(uint32_t k0, uint32_t k1,
                                       uint32_t x0, uint32_t x1,
                                       uint32_t* o0, uint32_t* o1) {
  uint32_t ks0 = k0, ks1 = k1, ks2 = k0 ^ k1 ^ 0x1BD11BDAu;
  x0 += ks0; x1 += ks1;
#define TF_RND(r) { x0 += x1; x1 = (x1 << (r)) | (x1 >> (32 - (r))); x1 ^= x0; }
  TF_RND(13) TF_RND(15) TF_RND(26) TF_RND(6)
  x0 += ks1; x1 += ks2 + 1u;
  TF_RND(17) TF_RND(29) TF_RND(16) TF_RND(24)
  x0 += ks2; x1 += ks0 + 2u;
  TF_RND(13) TF_RND(15) TF_RND(26) TF_RND(6)
  x0 += ks0; x1 += ks1 + 3u;
  TF_RND(17) TF_RND(29) TF_RND(16) TF_RND(24)
  x0 += ks1; x1 += ks2 + 4u;
  TF_RND(13) TF_RND(15) TF_RND(26) TF_RND(6)
  x0 += ks2; x1 += ks0 + 5u;
#undef TF_RND
  *o0 = x0; *o1 = x1;
}

__global__ void gen_idx_kernel(int* __restrict__ idx, uint32_t k0, uint32_t k1,
                               int n, int mask) {
  int j = blockIdx.x * 256 + threadIdx.x;
  if (j >= n) return;
  int half = n >> 1;
  uint32_t o0, o1;
  if (j < half) {
    tf2x32(k0, k1, (uint32_t)j, (uint32_t)(j + half), &o0, &o1);
    idx[j] = (int)(o0 & (uint32_t)mask);
  } else {
    tf2x32(k0, k1, (uint32_t)(j - half), (uint32_t)j, &o0, &o1);
    idx[j] = (int)(o1 & (uint32_t)mask);
  }
}

// ---------------- block reduce helpers (256 threads, wave64) ----------------
__device__ inline float blk_reduce_sum(float v) {
  __shared__ float s[4];
  for (int o = 32; o > 0; o >>= 1) v += __shfl_down(v, o);
  int lane = threadIdx.x & 63, w = threadIdx.x >> 6;
  if (lane == 0) s[w] = v;
  __syncthreads();
  float r = s[0] + s[1] + s[2] + s[3];
  __syncthreads();
  return r;
}

// ---------------- embedding (float4 per thread) ----------------
__global__ void embed_kernel(const float* __restrict__ x, const float* __restrict__ W,
                             const float* __restrict__ bias, float* __restrict__ h) {
  size_t gid = (size_t)blockIdx.x * 256 + threadIdx.x;  // over NB*4096*128 quads
  int o4 = (int)(gid & 127) * 4;
  size_t bl = gid >> 7;
  const float* xr = x + bl * 7;
  float xv[7];
#pragma unroll
  for (int i = 0; i < 7; ++i) xv[i] = xr[i];
  float4 acc = *(const float4*)(bias + o4);
#pragma unroll
  for (int i = 0; i < 7; ++i) {
    float4 w4 = *(const float4*)(W + i * 512 + o4);
    acc.x += xv[i] * w4.x;
    acc.y += xv[i] * w4.y;
    acc.z += xv[i] * w4.z;
    acc.w += xv[i] * w4.w;
  }
  *(float4*)(h + bl * 512 + o4) = acc;
}

// ---------------- cast kernels ----------------
__global__ void cast_bf16(const float* __restrict__ src, ushort_t* __restrict__ dst,
                          size_t n) {
  size_t i = ((size_t)blockIdx.x * 256 + threadIdx.x) * 4;
  if (i >= n) return;
  float4 v = *(const float4*)(src + i);
  ushort4 o;
  o.x = f2b(v.x); o.y = f2b(v.y); o.z = f2b(v.z); o.w = f2b(v.w);
  *(ushort4*)(dst + i) = o;
}

// Bt[n*512+k] = bf16(W[k*512+n])   (512x512)
__global__ void castT512(const float* __restrict__ W, ushort_t* __restrict__ Bt) {
  int gid = blockIdx.x * 256 + threadIdx.x;
  int n = gid >> 9, k = gid & 511;
  Bt[gid] = f2b(W[(size_t)k * 512 + n]);
}

// Bt[n*1536 + dt*512 + i] = bf16(convW[n][i][dt])
__global__ void cast_convW(const float* __restrict__ W, ushort_t* __restrict__ Bt) {
  int gid = blockIdx.x * 256 + threadIdx.x;
  int n = gid / 1536, k = gid - n * 1536;
  int dt = k >> 9, ii = k & 511;
  Bt[gid] = f2b(W[((size_t)n * 512 + ii) * 3 + dt]);
}

// concat 3x512 bias -> 1536
__global__ void concat3(const float* __restrict__ a, const float* __restrict__ b,
                        const float* __restrict__ c, float* __restrict__ o) {
  int t = blockIdx.x * 256 + threadIdx.x;
  if (t >= 1536) return;
  o[t] = t < 512 ? a[t] : (t < 1024 ? b[t - 512] : c[t - 1024]);
}

// ---------------- bf16 MFMA GEMM (m97 structure + T2 XOR swizzle) ----------------
__device__ __forceinline__ float gelu_exact(float c) {
  return 0.5f * c * (1.0f + erff(c * 0.70710678118654752f));
}

template <int MODE, int EPI>
__global__ __launch_bounds__(256) void mfma_gemm(
    const ushort_t* __restrict__ A, const ushort_t* __restrict__ Bt,
    const float* __restrict__ bias, float* __restrict__ Cf,
    ushort_t* __restrict__ Cb, const float* __restrict__ bng,
    const float* __restrict__ bnb, int N, int K, int L) {
  __shared__ __align__(16) ushort_t As[128 * 64];
  __shared__ __align__(16) ushort_t Bs[128 * 64];
  const int tid = threadIdx.x;
  const int lane = tid & 63;
  const int wid = tid >> 6;
  const int wr = wid >> 1, wc = wid & 1;
  const int bm = blockIdx.y, bn = blockIdx.x;
  const int ln = lane & 15, lh = lane >> 4;

  f32x4 acc[4][4] = {};

  for (int k0 = 0; k0 < K; k0 += 64) {
    __syncthreads();
#pragma unroll
    for (int it = 0; it < 4; ++it) {
      int c = it * 256 + tid;
      int row = c >> 3;
      int kc = (((c & 7) ^ (row & 7)) << 3);  // swizzled source chunk
      size_t ga;
      if (MODE == 1) {
        int m = bm * 128 + row;
        int b = m / L, tpos = m - b * L;
        int k = k0 + kc;
        int dt = k >> 9, ii = k & 511;
        int tr2 = tpos + dt - 1;
        if (tr2 < 0) tr2 += L;
        if (tr2 >= L) tr2 -= L;
        ga = ((size_t)(b * L + tr2)) * 512 + ii;
      } else {
        ga = (size_t)(bm * 128 + row) * K + k0 + kc;
      }
      __builtin_amdgcn_global_load_lds(
          (const __attribute__((address_space(1))) void*)(A + ga),
          (__attribute__((address_space(3))) void*)(As + c * 8), 16, 0, 0);
      size_t gb = (size_t)(bn * 128 + row) * K + k0 + kc;
      __builtin_amdgcn_global_load_lds(
          (const __attribute__((address_space(1))) void*)(Bt + gb),
          (__attribute__((address_space(3))) void*)(Bs + c * 8), 16, 0, 0);
    }
    __syncthreads();
#pragma unroll
    for (int kk = 0; kk < 2; ++kk) {
      bf16x8 af[4], bf_[4];
#pragma unroll
      for (int m = 0; m < 4; ++m) {
        int ar = wr * 64 + m * 16 + ln;
        int aoff = (kk * 32 + lh * 8) ^ ((ar & 7) << 3);
        af[m] = *(const bf16x8*)&As[ar * 64 + aoff];
      }
#pragma unroll
      for (int n = 0; n < 4; ++n) {
        int br = wc * 64 + n * 16 + ln;
        int boff = (kk * 32 + lh * 8) ^ ((br & 7) << 3);
        bf_[n] = *(const bf16x8*)&Bs[br * 64 + boff];
      }
#pragma unroll
      for (int m = 0; m < 4; ++m)
#pragma unroll
        for (int n = 0; n < 4; ++n)
          acc[m][n] =
              __builtin_amdgcn_mfma_f32_16x16x32_bf16(af[m], bf_[n], acc[m][n], 0, 0, 0);
    }
  }

  const float bnscale = 0.9999950000374996f;  // 1/sqrt(1+1e-5)
#pragma unroll
  for (int m = 0; m < 4; ++m) {
    int row = bm * 128 + wr * 64 + m * 16 + lh * 4;
#pragma unroll
    for (int n = 0; n < 4; ++n) {
      int col = bn * 128 + wc * 64 + n * 16 + ln;
      float bsv = bias[col];
#pragma unroll
      for (int r = 0; r < 4; ++r) {
        float cval = acc[m][n][r] + bsv;
        if (MODE == 2) {
          ushort_t* dst = Cb + (size_t)(bn >> 2) * (size_t)L;  // L = CBseg
          dst[(size_t)(row + r) * 512 + (col & 511)] = f2b(cval);
        } else {
          size_t oi = (size_t)(row + r) * N + col;
          if (EPI == 0) {
            Cb[oi] = f2b(cval);
          } else if (EPI == 1) {
            Cf[oi] += cval;
          } else if (EPI == 2) {
            Cb[oi] = f2b(gelu_exact(cval));
          } else {
            float c2 = cval * bnscale * bng[col] + bnb[col];
            Cf[oi] = c2 > 0.0f ? c2 : expm1f(c2);
          }
        }
      }
    }
  }
}

// ---------------- LN (in-place, row = 512) ----------------
__global__ __launch_bounds__(256) void ln_inplace(float* __restrict__ h,
                                                  const float* __restrict__ g,
                                                  const float* __restrict__ b) {
  size_t row = blockIdx.x;
  float* hr = h + row * 512;
  int t = threadIdx.x;
  float x0 = hr[t], x1 = hr[t + 256];
  float mean = blk_reduce_sum(x0 + x1) * (1.0f / 512.0f);
  float d0 = x0 - mean, d1 = x1 - mean;
  float var = blk_reduce_sum(d0 * d0 + d1 * d1) * (1.0f / 512.0f);
  float rstd = rsqrtf(var + 1e-5f);
  hr[t] = d0 * rstd * g[t] + b[t];
  hr[t + 256] = d1 * rstd * g[t + 256] + b[t + 256];
}

// ---------------- prob-sparse M scores: one wave per (b,l) + XCD-pinned b ----------
// Block->(b,l) mapping pins each batch b to a fixed XCD subset so b's 1-4MB
// K slice stays resident in that XCD's L2 (avoids 6-8x cross-XCD re-fetch).
__global__ __launch_bounds__(256) void prob_scores_wave(const ushort_t* __restrict__ q,
                                                        const ushort_t* __restrict__ k,
                                                        const int* __restrict__ idx,
                                                        float* __restrict__ Mout,
                                                        int L, int S, int CBl) {
  int bid = blockIdx.x;
  int w = threadIdx.x >> 6;
  int lane = threadIdx.x & 63;
  // bijective XCD-locality swizzle (grid size CBl*L/4, always %8==0)
  int nxb = CBl < 8 ? CBl : 8;  // XCD groups carrying distinct b
  int gpb = 8 / nxb;            // XCD slots per b   (CBl<8)
  int bmul = CBl / nxb;         // b's folded per slot (CBl>8)
  int xcd = bid & 7;
  int rest = bid >> 3;
  int b = (xcd / gpb) * bmul + (rest % bmul);
  int li = (rest / bmul) * gpb + (xcd % gpb);  // l-chunk in [0, L/4)
  int l = li * 4 + w;

  const ushort_t* qr = q + ((size_t)(b * L + l)) * 512 + lane * 8;
  uint4 qu = *(const uint4*)qr;
  float qf[8];
  qf[0] = b2f_lo(qu.x); qf[1] = b2f_hi(qu.x);
  qf[2] = b2f_lo(qu.y); qf[3] = b2f_hi(qu.y);
  qf[4] = b2f_lo(qu.z); qf[5] = b2f_hi(qu.z);
  qf[6] = b2f_lo(qu.w); qf[7] = b2f_hi(qu.w);
  const int* il = idx + l * S;
  const ushort_t* kb = k + (size_t)b * L * 512 + lane * 8;
  float m = -INFINITY, ssum = 0.0f;
  for (int s = 0; s < S; ++s) {
    int j = il[s];
    uint4 ku = *(const uint4*)(kb + (size_t)j * 512);
    float dot = qf[0] * b2f_lo(ku.x) + qf[1] * b2f_hi(ku.x) +
                qf[2] * b2f_lo(ku.y) + qf[3] * b2f_hi(ku.y) +
                qf[4] * b2f_lo(ku.z) + qf[5] * b2f_hi(ku.z) +
                qf[6] * b2f_lo(ku.w) + qf[7] * b2f_hi(ku.w);
    dot += __shfl_xor(dot, 1);
    dot += __shfl_xor(dot, 2);
    dot += __shfl_xor(dot, 4);
    m = fmaxf(m, dot);
    ssum += dot;
  }
  if ((lane & 7) == 0) {
    int hh = lane >> 3;
    Mout[((size_t)(b * 8 + hh)) * L + l] = m - ssum / (float)L;
  }
}

// ---------------- top-k via 4-pass radix select ----------------
__global__ __launch_bounds__(256) void topk_kernel(const float* __restrict__ Mbuf,
                                                   int* __restrict__ top_idx,
                                                   int L, int S) {
  int bh = blockIdx.x;
  __shared__ uint32_t keys[4096];
  __shared__ int hist[256];
  __shared__ int sh_bin, sh_found, sh_cnt;
  const float* Mr = Mbuf + (size_t)bh * L;
  int t = threadIdx.x;

  for (int j = t; j < L; j += 256) {
    uint32_t u = __float_as_uint(Mr[j]);
    keys[j] = (u & 0x80000000u) ? ~u : (u | 0x80000000u);
  }
  if (t == 0) sh_cnt = 0;
  __syncthreads();

  uint32_t prefix = 0;
  int found = 0;
  for (int p = 24; p >= 0; p -= 8) {
    hist[t] = 0;
    __syncthreads();
    for (int j = t; j < L; j += 256) {
      uint32_t key = keys[j];
      bool match = (p == 24) || ((key >> (p + 8)) == (prefix >> (p + 8)));
      if (match) atomicAdd(&hist[(key >> p) & 255], 1);
    }
    __syncthreads();
    for (int o = 1; o < 256; o <<= 1) {
      int add = (t + o < 256) ? hist[t + o] : 0;
      __syncthreads();
      hist[t] += add;
      __syncthreads();
    }
    int sufIncl = hist[t];
    int sufExcl = (t < 255) ? hist[t + 1] : 0;
    int needv = S - found;
    if (sufExcl < needv && needv <= sufIncl) { sh_bin = t; sh_found = found + sufExcl; }
    __syncthreads();
    prefix |= (uint32_t)sh_bin << p;
    found = sh_found;
    __syncthreads();
  }

  uint32_t tau = prefix;
  int r = S - found;
  int chunk = L >> 8;
  int base = t * chunk;
  int localEq = 0;
  for (int i = 0; i < chunk; ++i) localEq += (keys[base + i] == tau) ? 1 : 0;
  hist[t] = localEq;
  __syncthreads();
  for (int o = 1; o < 256; o <<= 1) {
    int add = (t >= o) ? hist[t - o] : 0;
    __syncthreads();
    hist[t] += add;
    __syncthreads();
  }
  int myRank = hist[t] - localEq;
  for (int i = 0; i < chunk; ++i) {
    uint32_t key = keys[base + i];
    bool isEq = (key == tau);
    bool sel = (key > tau) || (isEq && myRank < r);
    if (isEq) myRank++;
    if (sel) {
      int slot = atomicAdd(&sh_cnt, 1);
      top_idx[bh * S + slot] = base + i;
    }
  }
}

// ---------------- mean of V: stage 1 (coalesced column partial sums) ----------------
__global__ __launch_bounds__(256) void mean_v_partial(const ushort_t* __restrict__ v,
                                                      float* __restrict__ part, int L) {
  int b = blockIdx.x;
  int chunk = blockIdx.y;
  int t = threadIdx.x;
  int c = t * 2;
  const ushort_t* base = v + ((size_t)b * L + (size_t)chunk * 256) * 512 + c;
  float a0 = 0.0f, a1 = 0.0f;
#pragma unroll 8
  for (int r = 0; r < 256; ++r) {
    uint32_t u = *(const uint32_t*)(base + (size_t)r * 512);
    a0 += b2f_lo(u);
    a1 += b2f_hi(u);
  }
  float* p = part + ((size_t)b * 16 + chunk) * 512 + c;
  p[0] = a0;
  p[1] = a1;
}

// ---------------- mean of V: stage 2 ----------------
__global__ void mean_v_finish(const float* __restrict__ part, float* __restrict__ mv,
                              int L, int nchunks) {
  int b = blockIdx.x;
  int c = threadIdx.x;  // 512 threads
  float s = 0.0f;
  for (int k = 0; k < nchunks; ++k) s += part[((size_t)b * 16 + k) * 512 + c];
  mv[b * 512 + c] = s / (float)L;
}

// ---------------- fill ctx (bf16) with broadcast mean ----------------
__global__ void fill_ctx(ushort_t* __restrict__ ctx, const float* __restrict__ mv,
                         int L) {
  size_t gid = (size_t)blockIdx.x * 256 + threadIdx.x;  // CB*L*512
  int c = (int)(gid & 511);
  size_t bl = gid >> 9;
  int b = (int)(bl / (size_t)L);
  ctx[gid] = f2b(mv[b * 512 + c]);
}

// ---------------- fused flash attention (no-max softmax: scores bounded) ----------
__global__ __launch_bounds__(256) void flash_attn(const ushort_t* __restrict__ q,
                                                  const ushort_t* __restrict__ k,
                                                  const ushort_t* __restrict__ v,
                                                  const int* __restrict__ top_idx,
                                                  float* __restrict__ pz,
                                                  float* __restrict__ po,
                                                  int L, int S, int CBNH) {
  __shared__ float qs[SMAX * 64];
  __shared__ ushort_t pt[SMAX * 64];
  int bh = blockIdx.y, js = blockIdx.x;
  int hh = bh & 7, b = bh >> 3;
  int t = threadIdx.x;
  int lane = t & 63, w = t >> 6;
  for (int e = t; e < S * 64; e += 256) {
    int u = e >> 6, d = e & 63;
    int l = top_idx[bh * S + u];
    qs[e] = bu2f(q[((size_t)(b * L + l)) * 512 + hh * 64 + d]);
  }
  __syncthreads();
  int j0 = js * 64;
  const ushort_t* kr = k + ((size_t)(b * L + j0 + lane)) * 512 + hh * 64;
  uint4 kreg[8];
#pragma unroll
  for (int c = 0; c < 8; ++c) kreg[c] = ((const uint4*)kr)[c];
  float zs[12];
#pragma unroll
  for (int mi = 0; mi < 12; ++mi) {
    int u = w + mi * 4;
    if (u < S) {
      const float* qu = qs + u * 64;
      float dot = 0.0f;
#pragma unroll
      for (int c = 0; c < 8; ++c) {
        uint4 ku = kreg[c];
        const float* q8 = qu + c * 8;
        dot += q8[0] * b2f_lo(ku.x) + q8[1] * b2f_hi(ku.x) +
               q8[2] * b2f_lo(ku.y) + q8[3] * b2f_hi(ku.y) +
               q8[4] * b2f_lo(ku.z) + q8[5] * b2f_hi(ku.z) +
               q8[6] * b2f_lo(ku.w) + q8[7] * b2f_hi(ku.w);
      }
      float P = __expf(dot * 0.125f);
      ushort_t Pb = f2b(P);
      pt[u * 64 + lane] = Pb;
      float ps = bu2f(Pb);
#pragma unroll
      for (int o2 = 1; o2 < 64; o2 <<= 1) ps += __shfl_xor(ps, o2);
      zs[mi] = ps;
    }
  }
  __syncthreads();
  float oacc[12] = {};
  for (int jb = 0; jb < 64; jb += 4) {
    float vv[4];
#pragma unroll
    for (int r = 0; r < 4; ++r)
      vv[r] = bu2f(v[((size_t)(b * L + j0 + jb + r)) * 512 + hh * 64 + lane]);
#pragma unroll
    for (int mi = 0; mi < 12; ++mi) {
      int u = w + mi * 4;
      if (u < S) {
        const ushort_t* p4 = &pt[u * 64 + jb];
        oacc[mi] += bu2f(p4[0]) * vv[0] + bu2f(p4[1]) * vv[1] +
                    bu2f(p4[2]) * vv[2] + bu2f(p4[3]) * vv[3];
      }
    }
  }
  size_t base = (size_t)js * CBNH + bh;
#pragma unroll
  for (int mi = 0; mi < 12; ++mi) {
    int u = w + mi * 4;
    if (u < S) {
      po[(base * SMAX + u) * 64 + lane] = oacc[mi];
      if (lane == 0) pz[base * SMAX + u] = zs[mi];
    }
  }
}

// ---------------- combine flash partials, /Z, scatter into ctx ----------------
__global__ void flash_finish(const float* __restrict__ pz, const float* __restrict__ po,
                             const int* __restrict__ top_idx, ushort_t* __restrict__ ctx,
                             int L, int S, int CBNH, int fj) {
  int gid = blockIdx.x * 256 + threadIdx.x;  // over CBNH*S*64
  if (gid >= CBNH * S * 64) return;
  int d = gid & 63;
  int r = gid >> 6;  // bh*S + u
  int u = r % S, bh = r / S;
  int hh = bh & 7, b = bh >> 3;
  float Z = 0.0f, O = 0.0f;
  for (int js = 0; js < fj; ++js) {
    size_t pi = ((size_t)js * CBNH + bh) * SMAX + u;
    Z += pz[pi];
    O += po[pi * 64 + d];
  }
  int l = top_idx[bh * S + u];
  ctx[((size_t)(b * L + l)) * 512 + hh * 64 + d] = f2b(O / Z);
}

// ---------------- maxpool window 3 stride 2 ----------------
__global__ void maxpool_kernel(const float* __restrict__ y, float* __restrict__ hout,
                               int L) {
  size_t gid = (size_t)blockIdx.x * 256 + threadIdx.x;  // CB*(L/2)*512
  int Lh = L >> 1;
  int o = (int)(gid & 511);
  size_t bj = gid >> 9;
  int j = (int)(bj % (size_t)Lh);
  int b = (int)(bj / (size_t)Lh);
  const float* base = y + ((size_t)(b * L + 2 * j)) * 512 + o;
  float mx = base[0];
  if (j > 0) mx = fmaxf(mx, base[-512]);
  mx = fmaxf(mx, base[512]);
  hout[gid] = mx;
}

// ---------------- final LN + projection ----------------
__global__ __launch_bounds__(256) void final_ln_proj(const float* __restrict__ h,
                                                     const float* __restrict__ g,
                                                     const float* __restrict__ bb,
                                                     const float* __restrict__ pw,
                                                     const float* __restrict__ pb,
                                                     float* __restrict__ out, int L) {
  int b = blockIdx.x / 47, l = blockIdx.x % 47;
  const float* hr = h + ((size_t)(b * L + l)) * 512;
  int t = threadIdx.x;
  float x0 = hr[t], x1 = hr[t + 256];
  float mean = blk_reduce_sum(x0 + x1) * (1.0f / 512.0f);
  float d0 = x0 - mean, d1 = x1 - mean;
  float var = blk_reduce_sum(d0 * d0 + d1 * d1) * (1.0f / 512.0f);
  float rstd = rsqrtf(var + 1e-5f);
  float y0 = d0 * rstd * g[t] + bb[t];
  float y1 = d1 * rstd * g[t + 256] + bb[t + 256];
  float dot = blk_reduce_sum(y0 * pw[t] + y1 * pw[t + 256]);
  if (t == 0) out[b * 47 + l] = dot + pb[0];
}

// ---------------- launcher ----------------
extern "C" void kernel_launch(void* const* d_in, const int* in_sizes, int n_in,
                              void* d_out, int out_size, void* d_ws, size_t ws_size,
                              hipStream_t stream) {
  const float* x = (const float*)d_in[0];
  const float* emb_W = (const float*)d_in[1];
  const float* emb_b = (const float*)d_in[2];
  const float* Wq = (const float*)d_in[3];
  const float* bq = (const float*)d_in[4];
  const float* Wk = (const float*)d_in[5];
  const float* bk = (const float*)d_in[6];
  const float* Wv = (const float*)d_in[7];
  const float* bv = (const float*)d_in[8];
  const float* Wo = (const float*)d_in[9];
  const float* bo = (const float*)d_in[10];
  const float* fW1 = (const float*)d_in[11];
  const float* fb1 = (const float*)d_in[12];
  const float* fW2 = (const float*)d_in[13];
  const float* fb2 = (const float*)d_in[14];
  const float* ln1g = (const float*)d_in[15];
  const float* ln1b = (const float*)d_in[16];
  const float* ln2g = (const float*)d_in[17];
  const float* ln2b = (const float*)d_in[18];
  const float* cW = (const float*)d_in[19];
  const float* cb = (const float*)d_in[20];
  const float* bng = (const float*)d_in[21];
  const float* bnb = (const float*)d_in[22];
  const float* flng = (const float*)d_in[23];
  const float* flnb = (const float*)d_in[24];
  const float* pW = (const float*)d_in[25];
  const float* pb = (const float*)d_in[26];
  float* out = (float*)d_out;

  // base batch-group size from ws_size (try 16, 8, 4, 2, 1)
  int CB0 = 16;
  while (CB0 > 1) {
    size_t need = 35732992ull + (size_t)CB0 * 6806016ull;
    if (need * 4 <= ws_size) break;
    CB0 >>= 1;
  }
  const size_t CBseg = (size_t)CB0 * 2097152ull;  // CB0*4096*512 (bf16 elems)

  float* ws = (float*)d_ws;
  size_t off = 0;
  float* h = ws;                           off += 33554432ull;
  ushort_t* wbase = (ushort_t*)(ws + off); off += 1966080ull;
  ushort_t* WqkvT = wbase;                 // 1536 x 512 (q rows, k rows, v rows)
  ushort_t* WoT = wbase + 786432;
  ushort_t* W1b = wbase + 1048576;
  ushort_t* W2b = wbase + 2097152;
  ushort_t* Wcb = wbase + 3145728;
  float* bqkv = ws + off;                  off += 1536ull;
  ushort_t* gArea = (ushort_t*)(ws + off); off += (5ull * CBseg) / 2;
  ushort_t* hb = gArea;
  ushort_t* qb = gArea + CBseg;
  ushort_t* kbuf = gArea + 2 * CBseg;
  ushort_t* vb = gArea + 3 * CBseg;
  ushort_t* ctxb = gArea + 4 * CBseg;
  ushort_t* ybuf = qb;           // spans qb..ctxb (4*CBseg bf16)
  float* convY = (float*)qb;     // spans qb,kbuf (CBseg f32)
  float* Mbuf = ws + off;                  off += (size_t)CB0 * 32768;
  float* mv = ws + off;                    off += 8192ull;               // 16*512
  int* topidx = (int*)(ws + off);          off += 6144ull;               // 16*8*48
  int* idxbuf = (int*)(ws + off);          off += 196608ull;
  float* pzb = ws + off;                   off += (size_t)CB0 * 23040;   // (fj*CBNH=512*CB0)*SMAX
  float* pob = ws + off;                   off += (size_t)CB0 * 1474560; // ... *64
  float* mvpart = ws + off;                off += 131072ull;             // 16*16*512

  // embedding (float4 per thread)
  {
    size_t total = (size_t)NB * 4096 * 128;
    embed_kernel<<<(int)(total / 256), 256, 0, stream>>>(x, emb_W, emb_b, h);
  }

  int L = 4096;
  for (int i = 0; i < 3; ++i) {
    int S = (i == 0) ? 45 : (i == 1) ? 40 : 35;
    // layer-adaptive group size: same bytes per group across layers
    int CBl = CB0 * (4096 / L);
    if (CBl > NB) CBl = NB;
    int ngroups = NB / CBl;
    int CBNHl = CBl * NH;
    int Mg = CBl * L;                      // rows per group (const when uncapped)
    size_t segL = (size_t)Mg * 512;
    int fj = L / 64;                       // key splits: 64 / 32 / 16

    // per-layer weight casts
    castT512<<<1024, 256, 0, stream>>>(Wq + (size_t)i * 262144, WqkvT);
    castT512<<<1024, 256, 0, stream>>>(Wk + (size_t)i * 262144, WqkvT + 262144);
    castT512<<<1024, 256, 0, stream>>>(Wv + (size_t)i * 262144, WqkvT + 524288);
    castT512<<<1024, 256, 0, stream>>>(Wo + (size_t)i * 262144, WoT);
    cast_bf16<<<1024, 256, 0, stream>>>(fW1 + (size_t)i * 1048576, W1b, 1048576);
    cast_bf16<<<1024, 256, 0, stream>>>(fW2 + (size_t)i * 1048576, W2b, 1048576);
    if (i < 2) cast_convW<<<3072, 256, 0, stream>>>(cW + (size_t)i * 786432, Wcb);
    concat3<<<6, 256, 0, stream>>>(bq + i * DM, bk + i * DM, bv + i * DM, bqkv);

    // JAX randint key
    uint32_t fa, fbk;
    tf2x32(0u, 42u, 0u, (uint32_t)i, &fa, &fbk);
    uint32_t a0, b0, a1, b1;
    tf2x32(fa, fbk, 0u, 2u, &a0, &b0);
    tf2x32(fa, fbk, 1u, 3u, &a1, &b1);
    int n = L * S;
    gen_idx_kernel<<<(n + 255) / 256, 256, 0, stream>>>(idxbuf, b0, b1, n, L - 1);

    // ---- attention per batch group ----
    for (int g = 0; g < ngroups; ++g) {
      float* hg = h + (size_t)g * segL;
      cast_bf16<<<(int)(segL / 1024), 256, 0, stream>>>(hg, hb, segL);
      dim3 gqkv(12, Mg / 128);
      mfma_gemm<2, 0><<<gqkv, 256, 0, stream>>>(hb, WqkvT, bqkv, nullptr, qb,
                                                nullptr, nullptr, 1536, 512,
                                                (int)CBseg);

      prob_scores_wave<<<(CBl * L) / 4, 256, 0, stream>>>(qb, kbuf, idxbuf, Mbuf,
                                                          L, S, CBl);
      topk_kernel<<<CBNHl, 256, 0, stream>>>(Mbuf, topidx, L, S);

      mean_v_partial<<<dim3(CBl, L / 256), 256, 0, stream>>>(vb, mvpart, L);
      mean_v_finish<<<CBl, 512, 0, stream>>>(mvpart, mv, L, L / 256);
      fill_ctx<<<(int)(segL / 256), 256, 0, stream>>>(ctxb, mv, L);
      flash_attn<<<dim3(fj, CBNHl), 256, 0, stream>>>(qb, kbuf, vb, topidx,
                                                      pzb, pob, L, S, CBNHl);
      flash_finish<<<(CBNHl * S * 64 + 255) / 256, 256, 0, stream>>>(
          pzb, pob, topidx, ctxb, L, S, CBNHl, fj);

      dim3 gq(4, Mg / 128);
      mfma_gemm<0, 1><<<gq, 256, 0, stream>>>(ctxb, WoT, bo + i * DM, hg, nullptr,
                                              nullptr, nullptr, 512, 512, 0);
    }
    ln_inplace<<<NB * L, 256, 0, stream>>>(h, ln1g + i * DM, ln1b + i * DM);

    // ---- FF row-chunked ----
    int rows = NB * L;
    int R = CB0 * 4096;
    if (R > rows) R = rows;
    for (int r0 = 0; r0 < rows; r0 += R) {
      float* hr = h + (size_t)r0 * 512;
      size_t rseg = (size_t)R * 512;
      cast_bf16<<<(int)(rseg / 1024), 256, 0, stream>>>(hr, hb, rseg);
      dim3 g1(16, R / 128);
      mfma_gemm<0, 2><<<g1, 256, 0, stream>>>(hb, W1b, fb1 + i * DFF_, nullptr, ybuf,
                                              nullptr, nullptr, 2048, 512, 0);
      dim3 g2(4, R / 128);
      mfma_gemm<0, 1><<<g2, 256, 0, stream>>>(ybuf, W2b, fb2 + i * DM, hr, nullptr,
                                              nullptr, nullptr, 512, 2048, 0);
    }
    ln_inplace<<<NB * L, 256, 0, stream>>>(h, ln2g + i * DM, ln2b + i * DM);

    // ---- conv + maxpool per batch group ----
    if (i < 2) {
      int Lh = L / 2;
      for (int g = 0; g < ngroups; ++g) {
        float* hg = h + (size_t)g * segL;
        cast_bf16<<<(int)(segL / 1024), 256, 0, stream>>>(hg, hb, segL);
        dim3 gc(4, Mg / 128);
        mfma_gemm<1, 3><<<gc, 256, 0, stream>>>(hb, Wcb, cb + i * DM, convY, nullptr,
                                                bng + i * DM, bnb + i * DM, 512, 1536, L);
        size_t tot = (size_t)CBl * Lh * 512;
        maxpool_kernel<<<(int)(tot / 256), 256, 0, stream>>>(
            convY, h + (size_t)g * CBl * Lh * 512, L);
      }
      L = Lh;
    }
  }

  final_ln_proj<<<NB * 47, 256, 0, stream>>>(h, flng, flnb, pW, pb, out, L);
}

// Round 15
// 3085.387 us; speedup vs baseline: 3.0634x; 1.1371x over previous
//
#include <hip/hip_runtime.h>
#include <cstdint>
#include <math.h>

#define NB 16
#define DM 512
#define NH 8
#define DFF_ 2048
#define SMAX 45

typedef unsigned short ushort_t;
typedef __bf16 bf16x8 __attribute__((ext_vector_type(8)));
typedef float f32x4 __attribute__((ext_vector_type(4)));

// ---------------- bf16 helpers ----------------
__device__ __forceinline__ ushort_t f2b(float f) {  // RNE f32 -> bf16 bits
  uint32_t u = __float_as_uint(f);
  uint32_t r = (u + 0x7FFFu + ((u >> 16) & 1u)) >> 16;
  return (ushort_t)r;
}
__device__ __forceinline__ float bu2f(ushort_t x) {
  return __uint_as_float((uint32_t)x << 16);
}
__device__ __forceinline__ float b2f_lo(uint32_t u) { return __uint_as_float(u << 16); }
__device__ __forceinline__ float b2f_hi(uint32_t u) { return __uint_as_float(u & 0xFFFF0000u); }
__device__ __forceinline__ uint32_t pack2(float lo, float hi) {
  return (uint32_t)f2b(lo) | ((uint32_t)f2b(hi) << 16);
}

// ---------------- threefry2x32 (JAX-compatible) ----------------
__host__ __device__ inline void tf2x32(uint32_t k0, uint32_t k1,
                                       uint32_t x0, uint32_t x1,
                                       uint32_t* o0, uint32_t* o1) {
  uint32_t ks0 = k0, ks1 = k1, ks2 = k0 ^ k1 ^ 0x1BD11BDAu;
  x0 += ks0; x1 += ks1;
#define TF_RND(r) { x0 += x1; x1 = (x1 << (r)) | (x1 >> (32 - (r))); x1 ^= x0; }
  TF_RND(13) TF_RND(15) TF_RND(26) TF_RND(6)
  x0 += ks1; x1 += ks2 + 1u;
  TF_RND(17) TF_RND(29) TF_RND(16) TF_RND(24)
  x0 += ks2; x1 += ks0 + 2u;
  TF_RND(13) TF_RND(15) TF_RND(26) TF_RND(6)
  x0 += ks0; x1 += ks1 + 3u;
  TF_RND(17) TF_RND(29) TF_RND(16) TF_RND(24)
  x0 += ks1; x1 += ks2 + 4u;
  TF_RND(13) TF_RND(15) TF_RND(26) TF_RND(6)
  x0 += ks2; x1 += ks0 + 5u;
#undef TF_RND
  *o0 = x0; *o1 = x1;
}

__global__ void gen_idx_kernel(int* __restrict__ idx, uint32_t k0, uint32_t k1,
                               int n, int mask) {
  int j = blockIdx.x * 256 + threadIdx.x;
  if (j >= n) return;
  int half = n >> 1;
  uint32_t o0, o1;
  if (j < half) {
    tf2x32(k0, k1, (uint32_t)j, (uint32_t)(j + half), &o0, &o1);
    idx[j] = (int)(o0 & (uint32_t)mask);
  } else {
    tf2x32(k0, k1, (uint32_t)(j - half), (uint32_t)j, &o0, &o1);
    idx[j] = (int)(o1 & (uint32_t)mask);
  }
}

// ---------------- block reduce helpers (256 threads, wave64) ----------------
__device__ inline float blk_reduce_sum(float v) {
  __shared__ float s[4];
  for (int o = 32; o > 0; o >>= 1) v += __shfl_down(v, o);
  int lane = threadIdx.x & 63, w = threadIdx.x >> 6;
  if (lane == 0) s[w] = v;
  __syncthreads();
  float r = s[0] + s[1] + s[2] + s[3];
  __syncthreads();
  return r;
}

// ---------------- embedding (writes bf16 h, 4 cols/thread) ----------------
__global__ void embed_kernel(const float* __restrict__ x, const float* __restrict__ W,
                             const float* __restrict__ bias, ushort_t* __restrict__ h) {
  size_t gid = (size_t)blockIdx.x * 256 + threadIdx.x;  // over NB*4096*128 quads
  int o4 = (int)(gid & 127) * 4;
  size_t bl = gid >> 7;
  const float* xr = x + bl * 7;
  float xv[7];
#pragma unroll
  for (int i = 0; i < 7; ++i) xv[i] = xr[i];
  float4 acc = *(const float4*)(bias + o4);
#pragma unroll
  for (int i = 0; i < 7; ++i) {
    float4 w4 = *(const float4*)(W + i * 512 + o4);
    acc.x += xv[i] * w4.x;
    acc.y += xv[i] * w4.y;
    acc.z += xv[i] * w4.z;
    acc.w += xv[i] * w4.w;
  }
  ushort4 o;
  o.x = f2b(acc.x); o.y = f2b(acc.y); o.z = f2b(acc.z); o.w = f2b(acc.w);
  *(ushort4*)(h + bl * 512 + o4) = o;
}

// ---------------- weight cast kernels ----------------
__global__ void cast_bf16(const float* __restrict__ src, ushort_t* __restrict__ dst,
                          size_t n) {
  size_t i = ((size_t)blockIdx.x * 256 + threadIdx.x) * 4;
  if (i >= n) return;
  float4 v = *(const float4*)(src + i);
  ushort4 o;
  o.x = f2b(v.x); o.y = f2b(v.y); o.z = f2b(v.z); o.w = f2b(v.w);
  *(ushort4*)(dst + i) = o;
}

// Bt[n*512+k] = bf16(W[k*512+n])   (512x512)
__global__ void castT512(const float* __restrict__ W, ushort_t* __restrict__ Bt) {
  int gid = blockIdx.x * 256 + threadIdx.x;
  int n = gid >> 9, k = gid & 511;
  Bt[gid] = f2b(W[(size_t)k * 512 + n]);
}

// Bt[n*1536 + dt*512 + i] = bf16(convW[n][i][dt])
__global__ void cast_convW(const float* __restrict__ W, ushort_t* __restrict__ Bt) {
  int gid = blockIdx.x * 256 + threadIdx.x;
  int n = gid / 1536, k = gid - n * 1536;
  int dt = k >> 9, ii = k & 511;
  Bt[gid] = f2b(W[((size_t)n * 512 + ii) * 3 + dt]);
}

// concat 3x512 bias -> 1536
__global__ void concat3(const float* __restrict__ a, const float* __restrict__ b,
                        const float* __restrict__ c, float* __restrict__ o) {
  int t = blockIdx.x * 256 + threadIdx.x;
  if (t >= 1536) return;
  o[t] = t < 512 ? a[t] : (t < 1024 ? b[t - 512] : c[t - 1024]);
}

// ---------------- bf16 MFMA GEMM (m97 structure + T2 XOR swizzle) ----------------
// MODE 0: standard  1: conv circular-A  2: QKV fused (route by bn>>2)
// EPI 0: store bf16   1: bf16 residual accumulate (h += result)
//     2: GELU->bf16   3: BN+ELU->f32
__device__ __forceinline__ float gelu_exact(float c) {
  return 0.5f * c * (1.0f + erff(c * 0.70710678118654752f));
}

template <int MODE, int EPI>
__global__ __launch_bounds__(256) void mfma_gemm(
    const ushort_t* __restrict__ A, const ushort_t* __restrict__ Bt,
    const float* __restrict__ bias, float* __restrict__ Cf,
    ushort_t* __restrict__ Cb, const float* __restrict__ bng,
    const float* __restrict__ bnb, int N, int K, int L) {
  __shared__ __align__(16) ushort_t As[128 * 64];
  __shared__ __align__(16) ushort_t Bs[128 * 64];
  const int tid = threadIdx.x;
  const int lane = tid & 63;
  const int wid = tid >> 6;
  const int wr = wid >> 1, wc = wid & 1;
  const int bm = blockIdx.y, bn = blockIdx.x;
  const int ln = lane & 15, lh = lane >> 4;

  f32x4 acc[4][4] = {};

  for (int k0 = 0; k0 < K; k0 += 64) {
    __syncthreads();
#pragma unroll
    for (int it = 0; it < 4; ++it) {
      int c = it * 256 + tid;
      int row = c >> 3;
      int kc = (((c & 7) ^ (row & 7)) << 3);  // swizzled source chunk
      size_t ga;
      if (MODE == 1) {
        int m = bm * 128 + row;
        int b = m / L, tpos = m - b * L;
        int k = k0 + kc;
        int dt = k >> 9, ii = k & 511;
        int tr2 = tpos + dt - 1;
        if (tr2 < 0) tr2 += L;
        if (tr2 >= L) tr2 -= L;
        ga = ((size_t)(b * L + tr2)) * 512 + ii;
      } else {
        ga = (size_t)(bm * 128 + row) * K + k0 + kc;
      }
      __builtin_amdgcn_global_load_lds(
          (const __attribute__((address_space(1))) void*)(A + ga),
          (__attribute__((address_space(3))) void*)(As + c * 8), 16, 0, 0);
      size_t gb = (size_t)(bn * 128 + row) * K + k0 + kc;
      __builtin_amdgcn_global_load_lds(
          (const __attribute__((address_space(1))) void*)(Bt + gb),
          (__attribute__((address_space(3))) void*)(Bs + c * 8), 16, 0, 0);
    }
    __syncthreads();
#pragma unroll
    for (int kk = 0; kk < 2; ++kk) {
      bf16x8 af[4], bf_[4];
#pragma unroll
      for (int m = 0; m < 4; ++m) {
        int ar = wr * 64 + m * 16 + ln;
        int aoff = (kk * 32 + lh * 8) ^ ((ar & 7) << 3);
        af[m] = *(const bf16x8*)&As[ar * 64 + aoff];
      }
#pragma unroll
      for (int n = 0; n < 4; ++n) {
        int br = wc * 64 + n * 16 + ln;
        int boff = (kk * 32 + lh * 8) ^ ((br & 7) << 3);
        bf_[n] = *(const bf16x8*)&Bs[br * 64 + boff];
      }
#pragma unroll
      for (int m = 0; m < 4; ++m)
#pragma unroll
        for (int n = 0; n < 4; ++n)
          acc[m][n] =
              __builtin_amdgcn_mfma_f32_16x16x32_bf16(af[m], bf_[n], acc[m][n], 0, 0, 0);
    }
  }

  const float bnscale = 0.9999950000374996f;  // 1/sqrt(1+1e-5)
#pragma unroll
  for (int m = 0; m < 4; ++m) {
    int row = bm * 128 + wr * 64 + m * 16 + lh * 4;
#pragma unroll
    for (int n = 0; n < 4; ++n) {
      int col = bn * 128 + wc * 64 + n * 16 + ln;
      float bsv = bias[col];
#pragma unroll
      for (int r = 0; r < 4; ++r) {
        float cval = acc[m][n][r] + bsv;
        if (MODE == 2) {
          ushort_t* dst = Cb + (size_t)(bn >> 2) * (size_t)L;  // L = CBseg
          dst[(size_t)(row + r) * 512 + (col & 511)] = f2b(cval);
        } else {
          size_t oi = (size_t)(row + r) * N + col;
          if (EPI == 0) {
            Cb[oi] = f2b(cval);
          } else if (EPI == 1) {
            Cb[oi] = f2b(cval + bu2f(Cb[oi]));
          } else if (EPI == 2) {
            Cb[oi] = f2b(gelu_exact(cval));
          } else {
            float c2 = cval * bnscale * bng[col] + bnb[col];
            Cf[oi] = c2 > 0.0f ? c2 : expm1f(c2);
          }
        }
      }
    }
  }
}

// ---------------- LN (in-place on bf16 h, packed uint per thread) ----------------
__global__ __launch_bounds__(256) void ln_inplace(ushort_t* __restrict__ h,
                                                  const float* __restrict__ g,
                                                  const float* __restrict__ b) {
  size_t row = blockIdx.x;
  uint32_t* hr = (uint32_t*)(h + row * 512);
  int t = threadIdx.x;
  uint32_t u = hr[t];
  float x0 = b2f_lo(u), x1 = b2f_hi(u);
  float mean = blk_reduce_sum(x0 + x1) * (1.0f / 512.0f);
  float d0 = x0 - mean, d1 = x1 - mean;
  float var = blk_reduce_sum(d0 * d0 + d1 * d1) * (1.0f / 512.0f);
  float rstd = rsqrtf(var + 1e-5f);
  float y0 = d0 * rstd * g[2 * t] + b[2 * t];
  float y1 = d1 * rstd * g[2 * t + 1] + b[2 * t + 1];
  hr[t] = pack2(y0, y1);
}

// ---------------- prob-sparse M scores: one wave per (b,l) + XCD-pinned b ----------
__global__ __launch_bounds__(256) void prob_scores_wave(const ushort_t* __restrict__ q,
                                                        const ushort_t* __restrict__ k,
                                                        const int* __restrict__ idx,
                                                        float* __restrict__ Mout,
                                                        int L, int S, int CBl) {
  int bid = blockIdx.x;
  int w = threadIdx.x >> 6;
  int lane = threadIdx.x & 63;
  int nxb = CBl < 8 ? CBl : 8;
  int gpb = 8 / nxb;
  int bmul = CBl / nxb;
  int xcd = bid & 7;
  int rest = bid >> 3;
  int b = (xcd / gpb) * bmul + (rest % bmul);
  int li = (rest / bmul) * gpb + (xcd % gpb);
  int l = li * 4 + w;

  const ushort_t* qr = q + ((size_t)(b * L + l)) * 512 + lane * 8;
  uint4 qu = *(const uint4*)qr;
  float qf[8];
  qf[0] = b2f_lo(qu.x); qf[1] = b2f_hi(qu.x);
  qf[2] = b2f_lo(qu.y); qf[3] = b2f_hi(qu.y);
  qf[4] = b2f_lo(qu.z); qf[5] = b2f_hi(qu.z);
  qf[6] = b2f_lo(qu.w); qf[7] = b2f_hi(qu.w);
  const int* il = idx + l * S;
  const ushort_t* kb = k + (size_t)b * L * 512 + lane * 8;
  float m = -INFINITY, ssum = 0.0f;
  for (int s = 0; s < S; ++s) {
    int j = il[s];
    uint4 ku = *(const uint4*)(kb + (size_t)j * 512);
    float dot = qf[0] * b2f_lo(ku.x) + qf[1] * b2f_hi(ku.x) +
                qf[2] * b2f_lo(ku.y) + qf[3] * b2f_hi(ku.y) +
                qf[4] * b2f_lo(ku.z) + qf[5] * b2f_hi(ku.z) +
                qf[6] * b2f_lo(ku.w) + qf[7] * b2f_hi(ku.w);
    dot += __shfl_xor(dot, 1);
    dot += __shfl_xor(dot, 2);
    dot += __shfl_xor(dot, 4);
    m = fmaxf(m, dot);
    ssum += dot;
  }
  if ((lane & 7) == 0) {
    int hh = lane >> 3;
    Mout[((size_t)(b * 8 + hh)) * L + l] = m - ssum / (float)L;
  }
}

// ---------------- top-k via 4-pass radix select ----------------
__global__ __launch_bounds__(256) void topk_kernel(const float* __restrict__ Mbuf,
                                                   int* __restrict__ top_idx,
                                                   int L, int S) {
  int bh = blockIdx.x;
  __shared__ uint32_t keys[4096];
  __shared__ int hist[256];
  __shared__ int sh_bin, sh_found, sh_cnt;
  const float* Mr = Mbuf + (size_t)bh * L;
  int t = threadIdx.x;

  for (int j = t; j < L; j += 256) {
    uint32_t u = __float_as_uint(Mr[j]);
    keys[j] = (u & 0x80000000u) ? ~u : (u | 0x80000000u);
  }
  if (t == 0) sh_cnt = 0;
  __syncthreads();

  uint32_t prefix = 0;
  int found = 0;
  for (int p = 24; p >= 0; p -= 8) {
    hist[t] = 0;
    __syncthreads();
    for (int j = t; j < L; j += 256) {
      uint32_t key = keys[j];
      bool match = (p == 24) || ((key >> (p + 8)) == (prefix >> (p + 8)));
      if (match) atomicAdd(&hist[(key >> p) & 255], 1);
    }
    __syncthreads();
    for (int o = 1; o < 256; o <<= 1) {
      int add = (t + o < 256) ? hist[t + o] : 0;
      __syncthreads();
      hist[t] += add;
      __syncthreads();
    }
    int sufIncl = hist[t];
    int sufExcl = (t < 255) ? hist[t + 1] : 0;
    int needv = S - found;
    if (sufExcl < needv && needv <= sufIncl) { sh_bin = t; sh_found = found + sufExcl; }
    __syncthreads();
    prefix |= (uint32_t)sh_bin << p;
    found = sh_found;
    __syncthreads();
  }

  uint32_t tau = prefix;
  int r = S - found;
  int chunk = L >> 8;
  int base = t * chunk;
  int localEq = 0;
  for (int i = 0; i < chunk; ++i) localEq += (keys[base + i] == tau) ? 1 : 0;
  hist[t] = localEq;
  __syncthreads();
  for (int o = 1; o < 256; o <<= 1) {
    int add = (t >= o) ? hist[t - o] : 0;
    __syncthreads();
    hist[t] += add;
    __syncthreads();
  }
  int myRank = hist[t] - localEq;
  for (int i = 0; i < chunk; ++i) {
    uint32_t key = keys[base + i];
    bool isEq = (key == tau);
    bool sel = (key > tau) || (isEq && myRank < r);
    if (isEq) myRank++;
    if (sel) {
      int slot = atomicAdd(&sh_cnt, 1);
      top_idx[bh * S + slot] = base + i;
    }
  }
}

// ---------------- mean of V: stage 1 (coalesced column partial sums) ----------------
__global__ __launch_bounds__(256) void mean_v_partial(const ushort_t* __restrict__ v,
                                                      float* __restrict__ part, int L) {
  int b = blockIdx.x;
  int chunk = blockIdx.y;
  int t = threadIdx.x;
  int c = t * 2;
  const ushort_t* base = v + ((size_t)b * L + (size_t)chunk * 256) * 512 + c;
  float a0 = 0.0f, a1 = 0.0f;
#pragma unroll 8
  for (int r = 0; r < 256; ++r) {
    uint32_t u = *(const uint32_t*)(base + (size_t)r * 512);
    a0 += b2f_lo(u);
    a1 += b2f_hi(u);
  }
  float* p = part + ((size_t)b * 16 + chunk) * 512 + c;
  p[0] = a0;
  p[1] = a1;
}

// ---------------- mean of V: stage 2 ----------------
__global__ void mean_v_finish(const float* __restrict__ part, float* __restrict__ mv,
                              int L, int nchunks) {
  int b = blockIdx.x;
  int c = threadIdx.x;  // 512 threads
  float s = 0.0f;
  for (int k = 0; k < nchunks; ++k) s += part[((size_t)b * 16 + k) * 512 + c];
  mv[b * 512 + c] = s / (float)L;
}

// ---------------- fill ctx (bf16) with broadcast mean ----------------
__global__ void fill_ctx(ushort_t* __restrict__ ctx, const float* __restrict__ mv,
                         int L) {
  size_t gid = (size_t)blockIdx.x * 256 + threadIdx.x;  // CB*L*512
  int c = (int)(gid & 511);
  size_t bl = gid >> 9;
  int b = (int)(bl / (size_t)L);
  ctx[gid] = f2b(mv[b * 512 + c]);
}

// ---------------- fused flash attention (no-max softmax: scores bounded) ----------
__global__ __launch_bounds__(256) void flash_attn(const ushort_t* __restrict__ q,
                                                  const ushort_t* __restrict__ k,
                                                  const ushort_t* __restrict__ v,
                                                  const int* __restrict__ top_idx,
                                                  float* __restrict__ pz,
                                                  float* __restrict__ po,
                                                  int L, int S, int CBNH) {
  __shared__ float qs[SMAX * 64];
  __shared__ ushort_t pt[SMAX * 64];
  int bh = blockIdx.y, js = blockIdx.x;
  int hh = bh & 7, b = bh >> 3;
  int t = threadIdx.x;
  int lane = t & 63, w = t >> 6;
  for (int e = t; e < S * 64; e += 256) {
    int u = e >> 6, d = e & 63;
    int l = top_idx[bh * S + u];
    qs[e] = bu2f(q[((size_t)(b * L + l)) * 512 + hh * 64 + d]);
  }
  __syncthreads();
  int j0 = js * 64;
  const ushort_t* kr = k + ((size_t)(b * L + j0 + lane)) * 512 + hh * 64;
  uint4 kreg[8];
#pragma unroll
  for (int c = 0; c < 8; ++c) kreg[c] = ((const uint4*)kr)[c];
  float zs[12];
#pragma unroll
  for (int mi = 0; mi < 12; ++mi) {
    int u = w + mi * 4;
    if (u < S) {
      const float* qu = qs + u * 64;
      float dot = 0.0f;
#pragma unroll
      for (int c = 0; c < 8; ++c) {
        uint4 ku = kreg[c];
        const float* q8 = qu + c * 8;
        dot += q8[0] * b2f_lo(ku.x) + q8[1] * b2f_hi(ku.x) +
               q8[2] * b2f_lo(ku.y) + q8[3] * b2f_hi(ku.y) +
               q8[4] * b2f_lo(ku.z) + q8[5] * b2f_hi(ku.z) +
               q8[6] * b2f_lo(ku.w) + q8[7] * b2f_hi(ku.w);
      }
      float P = __expf(dot * 0.125f);
      ushort_t Pb = f2b(P);
      pt[u * 64 + lane] = Pb;
      float ps = bu2f(Pb);
#pragma unroll
      for (int o2 = 1; o2 < 64; o2 <<= 1) ps += __shfl_xor(ps, o2);
      zs[mi] = ps;
    }
  }
  __syncthreads();
  float oacc[12] = {};
  for (int jb = 0; jb < 64; jb += 4) {
    float vv[4];
#pragma unroll
    for (int r = 0; r < 4; ++r)
      vv[r] = bu2f(v[((size_t)(b * L + j0 + jb + r)) * 512 + hh * 64 + lane]);
#pragma unroll
    for (int mi = 0; mi < 12; ++mi) {
      int u = w + mi * 4;
      if (u < S) {
        const ushort_t* p4 = &pt[u * 64 + jb];
        oacc[mi] += bu2f(p4[0]) * vv[0] + bu2f(p4[1]) * vv[1] +
                    bu2f(p4[2]) * vv[2] + bu2f(p4[3]) * vv[3];
      }
    }
  }
  size_t base = (size_t)js * CBNH + bh;
#pragma unroll
  for (int mi = 0; mi < 12; ++mi) {
    int u = w + mi * 4;
    if (u < S) {
      po[(base * SMAX + u) * 64 + lane] = oacc[mi];
      if (lane == 0) pz[base * SMAX + u] = zs[mi];
    }
  }
}

// ---------------- combine flash partials, /Z, scatter into ctx ----------------
__global__ void flash_finish(const float* __restrict__ pz, const float* __restrict__ po,
                             const int* __restrict__ top_idx, ushort_t* __restrict__ ctx,
                             int L, int S, int CBNH, int fj) {
  int gid = blockIdx.x * 256 + threadIdx.x;  // over CBNH*S*64
  if (gid >= CBNH * S * 64) return;
  int d = gid & 63;
  int r = gid >> 6;  // bh*S + u
  int u = r % S, bh = r / S;
  int hh = bh & 7, b = bh >> 3;
  float Z = 0.0f, O = 0.0f;
  for (int js = 0; js < fj; ++js) {
    size_t pi = ((size_t)js * CBNH + bh) * SMAX + u;
    Z += pz[pi];
    O += po[pi * 64 + d];
  }
  int l = top_idx[bh * S + u];
  ctx[((size_t)(b * L + l)) * 512 + hh * 64 + d] = f2b(O / Z);
}

// ---------------- maxpool window 3 stride 2 (f32 in, bf16 out) ----------------
__global__ void maxpool_kernel(const float* __restrict__ y, ushort_t* __restrict__ hout,
                               int L) {
  size_t gid = (size_t)blockIdx.x * 256 + threadIdx.x;  // CB*(L/2)*512
  int Lh = L >> 1;
  int o = (int)(gid & 511);
  size_t bj = gid >> 9;
  int j = (int)(bj % (size_t)Lh);
  int b = (int)(bj / (size_t)Lh);
  const float* base = y + ((size_t)(b * L + 2 * j)) * 512 + o;
  float mx = base[0];
  if (j > 0) mx = fmaxf(mx, base[-512]);
  mx = fmaxf(mx, base[512]);
  hout[gid] = f2b(mx);
}

// ---------------- final LN + projection (bf16 h) ----------------
__global__ __launch_bounds__(256) void final_ln_proj(const ushort_t* __restrict__ h,
                                                     const float* __restrict__ g,
                                                     const float* __restrict__ bb,
                                                     const float* __restrict__ pw,
                                                     const float* __restrict__ pb,
                                                     float* __restrict__ out, int L) {
  int b = blockIdx.x / 47, l = blockIdx.x % 47;
  const uint32_t* hr = (const uint32_t*)(h + ((size_t)(b * L + l)) * 512);
  int t = threadIdx.x;
  uint32_t u = hr[t];
  float x0 = b2f_lo(u), x1 = b2f_hi(u);
  float mean = blk_reduce_sum(x0 + x1) * (1.0f / 512.0f);
  float d0 = x0 - mean, d1 = x1 - mean;
  float var = blk_reduce_sum(d0 * d0 + d1 * d1) * (1.0f / 512.0f);
  float rstd = rsqrtf(var + 1e-5f);
  float y0 = d0 * rstd * g[2 * t] + bb[2 * t];
  float y1 = d1 * rstd * g[2 * t + 1] + bb[2 * t + 1];
  float dot = blk_reduce_sum(y0 * pw[2 * t] + y1 * pw[2 * t + 1]);
  if (t == 0) out[b * 47 + l] = dot + pb[0];
}

// ---------------- launcher ----------------
extern "C" void kernel_launch(void* const* d_in, const int* in_sizes, int n_in,
                              void* d_out, int out_size, void* d_ws, size_t ws_size,
                              hipStream_t stream) {
  const float* x = (const float*)d_in[0];
  const float* emb_W = (const float*)d_in[1];
  const float* emb_b = (const float*)d_in[2];
  const float* Wq = (const float*)d_in[3];
  const float* bq = (const float*)d_in[4];
  const float* Wk = (const float*)d_in[5];
  const float* bk = (const float*)d_in[6];
  const float* Wv = (const float*)d_in[7];
  const float* bv = (const float*)d_in[8];
  const float* Wo = (const float*)d_in[9];
  const float* bo = (const float*)d_in[10];
  const float* fW1 = (const float*)d_in[11];
  const float* fb1 = (const float*)d_in[12];
  const float* fW2 = (const float*)d_in[13];
  const float* fb2 = (const float*)d_in[14];
  const float* ln1g = (const float*)d_in[15];
  const float* ln1b = (const float*)d_in[16];
  const float* ln2g = (const float*)d_in[17];
  const float* ln2b = (const float*)d_in[18];
  const float* cW = (const float*)d_in[19];
  const float* cb = (const float*)d_in[20];
  const float* bng = (const float*)d_in[21];
  const float* bnb = (const float*)d_in[22];
  const float* flng = (const float*)d_in[23];
  const float* flnb = (const float*)d_in[24];
  const float* pW = (const float*)d_in[25];
  const float* pb = (const float*)d_in[26];
  float* out = (float*)d_out;

  // base batch-group size from ws_size (try 16, 8, 4, 2, 1)
  // need(CB0) = 19,086,848 + CB0 * 5,724,672 floats
  int CB0 = 16;
  while (CB0 > 1) {
    size_t need = 19086848ull + (size_t)CB0 * 5724672ull;
    if (need * 4 <= ws_size) break;
    CB0 >>= 1;
  }
  const size_t CBseg = (size_t)CB0 * 2097152ull;  // CB0*4096*512 (bf16 elems)

  float* ws = (float*)d_ws;
  size_t off = 0;
  ushort_t* h = (ushort_t*)ws;             off += 16777216ull;  // NB*4096*512 bf16
  ushort_t* wbase = (ushort_t*)(ws + off); off += 1966080ull;
  ushort_t* WqkvT = wbase;                 // 1536 x 512 (q rows, k rows, v rows)
  ushort_t* WoT = wbase + 786432;
  ushort_t* W1b = wbase + 1048576;
  ushort_t* W2b = wbase + 2097152;
  ushort_t* Wcb = wbase + 3145728;
  float* bqkv = ws + off;                  off += 1536ull;
  ushort_t* gArea = (ushort_t*)(ws + off); off += 2ull * CBseg;  // 4 segs bf16
  ushort_t* qb = gArea;
  ushort_t* kbuf = gArea + CBseg;
  ushort_t* vb = gArea + 2 * CBseg;
  ushort_t* ctxb = gArea + 3 * CBseg;
  ushort_t* ybuf = gArea;        // spans all 4 segs during FF (R x 2048 bf16)
  float* convY = (float*)gArea;  // spans first 2 segs during conv (CBseg f32)
  float* Mbuf = ws + off;                  off += (size_t)CB0 * 32768;
  float* mv = ws + off;                    off += 8192ull;
  int* topidx = (int*)(ws + off);          off += 6144ull;
  int* idxbuf = (int*)(ws + off);          off += 196608ull;
  float* pzb = ws + off;                   off += (size_t)CB0 * 23040;
  float* pob = ws + off;                   off += (size_t)CB0 * 1474560;
  float* mvpart = ws + off;                off += 131072ull;

  // embedding (bf16 h)
  {
    size_t total = (size_t)NB * 4096 * 128;
    embed_kernel<<<(int)(total / 256), 256, 0, stream>>>(x, emb_W, emb_b, h);
  }

  int L = 4096;
  for (int i = 0; i < 3; ++i) {
    int S = (i == 0) ? 45 : (i == 1) ? 40 : 35;
    int CBl = CB0 * (4096 / L);
    if (CBl > NB) CBl = NB;
    int ngroups = NB / CBl;
    int CBNHl = CBl * NH;
    int Mg = CBl * L;
    size_t segL = (size_t)Mg * 512;
    int fj = L / 64;

    // per-layer weight casts
    castT512<<<1024, 256, 0, stream>>>(Wq + (size_t)i * 262144, WqkvT);
    castT512<<<1024, 256, 0, stream>>>(Wk + (size_t)i * 262144, WqkvT + 262144);
    castT512<<<1024, 256, 0, stream>>>(Wv + (size_t)i * 262144, WqkvT + 524288);
    castT512<<<1024, 256, 0, stream>>>(Wo + (size_t)i * 262144, WoT);
    cast_bf16<<<1024, 256, 0, stream>>>(fW1 + (size_t)i * 1048576, W1b, 1048576);
    cast_bf16<<<1024, 256, 0, stream>>>(fW2 + (size_t)i * 1048576, W2b, 1048576);
    if (i < 2) cast_convW<<<3072, 256, 0, stream>>>(cW + (size_t)i * 786432, Wcb);
    concat3<<<6, 256, 0, stream>>>(bq + i * DM, bk + i * DM, bv + i * DM, bqkv);

    // JAX randint key
    uint32_t fa, fbk;
    tf2x32(0u, 42u, 0u, (uint32_t)i, &fa, &fbk);
    uint32_t a0, b0, a1, b1;
    tf2x32(fa, fbk, 0u, 2u, &a0, &b0);
    tf2x32(fa, fbk, 1u, 3u, &a1, &b1);
    int n = L * S;
    gen_idx_kernel<<<(n + 255) / 256, 256, 0, stream>>>(idxbuf, b0, b1, n, L - 1);

    // ---- attention per batch group ----
    for (int g = 0; g < ngroups; ++g) {
      ushort_t* hg = h + (size_t)g * segL;
      dim3 gqkv(12, Mg / 128);
      mfma_gemm<2, 0><<<gqkv, 256, 0, stream>>>(hg, WqkvT, bqkv, nullptr, qb,
                                                nullptr, nullptr, 1536, 512,
                                                (int)CBseg);

      prob_scores_wave<<<(CBl * L) / 4, 256, 0, stream>>>(qb, kbuf, idxbuf, Mbuf,
                                                          L, S, CBl);
      topk_kernel<<<CBNHl, 256, 0, stream>>>(Mbuf, topidx, L, S);

      mean_v_partial<<<dim3(CBl, L / 256), 256, 0, stream>>>(vb, mvpart, L);
      mean_v_finish<<<CBl, 512, 0, stream>>>(mvpart, mv, L, L / 256);
      fill_ctx<<<(int)(segL / 256), 256, 0, stream>>>(ctxb, mv, L);
      flash_attn<<<dim3(fj, CBNHl), 256, 0, stream>>>(qb, kbuf, vb, topidx,
                                                      pzb, pob, L, S, CBNHl);
      flash_finish<<<(CBNHl * S * 64 + 255) / 256, 256, 0, stream>>>(
          pzb, pob, topidx, ctxb, L, S, CBNHl, fj);

      dim3 gq(4, Mg / 128);
      mfma_gemm<0, 1><<<gq, 256, 0, stream>>>(ctxb, WoT, bo + i * DM, nullptr, hg,
                                              nullptr, nullptr, 512, 512, 0);
    }
    ln_inplace<<<NB * L, 256, 0, stream>>>(h, ln1g + i * DM, ln1b + i * DM);

    // ---- FF row-chunked ----
    int rows = NB * L;
    int R = CB0 * 4096;
    if (R > rows) R = rows;
    for (int r0 = 0; r0 < rows; r0 += R) {
      ushort_t* hr = h + (size_t)r0 * 512;
      dim3 g1(16, R / 128);
      mfma_gemm<0, 2><<<g1, 256, 0, stream>>>(hr, W1b, fb1 + i * DFF_, nullptr, ybuf,
                                              nullptr, nullptr, 2048, 512, 0);
      dim3 g2(4, R / 128);
      mfma_gemm<0, 1><<<g2, 256, 0, stream>>>(ybuf, W2b, fb2 + i * DM, nullptr, hr,
                                              nullptr, nullptr, 512, 2048, 0);
    }
    ln_inplace<<<NB * L, 256, 0, stream>>>(h, ln2g + i * DM, ln2b + i * DM);

    // ---- conv + maxpool per batch group ----
    if (i < 2) {
      int Lh = L / 2;
      for (int g = 0; g < ngroups; ++g) {
        ushort_t* hg = h + (size_t)g * segL;
        dim3 gc(4, Mg / 128);
        mfma_gemm<1, 3><<<gc, 256, 0, stream>>>(hg, Wcb, cb + i * DM, convY, nullptr,
                                                bng + i * DM, bnb + i * DM, 512, 1536, L);
        size_t tot = (size_t)CBl * Lh * 512;
        maxpool_kernel<<<(int)(tot / 256), 256, 0, stream>>>(
            convY, h + (size_t)g * CBl * Lh * 512, L);
      }
      L = Lh;
    }
  }

  final_ln_proj<<<NB * 47, 256, 0, stream>>>(h, flng, flnb, pW, pb, out, L);
}

// Round 16
// 3029.443 us; speedup vs baseline: 3.1200x; 1.0185x over previous
//
#include <hip/hip_runtime.h>
#include <cstdint>
#include <math.h>

#define NB 16
#define DM 512
#define NH 8
#define DFF_ 2048
#define SMAX 45

typedef unsigned short ushort_t;
typedef __bf16 bf16x8 __attribute__((ext_vector_type(8)));
typedef float f32x4 __attribute__((ext_vector_type(4)));

// ---------------- bf16 helpers ----------------
__device__ __forceinline__ ushort_t f2b(float f) {  // RNE f32 -> bf16 bits
  uint32_t u = __float_as_uint(f);
  uint32_t r = (u + 0x7FFFu + ((u >> 16) & 1u)) >> 16;
  return (ushort_t)r;
}
__device__ __forceinline__ float bu2f(ushort_t x) {
  return __uint_as_float((uint32_t)x << 16);
}
__device__ __forceinline__ float b2f_lo(uint32_t u) { return __uint_as_float(u << 16); }
__device__ __forceinline__ float b2f_hi(uint32_t u) { return __uint_as_float(u & 0xFFFF0000u); }
__device__ __forceinline__ uint32_t pack2(float lo, float hi) {
  return (uint32_t)f2b(lo) | ((uint32_t)f2b(hi) << 16);
}

// ---------------- threefry2x32 (JAX-compatible) ----------------
__host__ __device__ inline void tf2x32(uint32_t k0, uint32_t k1,
                                       uint32_t x0, uint32_t x1,
                                       uint32_t* o0, uint32_t* o1) {
  uint32_t ks0 = k0, ks1 = k1, ks2 = k0 ^ k1 ^ 0x1BD11BDAu;
  x0 += ks0; x1 += ks1;
#define TF_RND(r) { x0 += x1; x1 = (x1 << (r)) | (x1 >> (32 - (r))); x1 ^= x0; }
  TF_RND(13) TF_RND(15) TF_RND(26) TF_RND(6)
  x0 += ks1; x1 += ks2 + 1u;
  TF_RND(17) TF_RND(29) TF_RND(16) TF_RND(24)
  x0 += ks2; x1 += ks0 + 2u;
  TF_RND(13) TF_RND(15) TF_RND(26) TF_RND(6)
  x0 += ks0; x1 += ks1 + 3u;
  TF_RND(17) TF_RND(29) TF_RND(16) TF_RND(24)
  x0 += ks1; x1 += ks2 + 4u;
  TF_RND(13) TF_RND(15) TF_RND(26) TF_RND(6)
  x0 += ks2; x1 += ks0 + 5u;
#undef TF_RND
  *o0 = x0; *o1 = x1;
}

__global__ void gen_idx_kernel(int* __restrict__ idx, uint32_t k0, uint32_t k1,
                               int n, int mask) {
  int j = blockIdx.x * 256 + threadIdx.x;
  if (j >= n) return;
  int half = n >> 1;
  uint32_t o0, o1;
  if (j < half) {
    tf2x32(k0, k1, (uint32_t)j, (uint32_t)(j + half), &o0, &o1);
    idx[j] = (int)(o0 & (uint32_t)mask);
  } else {
    tf2x32(k0, k1, (uint32_t)(j - half), (uint32_t)j, &o0, &o1);
    idx[j] = (int)(o1 & (uint32_t)mask);
  }
}

// ---------------- block reduce helpers (256 threads, wave64) ----------------
__device__ inline float blk_reduce_sum(float v) {
  __shared__ float s[4];
  for (int o = 32; o > 0; o >>= 1) v += __shfl_down(v, o);
  int lane = threadIdx.x & 63, w = threadIdx.x >> 6;
  if (lane == 0) s[w] = v;
  __syncthreads();
  float r = s[0] + s[1] + s[2] + s[3];
  __syncthreads();
  return r;
}

// ---------------- embedding (writes bf16 h, 4 cols/thread) ----------------
__global__ void embed_kernel(const float* __restrict__ x, const float* __restrict__ W,
                             const float* __restrict__ bias, ushort_t* __restrict__ h) {
  size_t gid = (size_t)blockIdx.x * 256 + threadIdx.x;  // over NB*4096*128 quads
  int o4 = (int)(gid & 127) * 4;
  size_t bl = gid >> 7;
  const float* xr = x + bl * 7;
  float xv[7];
#pragma unroll
  for (int i = 0; i < 7; ++i) xv[i] = xr[i];
  float4 acc = *(const float4*)(bias + o4);
#pragma unroll
  for (int i = 0; i < 7; ++i) {
    float4 w4 = *(const float4*)(W + i * 512 + o4);
    acc.x += xv[i] * w4.x;
    acc.y += xv[i] * w4.y;
    acc.z += xv[i] * w4.z;
    acc.w += xv[i] * w4.w;
  }
  ushort4 o;
  o.x = f2b(acc.x); o.y = f2b(acc.y); o.z = f2b(acc.z); o.w = f2b(acc.w);
  *(ushort4*)(h + bl * 512 + o4) = o;
}

// ---------------- weight cast kernels ----------------
__global__ void cast_bf16(const float* __restrict__ src, ushort_t* __restrict__ dst,
                          size_t n) {
  size_t i = ((size_t)blockIdx.x * 256 + threadIdx.x) * 4;
  if (i >= n) return;
  float4 v = *(const float4*)(src + i);
  ushort4 o;
  o.x = f2b(v.x); o.y = f2b(v.y); o.z = f2b(v.z); o.w = f2b(v.w);
  *(ushort4*)(dst + i) = o;
}

// Bt[n*512+k] = bf16(W[k*512+n])   (512x512)
__global__ void castT512(const float* __restrict__ W, ushort_t* __restrict__ Bt) {
  int gid = blockIdx.x * 256 + threadIdx.x;
  int n = gid >> 9, k = gid & 511;
  Bt[gid] = f2b(W[(size_t)k * 512 + n]);
}

// Bt[n*1536 + dt*512 + i] = bf16(convW[n][i][dt])
__global__ void cast_convW(const float* __restrict__ W, ushort_t* __restrict__ Bt) {
  int gid = blockIdx.x * 256 + threadIdx.x;
  int n = gid / 1536, k = gid - n * 1536;
  int dt = k >> 9, ii = k & 511;
  Bt[gid] = f2b(W[((size_t)n * 512 + ii) * 3 + dt]);
}

// concat 3x512 bias -> 1536
__global__ void concat3(const float* __restrict__ a, const float* __restrict__ b,
                        const float* __restrict__ c, float* __restrict__ o) {
  int t = blockIdx.x * 256 + threadIdx.x;
  if (t >= 1536) return;
  o[t] = t < 512 ? a[t] : (t < 1024 ? b[t - 512] : c[t - 1024]);
}

// ---------------- bf16 MFMA GEMM (m97 structure + T2 XOR swizzle) ----------------
__device__ __forceinline__ float gelu_exact(float c) {
  return 0.5f * c * (1.0f + erff(c * 0.70710678118654752f));
}

template <int MODE, int EPI>
__global__ __launch_bounds__(256) void mfma_gemm(
    const ushort_t* __restrict__ A, const ushort_t* __restrict__ Bt,
    const float* __restrict__ bias, float* __restrict__ Cf,
    ushort_t* __restrict__ Cb, const float* __restrict__ bng,
    const float* __restrict__ bnb, int N, int K, int L) {
  __shared__ __align__(16) ushort_t As[128 * 64];
  __shared__ __align__(16) ushort_t Bs[128 * 64];
  const int tid = threadIdx.x;
  const int lane = tid & 63;
  const int wid = tid >> 6;
  const int wr = wid >> 1, wc = wid & 1;
  const int bm = blockIdx.y, bn = blockIdx.x;
  const int ln = lane & 15, lh = lane >> 4;

  f32x4 acc[4][4] = {};

  for (int k0 = 0; k0 < K; k0 += 64) {
    __syncthreads();
#pragma unroll
    for (int it = 0; it < 4; ++it) {
      int c = it * 256 + tid;
      int row = c >> 3;
      int kc = (((c & 7) ^ (row & 7)) << 3);  // swizzled source chunk
      size_t ga;
      if (MODE == 1) {
        int m = bm * 128 + row;
        int b = m / L, tpos = m - b * L;
        int k = k0 + kc;
        int dt = k >> 9, ii = k & 511;
        int tr2 = tpos + dt - 1;
        if (tr2 < 0) tr2 += L;
        if (tr2 >= L) tr2 -= L;
        ga = ((size_t)(b * L + tr2)) * 512 + ii;
      } else {
        ga = (size_t)(bm * 128 + row) * K + k0 + kc;
      }
      __builtin_amdgcn_global_load_lds(
          (const __attribute__((address_space(1))) void*)(A + ga),
          (__attribute__((address_space(3))) void*)(As + c * 8), 16, 0, 0);
      size_t gb = (size_t)(bn * 128 + row) * K + k0 + kc;
      __builtin_amdgcn_global_load_lds(
          (const __attribute__((address_space(1))) void*)(Bt + gb),
          (__attribute__((address_space(3))) void*)(Bs + c * 8), 16, 0, 0);
    }
    __syncthreads();
#pragma unroll
    for (int kk = 0; kk < 2; ++kk) {
      bf16x8 af[4], bf_[4];
#pragma unroll
      for (int m = 0; m < 4; ++m) {
        int ar = wr * 64 + m * 16 + ln;
        int aoff = (kk * 32 + lh * 8) ^ ((ar & 7) << 3);
        af[m] = *(const bf16x8*)&As[ar * 64 + aoff];
      }
#pragma unroll
      for (int n = 0; n < 4; ++n) {
        int br = wc * 64 + n * 16 + ln;
        int boff = (kk * 32 + lh * 8) ^ ((br & 7) << 3);
        bf_[n] = *(const bf16x8*)&Bs[br * 64 + boff];
      }
#pragma unroll
      for (int m = 0; m < 4; ++m)
#pragma unroll
        for (int n = 0; n < 4; ++n)
          acc[m][n] =
              __builtin_amdgcn_mfma_f32_16x16x32_bf16(af[m], bf_[n], acc[m][n], 0, 0, 0);
    }
  }

  const float bnscale = 0.9999950000374996f;  // 1/sqrt(1+1e-5)
#pragma unroll
  for (int m = 0; m < 4; ++m) {
    int row = bm * 128 + wr * 64 + m * 16 + lh * 4;
#pragma unroll
    for (int n = 0; n < 4; ++n) {
      int col = bn * 128 + wc * 64 + n * 16 + ln;
      float bsv = bias[col];
#pragma unroll
      for (int r = 0; r < 4; ++r) {
        float cval = acc[m][n][r] + bsv;
        if (MODE == 2) {
          ushort_t* dst = Cb + (size_t)(bn >> 2) * (size_t)L;  // L = CBseg
          dst[(size_t)(row + r) * 512 + (col & 511)] = f2b(cval);
        } else {
          size_t oi = (size_t)(row + r) * N + col;
          if (EPI == 0) {
            Cb[oi] = f2b(cval);
          } else if (EPI == 1) {
            Cb[oi] = f2b(cval + bu2f(Cb[oi]));
          } else if (EPI == 2) {
            Cb[oi] = f2b(gelu_exact(cval));
          } else {
            float c2 = cval * bnscale * bng[col] + bnb[col];
            Cf[oi] = c2 > 0.0f ? c2 : expm1f(c2);
          }
        }
      }
    }
  }
}

// ---------------- LN (in-place on bf16 h, packed uint per thread) ----------------
__global__ __launch_bounds__(256) void ln_inplace(ushort_t* __restrict__ h,
                                                  const float* __restrict__ g,
                                                  const float* __restrict__ b) {
  size_t row = blockIdx.x;
  uint32_t* hr = (uint32_t*)(h + row * 512);
  int t = threadIdx.x;
  uint32_t u = hr[t];
  float x0 = b2f_lo(u), x1 = b2f_hi(u);
  float mean = blk_reduce_sum(x0 + x1) * (1.0f / 512.0f);
  float d0 = x0 - mean, d1 = x1 - mean;
  float var = blk_reduce_sum(d0 * d0 + d1 * d1) * (1.0f / 512.0f);
  float rstd = rsqrtf(var + 1e-5f);
  float y0 = d0 * rstd * g[2 * t] + b[2 * t];
  float y1 = d1 * rstd * g[2 * t + 1] + b[2 * t + 1];
  hr[t] = pack2(y0, y1);
}

// ---------------- prob-sparse M scores: one wave per (b,l) + XCD-pinned b ----------
__global__ __launch_bounds__(256) void prob_scores_wave(const ushort_t* __restrict__ q,
                                                        const ushort_t* __restrict__ k,
                                                        const int* __restrict__ idx,
                                                        float* __restrict__ Mout,
                                                        int L, int S, int CBl) {
  int bid = blockIdx.x;
  int w = threadIdx.x >> 6;
  int lane = threadIdx.x & 63;
  int nxb = CBl < 8 ? CBl : 8;
  int gpb = 8 / nxb;
  int bmul = CBl / nxb;
  int xcd = bid & 7;
  int rest = bid >> 3;
  int b = (xcd / gpb) * bmul + (rest % bmul);
  int li = (rest / bmul) * gpb + (xcd % gpb);
  int l = li * 4 + w;

  const ushort_t* qr = q + ((size_t)(b * L + l)) * 512 + lane * 8;
  uint4 qu = *(const uint4*)qr;
  float qf[8];
  qf[0] = b2f_lo(qu.x); qf[1] = b2f_hi(qu.x);
  qf[2] = b2f_lo(qu.y); qf[3] = b2f_hi(qu.y);
  qf[4] = b2f_lo(qu.z); qf[5] = b2f_hi(qu.z);
  qf[6] = b2f_lo(qu.w); qf[7] = b2f_hi(qu.w);
  const int* il = idx + l * S;
  const ushort_t* kb = k + (size_t)b * L * 512 + lane * 8;
  float m = -INFINITY, ssum = 0.0f;
  for (int s = 0; s < S; ++s) {
    int j = il[s];
    uint4 ku = *(const uint4*)(kb + (size_t)j * 512);
    float dot = qf[0] * b2f_lo(ku.x) + qf[1] * b2f_hi(ku.x) +
                qf[2] * b2f_lo(ku.y) + qf[3] * b2f_hi(ku.y) +
                qf[4] * b2f_lo(ku.z) + qf[5] * b2f_hi(ku.z) +
                qf[6] * b2f_lo(ku.w) + qf[7] * b2f_hi(ku.w);
    dot += __shfl_xor(dot, 1);
    dot += __shfl_xor(dot, 2);
    dot += __shfl_xor(dot, 4);
    m = fmaxf(m, dot);
    ssum += dot;
  }
  if ((lane & 7) == 0) {
    int hh = lane >> 3;
    Mout[((size_t)(b * 8 + hh)) * L + l] = m - ssum / (float)L;
  }
}

// ---------------- top-k via 4-pass radix select ----------------
__global__ __launch_bounds__(256) void topk_kernel(const float* __restrict__ Mbuf,
                                                   int* __restrict__ top_idx,
                                                   int L, int S) {
  int bh = blockIdx.x;
  __shared__ uint32_t keys[4096];
  __shared__ int hist[256];
  __shared__ int sh_bin, sh_found, sh_cnt;
  const float* Mr = Mbuf + (size_t)bh * L;
  int t = threadIdx.x;

  for (int j = t; j < L; j += 256) {
    uint32_t u = __float_as_uint(Mr[j]);
    keys[j] = (u & 0x80000000u) ? ~u : (u | 0x80000000u);
  }
  if (t == 0) sh_cnt = 0;
  __syncthreads();

  uint32_t prefix = 0;
  int found = 0;
  for (int p = 24; p >= 0; p -= 8) {
    hist[t] = 0;
    __syncthreads();
    for (int j = t; j < L; j += 256) {
      uint32_t key = keys[j];
      bool match = (p == 24) || ((key >> (p + 8)) == (prefix >> (p + 8)));
      if (match) atomicAdd(&hist[(key >> p) & 255], 1);
    }
    __syncthreads();
    for (int o = 1; o < 256; o <<= 1) {
      int add = (t + o < 256) ? hist[t + o] : 0;
      __syncthreads();
      hist[t] += add;
      __syncthreads();
    }
    int sufIncl = hist[t];
    int sufExcl = (t < 255) ? hist[t + 1] : 0;
    int needv = S - found;
    if (sufExcl < needv && needv <= sufIncl) { sh_bin = t; sh_found = found + sufExcl; }
    __syncthreads();
    prefix |= (uint32_t)sh_bin << p;
    found = sh_found;
    __syncthreads();
  }

  uint32_t tau = prefix;
  int r = S - found;
  int chunk = L >> 8;
  int base = t * chunk;
  int localEq = 0;
  for (int i = 0; i < chunk; ++i) localEq += (keys[base + i] == tau) ? 1 : 0;
  hist[t] = localEq;
  __syncthreads();
  for (int o = 1; o < 256; o <<= 1) {
    int add = (t >= o) ? hist[t - o] : 0;
    __syncthreads();
    hist[t] += add;
    __syncthreads();
  }
  int myRank = hist[t] - localEq;
  for (int i = 0; i < chunk; ++i) {
    uint32_t key = keys[base + i];
    bool isEq = (key == tau);
    bool sel = (key > tau) || (isEq && myRank < r);
    if (isEq) myRank++;
    if (sel) {
      int slot = atomicAdd(&sh_cnt, 1);
      top_idx[bh * S + slot] = base + i;
    }
  }
}

// ---------------- mean of V: stage 1 (coalesced column partial sums) ----------------
__global__ __launch_bounds__(256) void mean_v_partial(const ushort_t* __restrict__ v,
                                                      float* __restrict__ part, int L) {
  int b = blockIdx.x;
  int chunk = blockIdx.y;
  int t = threadIdx.x;
  int c = t * 2;
  const ushort_t* base = v + ((size_t)b * L + (size_t)chunk * 256) * 512 + c;
  float a0 = 0.0f, a1 = 0.0f;
#pragma unroll 8
  for (int r = 0; r < 256; ++r) {
    uint32_t u = *(const uint32_t*)(base + (size_t)r * 512);
    a0 += b2f_lo(u);
    a1 += b2f_hi(u);
  }
  float* p = part + ((size_t)b * 16 + chunk) * 512 + c;
  p[0] = a0;
  p[1] = a1;
}

// ---------------- mean of V: stage 2 ----------------
__global__ void mean_v_finish(const float* __restrict__ part, float* __restrict__ mv,
                              int L, int nchunks) {
  int b = blockIdx.x;
  int c = threadIdx.x;  // 512 threads
  float s = 0.0f;
  for (int k = 0; k < nchunks; ++k) s += part[((size_t)b * 16 + k) * 512 + c];
  mv[b * 512 + c] = s / (float)L;
}

// ---------------- fill ctx (bf16) with broadcast mean ----------------
__global__ void fill_ctx(ushort_t* __restrict__ ctx, const float* __restrict__ mv,
                         int L) {
  size_t gid = (size_t)blockIdx.x * 256 + threadIdx.x;  // CB*L*512
  int c = (int)(gid & 511);
  size_t bl = gid >> 9;
  int b = (int)(bl / (size_t)L);
  ctx[gid] = f2b(mv[b * 512 + c]);
}

// ---------------- fused flash attention (no-max softmax; K pre-converted, f32 P) ----
__global__ __launch_bounds__(256) void flash_attn(const ushort_t* __restrict__ q,
                                                  const ushort_t* __restrict__ k,
                                                  const ushort_t* __restrict__ v,
                                                  const int* __restrict__ top_idx,
                                                  float* __restrict__ pz,
                                                  float* __restrict__ po,
                                                  int L, int S, int CBNH) {
  __shared__ float qs[SMAX * 64];
  __shared__ float pt[SMAX * 64];
  int bh = blockIdx.y, js = blockIdx.x;
  int hh = bh & 7, b = bh >> 3;
  int t = threadIdx.x;
  int lane = t & 63, w = t >> 6;
  for (int e = t; e < S * 64; e += 256) {
    int u = e >> 6, d = e & 63;
    int l = top_idx[bh * S + u];
    qs[e] = bu2f(q[((size_t)(b * L + l)) * 512 + hh * 64 + d]);
  }
  __syncthreads();
  int j0 = js * 64;
  // pre-convert this lane's K row to f32 registers (once, reused for all S)
  const ushort_t* kr = k + ((size_t)(b * L + j0 + lane)) * 512 + hh * 64;
  float kf[64];
#pragma unroll
  for (int c = 0; c < 8; ++c) {
    uint4 ku = ((const uint4*)kr)[c];
    kf[c * 8 + 0] = b2f_lo(ku.x); kf[c * 8 + 1] = b2f_hi(ku.x);
    kf[c * 8 + 2] = b2f_lo(ku.y); kf[c * 8 + 3] = b2f_hi(ku.y);
    kf[c * 8 + 4] = b2f_lo(ku.z); kf[c * 8 + 5] = b2f_hi(ku.z);
    kf[c * 8 + 6] = b2f_lo(ku.w); kf[c * 8 + 7] = b2f_hi(ku.w);
  }
  float zs[12];
#pragma unroll
  for (int mi = 0; mi < 12; ++mi) {
    int u = w + mi * 4;
    if (u < S) {
      const float4* qu = (const float4*)(qs + u * 64);
      float dot = 0.0f;
#pragma unroll
      for (int c = 0; c < 16; ++c) {
        float4 q4 = qu[c];
        dot += q4.x * kf[c * 4 + 0] + q4.y * kf[c * 4 + 1] +
               q4.z * kf[c * 4 + 2] + q4.w * kf[c * 4 + 3];
      }
      float P = __expf(dot * 0.125f);
      pt[u * 64 + lane] = P;
      float ps = P;
#pragma unroll
      for (int o2 = 1; o2 < 64; o2 <<= 1) ps += __shfl_xor(ps, o2);
      zs[mi] = ps;
    }
  }
  __syncthreads();
  // stage B: lane = d; accumulate P*V (f32 P via float4 broadcast reads)
  float oacc[12] = {};
  for (int jb = 0; jb < 64; jb += 4) {
    float vv[4];
#pragma unroll
    for (int r = 0; r < 4; ++r)
      vv[r] = bu2f(v[((size_t)(b * L + j0 + jb + r)) * 512 + hh * 64 + lane]);
#pragma unroll
    for (int mi = 0; mi < 12; ++mi) {
      int u = w + mi * 4;
      if (u < S) {
        float4 p4 = *(const float4*)&pt[u * 64 + jb];
        oacc[mi] += p4.x * vv[0] + p4.y * vv[1] + p4.z * vv[2] + p4.w * vv[3];
      }
    }
  }
  size_t base = (size_t)js * CBNH + bh;
#pragma unroll
  for (int mi = 0; mi < 12; ++mi) {
    int u = w + mi * 4;
    if (u < S) {
      po[(base * SMAX + u) * 64 + lane] = oacc[mi];
      if (lane == 0) pz[base * SMAX + u] = zs[mi];
    }
  }
}

// ---------------- combine flash partials, /Z, scatter into ctx ----------------
__global__ void flash_finish(const float* __restrict__ pz, const float* __restrict__ po,
                             const int* __restrict__ top_idx, ushort_t* __restrict__ ctx,
                             int L, int S, int CBNH, int fj) {
  int gid = blockIdx.x * 256 + threadIdx.x;  // over CBNH*S*64
  if (gid >= CBNH * S * 64) return;
  int d = gid & 63;
  int r = gid >> 6;  // bh*S + u
  int u = r % S, bh = r / S;
  int hh = bh & 7, b = bh >> 3;
  float Z = 0.0f, O = 0.0f;
  for (int js = 0; js < fj; ++js) {
    size_t pi = ((size_t)js * CBNH + bh) * SMAX + u;
    Z += pz[pi];
    O += po[pi * 64 + d];
  }
  int l = top_idx[bh * S + u];
  ctx[((size_t)(b * L + l)) * 512 + hh * 64 + d] = f2b(O / Z);
}

// ---------------- maxpool window 3 stride 2 (f32 in, bf16 out) ----------------
__global__ void maxpool_kernel(const float* __restrict__ y, ushort_t* __restrict__ hout,
                               int L) {
  size_t gid = (size_t)blockIdx.x * 256 + threadIdx.x;  // CB*(L/2)*512
  int Lh = L >> 1;
  int o = (int)(gid & 511);
  size_t bj = gid >> 9;
  int j = (int)(bj % (size_t)Lh);
  int b = (int)(bj / (size_t)Lh);
  const float* base = y + ((size_t)(b * L + 2 * j)) * 512 + o;
  float mx = base[0];
  if (j > 0) mx = fmaxf(mx, base[-512]);
  mx = fmaxf(mx, base[512]);
  hout[gid] = f2b(mx);
}

// ---------------- final LN + projection (bf16 h) ----------------
__global__ __launch_bounds__(256) void final_ln_proj(const ushort_t* __restrict__ h,
                                                     const float* __restrict__ g,
                                                     const float* __restrict__ bb,
                                                     const float* __restrict__ pw,
                                                     const float* __restrict__ pb,
                                                     float* __restrict__ out, int L) {
  int b = blockIdx.x / 47, l = blockIdx.x % 47;
  const uint32_t* hr = (const uint32_t*)(h + ((size_t)(b * L + l)) * 512);
  int t = threadIdx.x;
  uint32_t u = hr[t];
  float x0 = b2f_lo(u), x1 = b2f_hi(u);
  float mean = blk_reduce_sum(x0 + x1) * (1.0f / 512.0f);
  float d0 = x0 - mean, d1 = x1 - mean;
  float var = blk_reduce_sum(d0 * d0 + d1 * d1) * (1.0f / 512.0f);
  float rstd = rsqrtf(var + 1e-5f);
  float y0 = d0 * rstd * g[2 * t] + bb[2 * t];
  float y1 = d1 * rstd * g[2 * t + 1] + bb[2 * t + 1];
  float dot = blk_reduce_sum(y0 * pw[2 * t] + y1 * pw[2 * t + 1]);
  if (t == 0) out[b * 47 + l] = dot + pb[0];
}

// ---------------- launcher ----------------
extern "C" void kernel_launch(void* const* d_in, const int* in_sizes, int n_in,
                              void* d_out, int out_size, void* d_ws, size_t ws_size,
                              hipStream_t stream) {
  const float* x = (const float*)d_in[0];
  const float* emb_W = (const float*)d_in[1];
  const float* emb_b = (const float*)d_in[2];
  const float* Wq = (const float*)d_in[3];
  const float* bq = (const float*)d_in[4];
  const float* Wk = (const float*)d_in[5];
  const float* bk = (const float*)d_in[6];
  const float* Wv = (const float*)d_in[7];
  const float* bv = (const float*)d_in[8];
  const float* Wo = (const float*)d_in[9];
  const float* bo = (const float*)d_in[10];
  const float* fW1 = (const float*)d_in[11];
  const float* fb1 = (const float*)d_in[12];
  const float* fW2 = (const float*)d_in[13];
  const float* fb2 = (const float*)d_in[14];
  const float* ln1g = (const float*)d_in[15];
  const float* ln1b = (const float*)d_in[16];
  const float* ln2g = (const float*)d_in[17];
  const float* ln2b = (const float*)d_in[18];
  const float* cW = (const float*)d_in[19];
  const float* cb = (const float*)d_in[20];
  const float* bng = (const float*)d_in[21];
  const float* bnb = (const float*)d_in[22];
  const float* flng = (const float*)d_in[23];
  const float* flnb = (const float*)d_in[24];
  const float* pW = (const float*)d_in[25];
  const float* pb = (const float*)d_in[26];
  float* out = (float*)d_out;

  // base batch-group size from ws_size (try 16, 8, 4, 2, 1)
  // need(CB0) = 19,086,848 + CB0 * 5,724,672 floats
  int CB0 = 16;
  while (CB0 > 1) {
    size_t need = 19086848ull + (size_t)CB0 * 5724672ull;
    if (need * 4 <= ws_size) break;
    CB0 >>= 1;
  }
  const size_t CBseg = (size_t)CB0 * 2097152ull;  // CB0*4096*512 (bf16 elems)

  float* ws = (float*)d_ws;
  size_t off = 0;
  ushort_t* h = (ushort_t*)ws;             off += 16777216ull;  // NB*4096*512 bf16
  ushort_t* wbase = (ushort_t*)(ws + off); off += 1966080ull;
  ushort_t* WqkvT = wbase;                 // 1536 x 512 (q rows, k rows, v rows)
  ushort_t* WoT = wbase + 786432;
  ushort_t* W1b = wbase + 1048576;
  ushort_t* W2b = wbase + 2097152;
  ushort_t* Wcb = wbase + 3145728;
  float* bqkv = ws + off;                  off += 1536ull;
  ushort_t* gArea = (ushort_t*)(ws + off); off += 2ull * CBseg;  // 4 segs bf16
  ushort_t* qb = gArea;
  ushort_t* kbuf = gArea + CBseg;
  ushort_t* vb = gArea + 2 * CBseg;
  ushort_t* ctxb = gArea + 3 * CBseg;
  ushort_t* ybuf = gArea;        // spans all 4 segs during FF (R x 2048 bf16)
  float* convY = (float*)gArea;  // spans first 2 segs during conv (CBseg f32)
  float* Mbuf = ws + off;                  off += (size_t)CB0 * 32768;
  float* mv = ws + off;                    off += 8192ull;
  int* topidx = (int*)(ws + off);          off += 6144ull;
  int* idxbuf = (int*)(ws + off);          off += 196608ull;
  float* pzb = ws + off;                   off += (size_t)CB0 * 23040;
  float* pob = ws + off;                   off += (size_t)CB0 * 1474560;
  float* mvpart = ws + off;                off += 131072ull;

  // embedding (bf16 h)
  {
    size_t total = (size_t)NB * 4096 * 128;
    embed_kernel<<<(int)(total / 256), 256, 0, stream>>>(x, emb_W, emb_b, h);
  }

  int L = 4096;
  for (int i = 0; i < 3; ++i) {
    int S = (i == 0) ? 45 : (i == 1) ? 40 : 35;
    int CBl = CB0 * (4096 / L);
    if (CBl > NB) CBl = NB;
    int ngroups = NB / CBl;
    int CBNHl = CBl * NH;
    int Mg = CBl * L;
    size_t segL = (size_t)Mg * 512;
    int fj = L / 64;

    // per-layer weight casts
    castT512<<<1024, 256, 0, stream>>>(Wq + (size_t)i * 262144, WqkvT);
    castT512<<<1024, 256, 0, stream>>>(Wk + (size_t)i * 262144, WqkvT + 262144);
    castT512<<<1024, 256, 0, stream>>>(Wv + (size_t)i * 262144, WqkvT + 524288);
    castT512<<<1024, 256, 0, stream>>>(Wo + (size_t)i * 262144, WoT);
    cast_bf16<<<1024, 256, 0, stream>>>(fW1 + (size_t)i * 1048576, W1b, 1048576);
    cast_bf16<<<1024, 256, 0, stream>>>(fW2 + (size_t)i * 1048576, W2b, 1048576);
    if (i < 2) cast_convW<<<3072, 256, 0, stream>>>(cW + (size_t)i * 786432, Wcb);
    concat3<<<6, 256, 0, stream>>>(bq + i * DM, bk + i * DM, bv + i * DM, bqkv);

    // JAX randint key
    uint32_t fa, fbk;
    tf2x32(0u, 42u, 0u, (uint32_t)i, &fa, &fbk);
    uint32_t a0, b0, a1, b1;
    tf2x32(fa, fbk, 0u, 2u, &a0, &b0);
    tf2x32(fa, fbk, 1u, 3u, &a1, &b1);
    int n = L * S;
    gen_idx_kernel<<<(n + 255) / 256, 256, 0, stream>>>(idxbuf, b0, b1, n, L - 1);

    // ---- attention per batch group ----
    for (int g = 0; g < ngroups; ++g) {
      ushort_t* hg = h + (size_t)g * segL;
      dim3 gqkv(12, Mg / 128);
      mfma_gemm<2, 0><<<gqkv, 256, 0, stream>>>(hg, WqkvT, bqkv, nullptr, qb,
                                                nullptr, nullptr, 1536, 512,
                                                (int)CBseg);

      prob_scores_wave<<<(CBl * L) / 4, 256, 0, stream>>>(qb, kbuf, idxbuf, Mbuf,
                                                          L, S, CBl);
      topk_kernel<<<CBNHl, 256, 0, stream>>>(Mbuf, topidx, L, S);

      mean_v_partial<<<dim3(CBl, L / 256), 256, 0, stream>>>(vb, mvpart, L);
      mean_v_finish<<<CBl, 512, 0, stream>>>(mvpart, mv, L, L / 256);
      fill_ctx<<<(int)(segL / 256), 256, 0, stream>>>(ctxb, mv, L);
      flash_attn<<<dim3(fj, CBNHl), 256, 0, stream>>>(qb, kbuf, vb, topidx,
                                                      pzb, pob, L, S, CBNHl);
      flash_finish<<<(CBNHl * S * 64 + 255) / 256, 256, 0, stream>>>(
          pzb, pob, topidx, ctxb, L, S, CBNHl, fj);

      dim3 gq(4, Mg / 128);
      mfma_gemm<0, 1><<<gq, 256, 0, stream>>>(ctxb, WoT, bo + i * DM, nullptr, hg,
                                              nullptr, nullptr, 512, 512, 0);
    }
    ln_inplace<<<NB * L, 256, 0, stream>>>(h, ln1g + i * DM, ln1b + i * DM);

    // ---- FF row-chunked ----
    int rows = NB * L;
    int R = CB0 * 4096;
    if (R > rows) R = rows;
    for (int r0 = 0; r0 < rows; r0 += R) {
      ushort_t* hr = h + (size_t)r0 * 512;
      dim3 g1(16, R / 128);
      mfma_gemm<0, 2><<<g1, 256, 0, stream>>>(hr, W1b, fb1 + i * DFF_, nullptr, ybuf,
                                              nullptr, nullptr, 2048, 512, 0);
      dim3 g2(4, R / 128);
      mfma_gemm<0, 1><<<g2, 256, 0, stream>>>(ybuf, W2b, fb2 + i * DM, nullptr, hr,
                                              nullptr, nullptr, 512, 2048, 0);
    }
    ln_inplace<<<NB * L, 256, 0, stream>>>(h, ln2g + i * DM, ln2b + i * DM);

    // ---- conv + maxpool per batch group ----
    if (i < 2) {
      int Lh = L / 2;
      for (int g = 0; g < ngroups; ++g) {
        ushort_t* hg = h + (size_t)g * segL;
        dim3 gc(4, Mg / 128);
        mfma_gemm<1, 3><<<gc, 256, 0, stream>>>(hg, Wcb, cb + i * DM, convY, nullptr,
                                                bng + i * DM, bnb + i * DM, 512, 1536, L);
        size_t tot = (size_t)CBl * Lh * 512;
        maxpool_kernel<<<(int)(tot / 256), 256, 0, stream>>>(
            convY, h + (size_t)g * CBl * Lh * 512, L);
      }
      L = Lh;
    }
  }

  final_ln_proj<<<NB * 47, 256, 0, stream>>>(h, flng, flnb, pW, pb, out, L);
}